// Round 1
// baseline (3795.023 us; speedup 1.0000x reference)
//
#include <hip/hip_runtime.h>

#define EDIM 512
#define NH 8
#define HD 64
#define SEQ 1024
#define BATCH 8
#define NLAYER 4
#define KSEL 256
#define BQ 16

// ---------------------------------------------------------------------------
// Tiled fp32 GEMM: C[M,N] = A[M,K] @ W[K,N] + bias[N]
// Tile 128x64, BK=16, 256 threads, 8x4 per thread.
// grid = dim3(M/128, N/64): blockIdx.x = bm (fastest) so the 8 bn-blocks of
// one A row-tile land on one XCD (id%8 = bm%8) -> A-tile reused in XCD L2.
// ---------------------------------------------------------------------------
__global__ __launch_bounds__(256) void gemm_bias(const float* __restrict__ A,
                                                 const float* __restrict__ W,
                                                 const float* __restrict__ bias,
                                                 float* __restrict__ C,
                                                 int M, int N, int K)
{
    __shared__ float As[16][132];   // transposed: As[k][m], pad->2-way max
    __shared__ float Bs[16][68];
    const int t  = threadIdx.x;
    const int bm = blockIdx.x, bn = blockIdx.y;
    const int tx = t & 15, ty = t >> 4;
    float acc[8][4] = {};
    const float* Ab = A + (size_t)bm * 128 * K;
    const float* Wb = W + (size_t)bn * 64;
    const int r0  = t >> 2, kc0 = (t & 3) << 2;    // A staging
    const int brw = t >> 4, bnc = (t & 15) << 2;   // B staging

    for (int k0 = 0; k0 < K; k0 += 16) {
#pragma unroll
        for (int i = 0; i < 2; ++i) {
            int row = r0 + i * 64;
            float4 a4 = *(const float4*)(Ab + (size_t)row * K + k0 + kc0);
            As[kc0 + 0][row] = a4.x; As[kc0 + 1][row] = a4.y;
            As[kc0 + 2][row] = a4.z; As[kc0 + 3][row] = a4.w;
        }
        *(float4*)&Bs[brw][bnc] = *(const float4*)(Wb + (size_t)(k0 + brw) * N + bnc);
        __syncthreads();
#pragma unroll
        for (int kk = 0; kk < 16; ++kk) {
            float4 a0 = *(const float4*)&As[kk][ty * 8];
            float4 a1 = *(const float4*)&As[kk][ty * 8 + 4];
            float4 bb = *(const float4*)&Bs[kk][tx * 4];
            float ar[8] = {a0.x, a0.y, a0.z, a0.w, a1.x, a1.y, a1.z, a1.w};
#pragma unroll
            for (int r = 0; r < 8; ++r) {
                acc[r][0] += ar[r] * bb.x;
                acc[r][1] += ar[r] * bb.y;
                acc[r][2] += ar[r] * bb.z;
                acc[r][3] += ar[r] * bb.w;
            }
        }
        __syncthreads();
    }
    float4 bv = *(const float4*)(bias + (size_t)bn * 64 + tx * 4);
#pragma unroll
    for (int r = 0; r < 8; ++r) {
        float4 o;
        o.x = acc[r][0] + bv.x; o.y = acc[r][1] + bv.y;
        o.z = acc[r][2] + bv.z; o.w = acc[r][3] + bv.w;
        *(float4*)(C + (size_t)(bm * 128 + ty * 8 + r) * N + bn * 64 + tx * 4) = o;
    }
}

// ---------------------------------------------------------------------------
// Per-head K transpose: Kin[b, j, h*64+c] -> Kt[(b*8+h)*64 + c][j]  (j contig)
// grid = dim3(SEQ/64, B*H)
// ---------------------------------------------------------------------------
__global__ __launch_bounds__(256) void transpose_k(const float* __restrict__ Kin,
                                                   float* __restrict__ Kt)
{
    __shared__ float tile[64][65];
    const int bh = blockIdx.y;
    const int b = bh >> 3, h = bh & 7;
    const int j0 = blockIdx.x * 64;
    const int t = threadIdx.x;
    const int c = t & 63, jl = t >> 6;
#pragma unroll
    for (int i = 0; i < 16; ++i) {
        int j = jl + i * 4;
        tile[j][c] = Kin[(size_t)(b * SEQ + j0 + j) * EDIM + h * HD + c];
    }
    __syncthreads();
    const int jj = t & 63, cg = t >> 6;
#pragma unroll
    for (int i = 0; i < 16; ++i) {
        int cc = cg + i * 4;
        Kt[(size_t)(bh * HD + cc) * SEQ + j0 + jj] = tile[jj][cc];
    }
}

// ---------------------------------------------------------------------------
// Fused sparse attention. WG = (bh, 16 q rows), 256 threads (4 waves).
// Phase 1: scores (16x1024) -> LDS.  Phase 2: exact top-256 threshold via
// 32-step binary search on monotone uint map (ballot counting), masked
// softmax numerators back into LDS.  Phase 3: PV, scaled by 1/Z.
// grid = dim3(B*H, SEQ/BQ): bh fastest -> each XCD caches 8 heads' K/V.
// ---------------------------------------------------------------------------
__global__ __launch_bounds__(256) void attn_sparse(const float* __restrict__ Q,
                                                   const float* __restrict__ Kt,
                                                   const float* __restrict__ V,
                                                   float* __restrict__ O)
{
    __shared__ float sc[BQ][SEQ];       // 64 KB
    __shared__ float qs[BQ][HD + 4];    // padded, float4-aligned rows
    __shared__ float zinv[BQ];

    const int bh = blockIdx.x;
    const int b = bh >> 3, h = bh & 7;
    const int q0 = blockIdx.y * BQ;
    const int t = threadIdx.x;
    const int lane = t & 63, w = t >> 6;

    // stage q rows, pre-scaled by 1/sqrt(d)
    {
        const int qi = t >> 4, c4 = (t & 15) << 2;
        float4 q4 = *(const float4*)(Q + (size_t)(b * SEQ + q0 + qi) * EDIM + h * HD + c4);
        const float scale = 0.125f;
        qs[qi][c4 + 0] = q4.x * scale; qs[qi][c4 + 1] = q4.y * scale;
        qs[qi][c4 + 2] = q4.z * scale; qs[qi][c4 + 3] = q4.w * scale;
    }
    __syncthreads();

    // ---- phase 1: scores.  wave w owns rows 4w..4w+3; lane owns j = (lane+64*jb)*4..+3
    {
        const float* ktb = Kt + (size_t)bh * HD * SEQ;
        float4 acc[4][4] = {};
        for (int c4 = 0; c4 < HD; c4 += 4) {
            float4 qv4[4];
#pragma unroll
            for (int a = 0; a < 4; ++a) qv4[a] = *(const float4*)&qs[w * 4 + a][c4];
#pragma unroll
            for (int cc = 0; cc < 4; ++cc) {
                const float4* krow = (const float4*)(ktb + (size_t)(c4 + cc) * SEQ);
                float4 kv0 = krow[lane];
                float4 kv1 = krow[lane + 64];
                float4 kv2 = krow[lane + 128];
                float4 kv3 = krow[lane + 192];
#pragma unroll
                for (int a = 0; a < 4; ++a) {
                    float qv = ((const float*)&qv4[a])[cc];
                    acc[a][0].x += qv * kv0.x; acc[a][0].y += qv * kv0.y;
                    acc[a][0].z += qv * kv0.z; acc[a][0].w += qv * kv0.w;
                    acc[a][1].x += qv * kv1.x; acc[a][1].y += qv * kv1.y;
                    acc[a][1].z += qv * kv1.z; acc[a][1].w += qv * kv1.w;
                    acc[a][2].x += qv * kv2.x; acc[a][2].y += qv * kv2.y;
                    acc[a][2].z += qv * kv2.z; acc[a][2].w += qv * kv2.w;
                    acc[a][3].x += qv * kv3.x; acc[a][3].y += qv * kv3.y;
                    acc[a][3].z += qv * kv3.z; acc[a][3].w += qv * kv3.w;
                }
            }
        }
#pragma unroll
        for (int a = 0; a < 4; ++a)
#pragma unroll
            for (int jb = 0; jb < 4; ++jb)
                *(float4*)&sc[w * 4 + a][(lane + 64 * jb) * 4] = acc[a][jb];
    }
    __syncthreads();

    // ---- phase 2: exact 256th-largest threshold + masked softmax numerators
    for (int a = 0; a < 4; ++a) {
        const int qi = w * 4 + a;
        float4 sv4[4];
#pragma unroll
        for (int i = 0; i < 4; ++i)
            sv4[i] = *(const float4*)&sc[qi][(lane + 64 * i) * 4];
        const float* sv = (const float*)sv4;

        float m = sv[0];
#pragma unroll
        for (int i = 1; i < 16; ++i) m = fmaxf(m, sv[i]);
#pragma unroll
        for (int off = 32; off > 0; off >>= 1) m = fmaxf(m, __shfl_xor(m, off));

        unsigned u[16];
#pragma unroll
        for (int i = 0; i < 16; ++i) {
            int fi = __float_as_int(sv[i]);
            u[i] = (unsigned)(fi ^ ((fi >> 31) | 0x80000000));
        }
        // largest T with count(u >= T) >= KSEL  ==  256th-largest u (exact)
        unsigned T = 0;
        for (int bit = 31; bit >= 0; --bit) {
            unsigned cand = T | (1u << bit);
            int cnt = 0;
#pragma unroll
            for (int i = 0; i < 16; ++i)
                cnt += (int)__popcll(__ballot(u[i] >= cand));
            if (cnt >= KSEL) T = cand;
        }

        float4 ev4[4];
        float* ev = (float*)ev4;
        float Z = 0.f;
#pragma unroll
        for (int i = 0; i < 16; ++i) {
            float e = (u[i] >= T) ? __expf(sv[i] - m) : 0.f;
            ev[i] = e;
            Z += e;
        }
#pragma unroll
        for (int off = 32; off > 0; off >>= 1) Z += __shfl_xor(Z, off);
#pragma unroll
        for (int i = 0; i < 4; ++i)
            *(float4*)&sc[qi][(lane + 64 * i) * 4] = ev4[i];
        if (lane == 0) zinv[qi] = 1.0f / Z;
    }
    __syncthreads();

    // ---- phase 3: O = (P @ V) * zinv.  lane = channel c, wave w rows 4w..4w+3
    {
        const float* vb = V + (size_t)b * SEQ * EDIM + h * HD + lane;
        float accO[4] = {};
#pragma unroll 2
        for (int j0 = 0; j0 < SEQ; j0 += 4) {
            float v0 = vb[(size_t)(j0 + 0) * EDIM];
            float v1 = vb[(size_t)(j0 + 1) * EDIM];
            float v2 = vb[(size_t)(j0 + 2) * EDIM];
            float v3 = vb[(size_t)(j0 + 3) * EDIM];
#pragma unroll
            for (int i = 0; i < 4; ++i) {
                float4 e4 = *(const float4*)&sc[w * 4 + i][j0];
                accO[i] += e4.x * v0 + e4.y * v1 + e4.z * v2 + e4.w * v3;
            }
        }
#pragma unroll
        for (int i = 0; i < 4; ++i)
            O[(size_t)(b * SEQ + q0 + w * 4 + i) * EDIM + h * HD + lane] =
                accO[i] * zinv[w * 4 + i];
    }
}

// ---------------------------------------------------------------------------
// out[b, n] = mean_s(h[b, s, :]) @ fc_w + fc_b.   grid = 8 (one WG per b)
// ---------------------------------------------------------------------------
__global__ __launch_bounds__(256) void mean_fc(const float* __restrict__ Hf,
                                               const float* __restrict__ fcw,
                                               const float* __restrict__ fcb,
                                               float* __restrict__ out)
{
    __shared__ float hm[EDIM];
    const int b = blockIdx.x, t = threadIdx.x;
    const float* hb = Hf + (size_t)b * SEQ * EDIM;
    float s0 = 0.f, s1 = 0.f;
    for (int s = 0; s < SEQ; ++s) {
        s0 += hb[(size_t)s * EDIM + t];
        s1 += hb[(size_t)s * EDIM + t + 256];
    }
    hm[t] = s0 * (1.0f / SEQ);
    hm[t + 256] = s1 * (1.0f / SEQ);
    __syncthreads();
    if (t < 10) {
        float acc = fcb[t];
        for (int e = 0; e < EDIM; ++e) acc += hm[e] * fcw[e * 10 + t];
        out[b * 10 + t] = acc;
    }
}

// ---------------------------------------------------------------------------
extern "C" void kernel_launch(void* const* d_in, const int* in_sizes, int n_in,
                              void* d_out, int out_size, void* d_ws, size_t ws_size,
                              hipStream_t stream)
{
    const float* x     = (const float*)d_in[0];
    const float* emb_w = (const float*)d_in[1];
    const float* emb_b = (const float*)d_in[2];
    const float* Wq    = (const float*)d_in[3];
    const float* Wk    = (const float*)d_in[4];
    const float* Wv    = (const float*)d_in[5];
    const float* Wo    = (const float*)d_in[6];
    const float* bq    = (const float*)d_in[7];
    const float* bk    = (const float*)d_in[8];
    const float* bv    = (const float*)d_in[9];
    const float* bo    = (const float*)d_in[10];
    const float* fcw   = (const float*)d_in[11];
    const float* fcb   = (const float*)d_in[12];
    float* out = (float*)d_out;
    float* ws  = (float*)d_ws;

    const size_t SZ = (size_t)BATCH * SEQ * EDIM;   // 4,194,304 floats
    float* h  = ws;
    float* q  = ws + SZ;
    float* k  = ws + 2 * SZ;
    float* v  = ws + 3 * SZ;
    float* kt = ws + 4 * SZ;
    float* o  = ws + 5 * SZ;    // total ~96 MB of d_ws

    const int M = BATCH * SEQ;                      // 8192
    const dim3 gG(M / 128, EDIM / 64);              // (64, 8)
    const dim3 gT(SEQ / 64, BATCH * NH);            // (16, 64)
    const dim3 gA(BATCH * NH, SEQ / BQ);            // (64, 64)

    gemm_bias<<<gG, 256, 0, stream>>>(x, emb_w, emb_b, h, M, EDIM, 128);
    for (int l = 0; l < NLAYER; ++l) {
        const float* wq = Wq + (size_t)l * EDIM * EDIM;
        const float* wk = Wk + (size_t)l * EDIM * EDIM;
        const float* wv = Wv + (size_t)l * EDIM * EDIM;
        const float* wo = Wo + (size_t)l * EDIM * EDIM;
        gemm_bias<<<gG, 256, 0, stream>>>(h, wq, bq + l * EDIM, q, M, EDIM, EDIM);
        gemm_bias<<<gG, 256, 0, stream>>>(h, wk, bk + l * EDIM, k, M, EDIM, EDIM);
        gemm_bias<<<gG, 256, 0, stream>>>(h, wv, bv + l * EDIM, v, M, EDIM, EDIM);
        transpose_k<<<gT, 256, 0, stream>>>(k, kt);
        attn_sparse<<<gA, 256, 0, stream>>>(q, kt, v, o);
        gemm_bias<<<gG, 256, 0, stream>>>(o, wo, bo + l * EDIM, h, M, EDIM, EDIM);
    }
    mean_fc<<<8, 256, 0, stream>>>(h, fcw, fcb, out);
}

// Round 2
// 2652.312 us; speedup vs baseline: 1.4308x; 1.4308x over previous
//
#include <hip/hip_runtime.h>

#define EDIM 512
#define NH 8
#define HD 64
#define SEQ 1024
#define BATCH 8
#define NLAYER 4
#define KSEL 256

typedef __attribute__((ext_vector_type(8))) short short8;
typedef __attribute__((ext_vector_type(4))) float f32x4;

// ---- split-bf16 helpers: f ~= hi + lo, |err| ~ 2^-17 |f| ---------------
__device__ __forceinline__ unsigned short bf16_rne(float f) {
    unsigned u = __float_as_uint(f);
    return (unsigned short)((u + 0x7FFFu + ((u >> 16) & 1u)) >> 16);
}
__device__ __forceinline__ float bf16_tof(unsigned short h) {
    return __uint_as_float(((unsigned)h) << 16);
}
__device__ __forceinline__ void split2(float f, unsigned short& hi, unsigned short& lo) {
    hi = bf16_rne(f);
    float r = f - bf16_tof(hi);
    lo = (unsigned short)(__float_as_uint(r) >> 16);   // truncated bf16 of residual
}

// ---------------------------------------------------------------------------
// Tiled fp32 GEMM: C[M,N] = A[M,K] @ W[K,N] + bias[N]  (unchanged, known-good)
// ---------------------------------------------------------------------------
__global__ __launch_bounds__(256) void gemm_bias(const float* __restrict__ A,
                                                 const float* __restrict__ W,
                                                 const float* __restrict__ bias,
                                                 float* __restrict__ C,
                                                 int M, int N, int K)
{
    __shared__ float As[16][132];
    __shared__ float Bs[16][68];
    const int t  = threadIdx.x;
    const int bm = blockIdx.x, bn = blockIdx.y;
    const int tx = t & 15, ty = t >> 4;
    float acc[8][4] = {};
    const float* Ab = A + (size_t)bm * 128 * K;
    const float* Wb = W + (size_t)bn * 64;
    const int r0  = t >> 2, kc0 = (t & 3) << 2;
    const int brw = t >> 4, bnc = (t & 15) << 2;

    for (int k0 = 0; k0 < K; k0 += 16) {
#pragma unroll
        for (int i = 0; i < 2; ++i) {
            int row = r0 + i * 64;
            float4 a4 = *(const float4*)(Ab + (size_t)row * K + k0 + kc0);
            As[kc0 + 0][row] = a4.x; As[kc0 + 1][row] = a4.y;
            As[kc0 + 2][row] = a4.z; As[kc0 + 3][row] = a4.w;
        }
        *(float4*)&Bs[brw][bnc] = *(const float4*)(Wb + (size_t)(k0 + brw) * N + bnc);
        __syncthreads();
#pragma unroll
        for (int kk = 0; kk < 16; ++kk) {
            float4 a0 = *(const float4*)&As[kk][ty * 8];
            float4 a1 = *(const float4*)&As[kk][ty * 8 + 4];
            float4 bb = *(const float4*)&Bs[kk][tx * 4];
            float ar[8] = {a0.x, a0.y, a0.z, a0.w, a1.x, a1.y, a1.z, a1.w};
#pragma unroll
            for (int r = 0; r < 8; ++r) {
                acc[r][0] += ar[r] * bb.x;
                acc[r][1] += ar[r] * bb.y;
                acc[r][2] += ar[r] * bb.z;
                acc[r][3] += ar[r] * bb.w;
            }
        }
        __syncthreads();
    }
    float4 bv = *(const float4*)(bias + (size_t)bn * 64 + tx * 4);
#pragma unroll
    for (int r = 0; r < 8; ++r) {
        float4 o;
        o.x = acc[r][0] + bv.x; o.y = acc[r][1] + bv.y;
        o.z = acc[r][2] + bv.z; o.w = acc[r][3] + bv.w;
        *(float4*)(C + (size_t)(bm * 128 + ty * 8 + r) * N + bn * 64 + tx * 4) = o;
    }
}

// ---------------------------------------------------------------------------
// K fragment prep: k fp32 [B,S,E] -> kf shorts, MFMA B-operand layout:
// idx = ((((bh*64 + kt)*2 + kc)*2 + p)*64 + lane)*8, lane holds
// K[key=16kt+(lane&15)][c = 32kc + 8*(lane>>4) + 0..7], p=0 hi / p=1 lo.
// grid (32, 64), 256 thr: sub = t>>6 -> (kt pair, kc)
// ---------------------------------------------------------------------------
__global__ __launch_bounds__(256) void prep_kf(const float* __restrict__ k,
                                               short* __restrict__ kf)
{
    const int bh = blockIdx.y, b = bh >> 3, hh = bh & 7;
    const int t = threadIdx.x, l = t & 63, sub = t >> 6;
    const int kt = blockIdx.x * 2 + (sub >> 1), kc = sub & 1;
    const int key = kt * 16 + (l & 15);
    const int coff = kc * 32 + ((l >> 4) << 3);
    const float* src = k + (size_t)(b * SEQ + key) * EDIM + hh * HD + coff;
    float4 x0 = *(const float4*)(src);
    float4 x1 = *(const float4*)(src + 4);
    float xs[8] = {x0.x, x0.y, x0.z, x0.w, x1.x, x1.y, x1.z, x1.w};
    short8 hi, lo;
#pragma unroll
    for (int j = 0; j < 8; ++j) {
        unsigned short h, lw;
        split2(xs[j], h, lw);
        hi[j] = (short)h; lo[j] = (short)lw;
    }
    short* dst = kf + (size_t)(((bh * 64 + kt) * 2 + kc) * 2) * 512 + l * 8;
    *(short8*)(dst) = hi;
    *(short8*)(dst + 512) = lo;
}

// ---------------------------------------------------------------------------
// V fragment prep: v fp32 [B,S,E] -> vf shorts, MFMA B-operand layout for P@V:
// idx = ((((bh*32 + jc)*4 + n)*2 + p)*64 + lane)*8, lane holds
// V[j = 32jc + 8*(lane>>4) + 0..7][c = 16n + (lane&15)].
// grid (32, 64), 256 thr: n = t>>6.
// ---------------------------------------------------------------------------
__global__ __launch_bounds__(256) void prep_vf(const float* __restrict__ v,
                                               short* __restrict__ vf)
{
    const int bh = blockIdx.y, b = bh >> 3, hh = bh & 7;
    const int t = threadIdx.x, l = t & 63, n = t >> 6;
    const int jc = blockIdx.x;
    const int c = n * 16 + (l & 15);
    const int jb = jc * 32 + ((l >> 4) << 3);
    short8 hi, lo;
#pragma unroll
    for (int jj = 0; jj < 8; ++jj) {
        float f = v[(size_t)(b * SEQ + jb + jj) * EDIM + hh * HD + c];
        unsigned short h, lw;
        split2(f, h, lw);
        hi[jj] = (short)h; lo[jj] = (short)lw;
    }
    short* dst = vf + (size_t)(((bh * 32 + jc) * 4 + n) * 2) * 512 + l * 8;
    *(short8*)(dst) = hi;
    *(short8*)(dst + 512) = lo;
}

// ---------------------------------------------------------------------------
// Fused sparse attention, MFMA edition. WG = (bh, 16 q rows), 256 thr (4 waves).
// Phase 1: S = Q Kt via split-bf16 3-term mfma_f32_16x16x32_bf16; scores stored
//   in LDS as bf16 hi/lo planes (exactly reconstructible to the value selection
//   and softmax both use).
// Phase 2: exact top-256 threshold (32-bit ballot binary search) + softmax;
//   e written back to the same planes as hi/lo.
// Phase 3: O = P V via split-bf16 MFMA (P planes are already A-fragment-readable).
// grid (64 bh, 64 qblk): bh fastest -> 8 bh per XCD, K/V frags L2-resident.
// ---------------------------------------------------------------------------
#define PST 1040                     // plane row stride (shorts); 2080B, %128=32
#define PLO (16 * PST)

__global__ __launch_bounds__(256) void attn_mfma(const float* __restrict__ Q,
                                                 const short* __restrict__ KF,
                                                 const short* __restrict__ VF,
                                                 float* __restrict__ O)
{
    __shared__ short P[2 * 16 * PST];   // 66,560 B -> 2 WG/CU
    __shared__ float zinv[16];

    const int bh = blockIdx.x, b = bh >> 3, hh = bh & 7;
    const int q0 = blockIdx.y * 16;
    const int t = threadIdx.x, l = t & 63, w = t >> 6;

    // ---- Q A-fragments (scale 1/8 folded in): lane holds Q[m=l&15][k=8*(l>>4)+j]
    short8 aqh[2], aql[2];
    {
        const float* qp = Q + (size_t)(b * SEQ + q0 + (l & 15)) * EDIM + hh * HD + ((l >> 4) << 3);
#pragma unroll
        for (int kc = 0; kc < 2; ++kc) {
            float4 x0 = *(const float4*)(qp + kc * 32);
            float4 x1 = *(const float4*)(qp + kc * 32 + 4);
            float xs[8] = {x0.x, x0.y, x0.z, x0.w, x1.x, x1.y, x1.z, x1.w};
#pragma unroll
            for (int j = 0; j < 8; ++j) {
                unsigned short h, lw;
                split2(xs[j] * 0.125f, h, lw);
                aqh[kc][j] = (short)h; aql[kc][j] = (short)lw;
            }
        }
    }

    // ---- phase 1: wave w computes key tiles 16w..16w+15
    {
        const short* kfb = KF + (size_t)bh * 64 * 2048;
        for (int i = 0; i < 16; ++i) {
            const int kt = (w << 4) + i;
            const short* kp = kfb + (size_t)kt * 2048 + l * 8;
            short8 b00 = *(const short8*)(kp);
            short8 b01 = *(const short8*)(kp + 512);
            short8 b10 = *(const short8*)(kp + 1024);
            short8 b11 = *(const short8*)(kp + 1536);
            f32x4 acc = {0.f, 0.f, 0.f, 0.f};
            acc = __builtin_amdgcn_mfma_f32_16x16x32_bf16(aqh[0], b00, acc, 0, 0, 0);
            acc = __builtin_amdgcn_mfma_f32_16x16x32_bf16(aqh[0], b01, acc, 0, 0, 0);
            acc = __builtin_amdgcn_mfma_f32_16x16x32_bf16(aql[0], b00, acc, 0, 0, 0);
            acc = __builtin_amdgcn_mfma_f32_16x16x32_bf16(aqh[1], b10, acc, 0, 0, 0);
            acc = __builtin_amdgcn_mfma_f32_16x16x32_bf16(aqh[1], b11, acc, 0, 0, 0);
            acc = __builtin_amdgcn_mfma_f32_16x16x32_bf16(aql[1], b10, acc, 0, 0, 0);
            const int col = (kt << 4) + (l & 15);
            const int rb = (l >> 4) << 2;
#pragma unroll
            for (int r = 0; r < 4; ++r) {
                unsigned short h, lw;
                split2(acc[r], h, lw);
                P[(rb + r) * PST + col] = (short)h;
                P[PLO + (rb + r) * PST + col] = (short)lw;
            }
        }
    }
    __syncthreads();

    // ---- phase 2: rows 4w..4w+3; lane owns j = 16*l .. 16*l+15
    for (int a = 0; a < 4; ++a) {
        const int qi = (w << 2) + a;
        const int base = qi * PST + (l << 4);
        short8 H0 = *(const short8*)&P[base];
        short8 H1 = *(const short8*)&P[base + 8];
        short8 L0 = *(const short8*)&P[PLO + base];
        short8 L1 = *(const short8*)&P[PLO + base + 8];
        float s[16];
#pragma unroll
        for (int i = 0; i < 8; ++i) {
            s[i]     = bf16_tof((unsigned short)H0[i]) + bf16_tof((unsigned short)L0[i]);
            s[8 + i] = bf16_tof((unsigned short)H1[i]) + bf16_tof((unsigned short)L1[i]);
        }
        float m = s[0];
#pragma unroll
        for (int i = 1; i < 16; ++i) m = fmaxf(m, s[i]);
#pragma unroll
        for (int off = 32; off > 0; off >>= 1) m = fmaxf(m, __shfl_xor(m, off));

        unsigned u[16];
#pragma unroll
        for (int i = 0; i < 16; ++i) {
            int fi = __float_as_int(s[i]);
            u[i] = (unsigned)(fi ^ ((fi >> 31) | 0x80000000));
        }
        unsigned T = 0;
        for (int bit = 31; bit >= 0; --bit) {
            unsigned cand = T | (1u << bit);
            int cnt = 0;
#pragma unroll
            for (int i = 0; i < 16; ++i)
                cnt += (int)__popcll(__ballot(u[i] >= cand));
            if (cnt >= KSEL) T = cand;
        }

        float e[16];
        float Z = 0.f;
#pragma unroll
        for (int i = 0; i < 16; ++i) {
            e[i] = (u[i] >= T) ? __expf(s[i] - m) : 0.f;
            Z += e[i];
        }
#pragma unroll
        for (int off = 32; off > 0; off >>= 1) Z += __shfl_xor(Z, off);

        short8 EH0, EH1, EL0, EL1;
#pragma unroll
        for (int i = 0; i < 8; ++i) {
            unsigned short h, lw;
            split2(e[i], h, lw);     EH0[i] = (short)h; EL0[i] = (short)lw;
            split2(e[8 + i], h, lw); EH1[i] = (short)h; EL1[i] = (short)lw;
        }
        *(short8*)&P[base] = EH0;
        *(short8*)&P[base + 8] = EH1;
        *(short8*)&P[PLO + base] = EL0;
        *(short8*)&P[PLO + base + 8] = EL1;
        if (l == 0) zinv[qi] = 1.0f / Z;
    }
    __syncthreads();

    // ---- phase 3: wave w owns channel tile n=w (channels 16w..16w+15)
    {
        f32x4 oacc = {0.f, 0.f, 0.f, 0.f};
        const short* vfb = VF + (size_t)bh * 32 * 4096 + (size_t)w * 1024;
        for (int jc = 0; jc < 32; ++jc) {
            const int ab = (l & 15) * PST + (jc << 5) + ((l >> 4) << 3);
            short8 phv = *(const short8*)&P[ab];
            short8 plv = *(const short8*)&P[PLO + ab];
            const short* vp = vfb + (size_t)jc * 4096 + l * 8;
            short8 vh = *(const short8*)(vp);
            short8 vl = *(const short8*)(vp + 512);
            oacc = __builtin_amdgcn_mfma_f32_16x16x32_bf16(phv, vh, oacc, 0, 0, 0);
            oacc = __builtin_amdgcn_mfma_f32_16x16x32_bf16(phv, vl, oacc, 0, 0, 0);
            oacc = __builtin_amdgcn_mfma_f32_16x16x32_bf16(plv, vh, oacc, 0, 0, 0);
        }
        const int c = (w << 4) + (l & 15);
        const int rb = (l >> 4) << 2;
#pragma unroll
        for (int r = 0; r < 4; ++r)
            O[(size_t)(b * SEQ + q0 + rb + r) * EDIM + hh * HD + c] = oacc[r] * zinv[rb + r];
    }
}

// ---------------------------------------------------------------------------
__global__ __launch_bounds__(256) void mean_fc(const float* __restrict__ Hf,
                                               const float* __restrict__ fcw,
                                               const float* __restrict__ fcb,
                                               float* __restrict__ out)
{
    __shared__ float hm[EDIM];
    const int b = blockIdx.x, t = threadIdx.x;
    const float* hb = Hf + (size_t)b * SEQ * EDIM;
    float s0 = 0.f, s1 = 0.f;
    for (int s = 0; s < SEQ; ++s) {
        s0 += hb[(size_t)s * EDIM + t];
        s1 += hb[(size_t)s * EDIM + t + 256];
    }
    hm[t] = s0 * (1.0f / SEQ);
    hm[t + 256] = s1 * (1.0f / SEQ);
    __syncthreads();
    if (t < 10) {
        float acc = fcb[t];
        for (int e = 0; e < EDIM; ++e) acc += hm[e] * fcw[e * 10 + t];
        out[b * 10 + t] = acc;
    }
}

// ---------------------------------------------------------------------------
extern "C" void kernel_launch(void* const* d_in, const int* in_sizes, int n_in,
                              void* d_out, int out_size, void* d_ws, size_t ws_size,
                              hipStream_t stream)
{
    const float* x     = (const float*)d_in[0];
    const float* emb_w = (const float*)d_in[1];
    const float* emb_b = (const float*)d_in[2];
    const float* Wq    = (const float*)d_in[3];
    const float* Wk    = (const float*)d_in[4];
    const float* Wv    = (const float*)d_in[5];
    const float* Wo    = (const float*)d_in[6];
    const float* bq    = (const float*)d_in[7];
    const float* bk    = (const float*)d_in[8];
    const float* bv    = (const float*)d_in[9];
    const float* bo    = (const float*)d_in[10];
    const float* fcw   = (const float*)d_in[11];
    const float* fcb   = (const float*)d_in[12];
    float* out = (float*)d_out;
    float* ws  = (float*)d_ws;

    const size_t SZ = (size_t)BATCH * SEQ * EDIM;   // 4,194,304 floats = 16 MiB
    float* h  = ws;
    float* q  = ws + SZ;
    float* k  = ws + 2 * SZ;
    float* v  = ws + 3 * SZ;
    float* o  = ws + 4 * SZ;
    short* kf = (short*)(ws + 5 * SZ);              // 8.39M shorts = 16 MiB
    short* vf = (short*)(ws + 2 * SZ);              // overwrites dead fp32 k

    const int M = BATCH * SEQ;                      // 8192
    const dim3 gG(M / 128, EDIM / 64);              // (64, 8)
    const dim3 gP(32, BATCH * NH);                  // (32, 64)
    const dim3 gA(BATCH * NH, SEQ / 16);            // (64, 64)

    gemm_bias<<<gG, 256, 0, stream>>>(x, emb_w, emb_b, h, M, EDIM, 128);
    for (int l = 0; l < NLAYER; ++l) {
        const float* wq = Wq + (size_t)l * EDIM * EDIM;
        const float* wk = Wk + (size_t)l * EDIM * EDIM;
        const float* wv = Wv + (size_t)l * EDIM * EDIM;
        const float* wo = Wo + (size_t)l * EDIM * EDIM;
        gemm_bias<<<gG, 256, 0, stream>>>(h, wq, bq + l * EDIM, q, M, EDIM, EDIM);
        gemm_bias<<<gG, 256, 0, stream>>>(h, wk, bk + l * EDIM, k, M, EDIM, EDIM);
        gemm_bias<<<gG, 256, 0, stream>>>(h, wv, bv + l * EDIM, v, M, EDIM, EDIM);
        prep_kf<<<gP, 256, 0, stream>>>(k, kf);
        prep_vf<<<gP, 256, 0, stream>>>(v, vf);     // k fp32 is dead from here
        attn_mfma<<<gA, 256, 0, stream>>>(q, kf, vf, o);
        gemm_bias<<<gG, 256, 0, stream>>>(o, wo, bo + l * EDIM, h, M, EDIM, EDIM);
    }
    mean_fc<<<8, 256, 0, stream>>>(h, fcw, fcb, out);
}

// Round 3
// 1468.847 us; speedup vs baseline: 2.5837x; 1.8057x over previous
//
#include <hip/hip_runtime.h>

#define EDIM 512
#define NH 8
#define HD 64
#define SEQ 1024
#define BATCH 8
#define NLAYER 4
#define KSEL 256
#define PQ 8

typedef __attribute__((ext_vector_type(8))) short short8;
typedef __attribute__((ext_vector_type(4))) float f32x4;

// ---- split-bf16 helpers: f ~= hi + lo, |err| ~ 2^-17 |f| ---------------
__device__ __forceinline__ unsigned short bf16_rne(float f) {
    unsigned u = __float_as_uint(f);
    return (unsigned short)((u + 0x7FFFu + ((u >> 16) & 1u)) >> 16);
}
__device__ __forceinline__ float bf16_tof(unsigned short h) {
    return __uint_as_float(((unsigned)h) << 16);
}
__device__ __forceinline__ void split2(float f, unsigned short& hi, unsigned short& lo) {
    hi = bf16_rne(f);
    float r = f - bf16_tof(hi);
    lo = (unsigned short)(__float_as_uint(r) >> 16);
}
__device__ __forceinline__ unsigned fmap(float s) {
    int fi = __float_as_int(s);
    return (unsigned)(fi ^ ((fi >> 31) | 0x80000000));
}
__device__ __forceinline__ float funmap(unsigned u) {
    int fi = (u & 0x80000000u) ? (int)(u ^ 0x80000000u) : (int)~u;
    return __int_as_float(fi);
}

// ---------------------------------------------------------------------------
// A-fragment convert: fp32 A[M,K] -> af shorts, layout
// ((mt*KC + kc)*2 + p)*512 + l*8 ; lane holds A[m=16mt+(l&15)][k=32kc+8(l>>4)+j]
// grid ((K/32)/4 or 1, M/16)
// ---------------------------------------------------------------------------
__global__ __launch_bounds__(256) void conv_a(const float* __restrict__ A,
                                              short* __restrict__ af, int K)
{
    const int t = threadIdx.x, l = t & 63;
    const int KC = K >> 5;
    const int kc = blockIdx.x * 4 + (t >> 6);
    const int mt = blockIdx.y;
    const int m = mt * 16 + (l & 15);
    const int kb = kc * 32 + ((l >> 4) << 3);
    float4 x0 = *(const float4*)(A + (size_t)m * K + kb);
    float4 x1 = *(const float4*)(A + (size_t)m * K + kb + 4);
    float xs[8] = {x0.x, x0.y, x0.z, x0.w, x1.x, x1.y, x1.z, x1.w};
    short8 hi, lo;
#pragma unroll
    for (int j = 0; j < 8; ++j) {
        unsigned short h, lw;
        split2(xs[j], h, lw);
        hi[j] = (short)h; lo[j] = (short)lw;
    }
    short* dst = af + (size_t)((mt * KC + kc) * 2) * 512 + l * 8;
    *(short8*)(dst) = hi;
    *(short8*)(dst + 512) = lo;
}

// ---------------------------------------------------------------------------
// Weight (B-operand) convert, one layer's Wq/Wk/Wv/Wo (z picks matrix).
// layout ((nt*16 + kc)*2 + p)*512 + l*8 ; lane holds W[k=32kc+8(l>>4)+j][n=16nt+(l&15)]
// grid (4, 32, 4). K = EDIM.
// ---------------------------------------------------------------------------
__global__ __launch_bounds__(256) void conv_w4(const float* __restrict__ Wq,
                                               const float* __restrict__ Wk,
                                               const float* __restrict__ Wv,
                                               const float* __restrict__ Wo,
                                               int layer, short* __restrict__ wf)
{
    const int z = blockIdx.z;
    const float* W = (z == 0 ? Wq : z == 1 ? Wk : z == 2 ? Wv : Wo)
                     + (size_t)layer * EDIM * EDIM;
    const int t = threadIdx.x, l = t & 63;
    const int kc = blockIdx.x * 4 + (t >> 6);
    const int nt = blockIdx.y;
    const int n = nt * 16 + (l & 15);
    const int kb = kc * 32 + ((l >> 4) << 3);
    short8 hi, lo;
#pragma unroll
    for (int j = 0; j < 8; ++j) {
        unsigned short h, lw;
        split2(W[(size_t)(kb + j) * EDIM + n], h, lw);
        hi[j] = (short)h; lo[j] = (short)lw;
    }
    short* dst = wf + (size_t)z * 524288 + (size_t)((nt * 16 + kc) * 2) * 512 + l * 8;
    *(short8*)(dst) = hi;
    *(short8*)(dst + 512) = lo;
}

// single matrix variant (emb_w, K=128): grid (1, 32)
__global__ __launch_bounds__(256) void conv_w1(const float* __restrict__ W,
                                               short* __restrict__ wf, int K, int N)
{
    const int t = threadIdx.x, l = t & 63;
    const int KC = K >> 5;
    const int kc = blockIdx.x * 4 + (t >> 6);
    const int nt = blockIdx.y;
    const int n = nt * 16 + (l & 15);
    const int kb = kc * 32 + ((l >> 4) << 3);
    short8 hi, lo;
#pragma unroll
    for (int j = 0; j < 8; ++j) {
        unsigned short h, lw;
        split2(W[(size_t)(kb + j) * N + n], h, lw);
        hi[j] = (short)h; lo[j] = (short)lw;
    }
    short* dst = wf + (size_t)((nt * KC + kc) * 2) * 512 + l * 8;
    *(short8*)(dst) = hi;
    *(short8*)(dst + 512) = lo;
}

// ---------------------------------------------------------------------------
// Split-bf16 MFMA GEMM: C[M,N] = A@W + bias (3-term: AhBh + AhBl + AlBh).
// grid (M/128, N/128), 256 thr. Wave w: m-half w&1, n-half w>>1; 4x4 16x16 tiles.
// ---------------------------------------------------------------------------
__global__ __launch_bounds__(256) void gemm_mfma(const short* __restrict__ af,
                                                 const short* __restrict__ wf,
                                                 const float* __restrict__ bias,
                                                 float* __restrict__ C,
                                                 int M, int N, int K)
{
    const int t = threadIdx.x, l = t & 63, w = t >> 6;
    const int KC = K >> 5;
    const int mt0 = blockIdx.x * 8 + (w & 1) * 4;
    const int nt0 = blockIdx.y * 8 + (w >> 1) * 4;
    f32x4 acc[4][4] = {};

#pragma unroll 2
    for (int kc = 0; kc < KC; ++kc) {
        short8 ah[4], al[4], bh[4], bl[4];
#pragma unroll
        for (int i = 0; i < 4; ++i) {
            const short* ap = af + (size_t)(((mt0 + i) * KC + kc) * 2) * 512 + l * 8;
            ah[i] = *(const short8*)(ap);
            al[i] = *(const short8*)(ap + 512);
            const short* bp = wf + (size_t)(((nt0 + i) * KC + kc) * 2) * 512 + l * 8;
            bh[i] = *(const short8*)(bp);
            bl[i] = *(const short8*)(bp + 512);
        }
#pragma unroll
        for (int i = 0; i < 4; ++i)
#pragma unroll
            for (int j = 0; j < 4; ++j) {
                acc[i][j] = __builtin_amdgcn_mfma_f32_16x16x32_bf16(ah[i], bh[j], acc[i][j], 0, 0, 0);
                acc[i][j] = __builtin_amdgcn_mfma_f32_16x16x32_bf16(ah[i], bl[j], acc[i][j], 0, 0, 0);
                acc[i][j] = __builtin_amdgcn_mfma_f32_16x16x32_bf16(al[i], bh[j], acc[i][j], 0, 0, 0);
            }
    }
#pragma unroll
    for (int j = 0; j < 4; ++j) {
        const int col = (nt0 + j) * 16 + (l & 15);
        const float bv = bias[col];
#pragma unroll
        for (int i = 0; i < 4; ++i) {
            const int rowb = (mt0 + i) * 16 + ((l >> 4) << 2);
#pragma unroll
            for (int r = 0; r < 4; ++r)
                C[(size_t)(rowb + r) * N + col] = acc[i][j][r] + bv;
        }
    }
}

// ---------------------------------------------------------------------------
// K fragment prep (unchanged, verified): grid (32, 64)
// ---------------------------------------------------------------------------
__global__ __launch_bounds__(256) void prep_kf(const float* __restrict__ k,
                                               short* __restrict__ kf)
{
    const int bh = blockIdx.y, b = bh >> 3, hh = bh & 7;
    const int t = threadIdx.x, l = t & 63, sub = t >> 6;
    const int kt = blockIdx.x * 2 + (sub >> 1), kc = sub & 1;
    const int key = kt * 16 + (l & 15);
    const int coff = kc * 32 + ((l >> 4) << 3);
    const float* src = k + (size_t)(b * SEQ + key) * EDIM + hh * HD + coff;
    float4 x0 = *(const float4*)(src);
    float4 x1 = *(const float4*)(src + 4);
    float xs[8] = {x0.x, x0.y, x0.z, x0.w, x1.x, x1.y, x1.z, x1.w};
    short8 hi, lo;
#pragma unroll
    for (int j = 0; j < 8; ++j) {
        unsigned short h, lw;
        split2(xs[j], h, lw);
        hi[j] = (short)h; lo[j] = (short)lw;
    }
    short* dst = kf + (size_t)(((bh * 64 + kt) * 2 + kc) * 2) * 512 + l * 8;
    *(short8*)(dst) = hi;
    *(short8*)(dst + 512) = lo;
}

// ---------------------------------------------------------------------------
// V fragment prep (unchanged, verified): grid (32, 64)
// ---------------------------------------------------------------------------
__global__ __launch_bounds__(256) void prep_vf(const float* __restrict__ v,
                                               short* __restrict__ vf)
{
    const int bh = blockIdx.y, b = bh >> 3, hh = bh & 7;
    const int t = threadIdx.x, l = t & 63, n = t >> 6;
    const int jc = blockIdx.x;
    const int c = n * 16 + (l & 15);
    const int jb = jc * 32 + ((l >> 4) << 3);
    short8 hi, lo;
#pragma unroll
    for (int jj = 0; jj < 8; ++jj) {
        float f = v[(size_t)(b * SEQ + jb + jj) * EDIM + hh * HD + c];
        unsigned short h, lw;
        split2(f, h, lw);
        hi[jj] = (short)h; lo[jj] = (short)lw;
    }
    short* dst = vf + (size_t)(((bh * 32 + jc) * 4 + n) * 2) * 512 + l * 8;
    *(short8*)(dst) = hi;
    *(short8*)(dst + 512) = lo;
}

// ---------------------------------------------------------------------------
// Fused sparse attention, 8-row WG (32 KB LDS -> 4 WG/CU), XOR-swizzled P,
// dual-row interleaved exact top-256 search.
// P addressing: plane*8192 + row*1024 + ((chunk ^ row) << 3) + (col & 7),
// chunk = col >> 3  (16B granules, swizzle breaks same-bank row stride).
// grid (64 bh, 128 qblk), 256 thr.
// ---------------------------------------------------------------------------
__global__ __launch_bounds__(256, 4) void attn_mfma(const float* __restrict__ Q,
                                                    const short* __restrict__ KF,
                                                    const short* __restrict__ VF,
                                                    float* __restrict__ O)
{
    __shared__ short P[2 * PQ * 1024];   // 32 KB
    __shared__ float zinv[PQ];

    const int bh = blockIdx.x, b = bh >> 3, hh = bh & 7;
    const int q0 = blockIdx.y * PQ;
    const int t = threadIdx.x, l = t & 63, w = t >> 6;

    // Q A-fragments, rows duplicated (m = l&7), scale 1/8 folded in
    short8 aqh[2], aql[2];
    {
        const float* qp = Q + (size_t)(b * SEQ + q0 + (l & 7)) * EDIM + hh * HD + ((l >> 4) << 3);
#pragma unroll
        for (int kc = 0; kc < 2; ++kc) {
            float4 x0 = *(const float4*)(qp + kc * 32);
            float4 x1 = *(const float4*)(qp + kc * 32 + 4);
            float xs[8] = {x0.x, x0.y, x0.z, x0.w, x1.x, x1.y, x1.z, x1.w};
#pragma unroll
            for (int j = 0; j < 8; ++j) {
                unsigned short h, lw;
                split2(xs[j] * 0.125f, h, lw);
                aqh[kc][j] = (short)h; aql[kc][j] = (short)lw;
            }
        }
    }

    // ---- phase 1: wave w computes key tiles 16w..16w+15.
    // C rows 8..15 duplicate rows 0..7 -> lane groups 2,3 write the LO plane.
    {
        const short* kfb = KF + (size_t)bh * 64 * 2048;
        const int g = l >> 4;
        const int row4 = (g & 1) << 2;
        const int plane = g >> 1;
        for (int i = 0; i < 16; ++i) {
            const int kt = (w << 4) + i;
            const short* kp = kfb + (size_t)kt * 2048 + l * 8;
            short8 b00 = *(const short8*)(kp);
            short8 b01 = *(const short8*)(kp + 512);
            short8 b10 = *(const short8*)(kp + 1024);
            short8 b11 = *(const short8*)(kp + 1536);
            f32x4 acc = {0.f, 0.f, 0.f, 0.f};
            acc = __builtin_amdgcn_mfma_f32_16x16x32_bf16(aqh[0], b00, acc, 0, 0, 0);
            acc = __builtin_amdgcn_mfma_f32_16x16x32_bf16(aqh[0], b01, acc, 0, 0, 0);
            acc = __builtin_amdgcn_mfma_f32_16x16x32_bf16(aql[0], b00, acc, 0, 0, 0);
            acc = __builtin_amdgcn_mfma_f32_16x16x32_bf16(aqh[1], b10, acc, 0, 0, 0);
            acc = __builtin_amdgcn_mfma_f32_16x16x32_bf16(aqh[1], b11, acc, 0, 0, 0);
            acc = __builtin_amdgcn_mfma_f32_16x16x32_bf16(aql[1], b10, acc, 0, 0, 0);
            const int col = (kt << 4) + (l & 15);
            const int ch = col >> 3, co = col & 7;
#pragma unroll
            for (int r = 0; r < 4; ++r) {
                const int row = row4 + r;
                unsigned short h, lw;
                split2(acc[r], h, lw);
                P[plane * 8192 + row * 1024 + ((ch ^ row) << 3) + co] =
                    plane ? (short)lw : (short)h;
            }
        }
    }
    __syncthreads();

    // ---- phase 2: wave w owns rows 2w, 2w+1; lane owns chunks {l, 64+l}.
    {
        const int r0 = w << 1, r1 = r0 + 1;
        const int a00 = r0 * 1024 + ((l ^ r0) << 3);
        const int a01 = r0 * 1024 + (((64 + l) ^ r0) << 3);
        const int a10 = r1 * 1024 + ((l ^ r1) << 3);
        const int a11 = r1 * 1024 + (((64 + l) ^ r1) << 3);

        unsigned u0[16], u1[16];
        {
            short8 H0 = *(const short8*)&P[a00];
            short8 H1 = *(const short8*)&P[a01];
            short8 L0 = *(const short8*)&P[8192 + a00];
            short8 L1 = *(const short8*)&P[8192 + a01];
#pragma unroll
            for (int i = 0; i < 8; ++i) {
                u0[i]     = fmap(bf16_tof((unsigned short)H0[i]) + bf16_tof((unsigned short)L0[i]));
                u0[8 + i] = fmap(bf16_tof((unsigned short)H1[i]) + bf16_tof((unsigned short)L1[i]));
            }
        }
        {
            short8 H0 = *(const short8*)&P[a10];
            short8 H1 = *(const short8*)&P[a11];
            short8 L0 = *(const short8*)&P[8192 + a10];
            short8 L1 = *(const short8*)&P[8192 + a11];
#pragma unroll
            for (int i = 0; i < 8; ++i) {
                u1[i]     = fmap(bf16_tof((unsigned short)H0[i]) + bf16_tof((unsigned short)L0[i]));
                u1[8 + i] = fmap(bf16_tof((unsigned short)H1[i]) + bf16_tof((unsigned short)L1[i]));
            }
        }

        unsigned um0 = u0[0], um1 = u1[0];
#pragma unroll
        for (int i = 1; i < 16; ++i) {
            um0 = u0[i] > um0 ? u0[i] : um0;
            um1 = u1[i] > um1 ? u1[i] : um1;
        }
#pragma unroll
        for (int off = 32; off > 0; off >>= 1) {
            unsigned o0 = __shfl_xor((int)um0, off);
            unsigned o1 = __shfl_xor((int)um1, off);
            um0 = o0 > um0 ? o0 : um0;
            um1 = o1 > um1 ? o1 : um1;
        }

        // dual-row exact 256th-largest: interleaved 32-step binary search
        unsigned T0 = 0, T1 = 0;
        for (int bit = 31; bit >= 0; --bit) {
            const unsigned c0 = T0 | (1u << bit), c1 = T1 | (1u << bit);
            int n0 = 0, n1 = 0;
#pragma unroll
            for (int i = 0; i < 16; ++i) {
                n0 += (int)__popcll(__ballot(u0[i] >= c0));
                n1 += (int)__popcll(__ballot(u1[i] >= c1));
            }
            if (n0 >= KSEL) T0 = c0;
            if (n1 >= KSEL) T1 = c1;
        }

        // softmax numerators, written back hi/lo; Z reduced per row
        const float m0 = funmap(um0), m1 = funmap(um1);
        float Z0 = 0.f, Z1 = 0.f;
        short8 E, F;
#pragma unroll
        for (int i = 0; i < 8; ++i) {
            float e0 = (u0[i] >= T0) ? __expf(funmap(u0[i]) - m0) : 0.f;
            Z0 += e0;
            unsigned short h, lw; split2(e0, h, lw);
            E[i] = (short)h; F[i] = (short)lw;
        }
        *(short8*)&P[a00] = E; *(short8*)&P[8192 + a00] = F;
#pragma unroll
        for (int i = 0; i < 8; ++i) {
            float e0 = (u0[8 + i] >= T0) ? __expf(funmap(u0[8 + i]) - m0) : 0.f;
            Z0 += e0;
            unsigned short h, lw; split2(e0, h, lw);
            E[i] = (short)h; F[i] = (short)lw;
        }
        *(short8*)&P[a01] = E; *(short8*)&P[8192 + a01] = F;
#pragma unroll
        for (int i = 0; i < 8; ++i) {
            float e1 = (u1[i] >= T1) ? __expf(funmap(u1[i]) - m1) : 0.f;
            Z1 += e1;
            unsigned short h, lw; split2(e1, h, lw);
            E[i] = (short)h; F[i] = (short)lw;
        }
        *(short8*)&P[a10] = E; *(short8*)&P[8192 + a10] = F;
#pragma unroll
        for (int i = 0; i < 8; ++i) {
            float e1 = (u1[8 + i] >= T1) ? __expf(funmap(u1[8 + i]) - m1) : 0.f;
            Z1 += e1;
            unsigned short h, lw; split2(e1, h, lw);
            E[i] = (short)h; F[i] = (short)lw;
        }
        *(short8*)&P[a11] = E; *(short8*)&P[8192 + a11] = F;

#pragma unroll
        for (int off = 32; off > 0; off >>= 1) {
            Z0 += __shfl_xor(Z0, off);
            Z1 += __shfl_xor(Z1, off);
        }
        if (l == 0) { zinv[r0] = 1.0f / Z0; zinv[r1] = 1.0f / Z1; }
    }
    __syncthreads();

    // ---- phase 3: wave w owns channel tile w; A rows duplicated (m = l&7)
    {
        f32x4 oacc = {0.f, 0.f, 0.f, 0.f};
        const short* vfb = VF + (size_t)bh * 32 * 4096 + (size_t)w * 1024;
        const int m = l & 7, g = l >> 4;
        for (int jc = 0; jc < 32; ++jc) {
            const int chunk = (jc << 2) + g;
            const int base = m * 1024 + ((chunk ^ m) << 3);
            short8 ph = *(const short8*)&P[base];
            short8 pl = *(const short8*)&P[8192 + base];
            const short* vp = vfb + (size_t)jc * 4096 + l * 8;
            short8 vh = *(const short8*)(vp);
            short8 vl = *(const short8*)(vp + 512);
            oacc = __builtin_amdgcn_mfma_f32_16x16x32_bf16(ph, vh, oacc, 0, 0, 0);
            oacc = __builtin_amdgcn_mfma_f32_16x16x32_bf16(ph, vl, oacc, 0, 0, 0);
            oacc = __builtin_amdgcn_mfma_f32_16x16x32_bf16(pl, vh, oacc, 0, 0, 0);
        }
        if (l < 32) {
            const int c = (w << 4) + (l & 15);
            const int rb = (l >> 4) << 2;
#pragma unroll
            for (int r = 0; r < 4; ++r)
                O[(size_t)(b * SEQ + q0 + rb + r) * EDIM + hh * HD + c] =
                    oacc[r] * zinv[rb + r];
        }
    }
}

// ---------------------------------------------------------------------------
__global__ __launch_bounds__(256) void mean_fc(const float* __restrict__ Hf,
                                               const float* __restrict__ fcw,
                                               const float* __restrict__ fcb,
                                               float* __restrict__ out)
{
    __shared__ float hm[EDIM];
    const int b = blockIdx.x, t = threadIdx.x;
    const float* hb = Hf + (size_t)b * SEQ * EDIM;
    float s0 = 0.f, s1 = 0.f;
    for (int s = 0; s < SEQ; ++s) {
        s0 += hb[(size_t)s * EDIM + t];
        s1 += hb[(size_t)s * EDIM + t + 256];
    }
    hm[t] = s0 * (1.0f / SEQ);
    hm[t + 256] = s1 * (1.0f / SEQ);
    __syncthreads();
    if (t < 10) {
        float acc = fcb[t];
        for (int e = 0; e < EDIM; ++e) acc += hm[e] * fcw[e * 10 + t];
        out[b * 10 + t] = acc;
    }
}

// ---------------------------------------------------------------------------
extern "C" void kernel_launch(void* const* d_in, const int* in_sizes, int n_in,
                              void* d_out, int out_size, void* d_ws, size_t ws_size,
                              hipStream_t stream)
{
    const float* x     = (const float*)d_in[0];
    const float* emb_w = (const float*)d_in[1];
    const float* emb_b = (const float*)d_in[2];
    const float* Wq    = (const float*)d_in[3];
    const float* Wk    = (const float*)d_in[4];
    const float* Wv    = (const float*)d_in[5];
    const float* Wo    = (const float*)d_in[6];
    const float* bq    = (const float*)d_in[7];
    const float* bk    = (const float*)d_in[8];
    const float* bv    = (const float*)d_in[9];
    const float* bo    = (const float*)d_in[10];
    const float* fcw   = (const float*)d_in[11];
    const float* fcb   = (const float*)d_in[12];
    float* out = (float*)d_out;
    float* ws  = (float*)d_ws;

    const size_t SZ = (size_t)BATCH * SEQ * EDIM;   // 4,194,304 floats = 16 MiB
    float* h  = ws;                                  // S0
    float* q  = ws + SZ;                             // S1
    float* ko = ws + 2 * SZ;                         // S2: k, then attn out o
    float* v  = ws + 3 * SZ;                         // S3
    short* kf = (short*)(ws + 4 * SZ);               // S4 (16 MiB)
    short* vf = (short*)(ws + 5 * SZ);               // S5 (16 MiB)
    short* af = (short*)(ws + 6 * SZ);               // S6: xf / hf / of (16 MiB)
    short* wf = (short*)(ws + 7 * SZ);               // S7: 4x524288 + emb frags
    short* wfe = wf + 4 * 524288;

    const int M = BATCH * SEQ;                       // 8192
    const dim3 gG(M / 128, EDIM / 128);              // (64, 4)
    const dim3 gP(32, BATCH * NH);                   // (32, 64)
    const dim3 gA(BATCH * NH, SEQ / PQ);             // (64, 128)
    const dim3 gW4(4, 32, 4);
    const dim3 gCA(4, M / 16);                       // K=512 A-convert
    const dim3 gCAx(1, M / 16);                      // K=128 A-convert

    conv_w1<<<dim3(1, 32), 256, 0, stream>>>(emb_w, wfe, 128, EDIM);
    conv_a<<<gCAx, 256, 0, stream>>>(x, af, 128);
    gemm_mfma<<<gG, 256, 0, stream>>>(af, wfe, emb_b, h, M, EDIM, 128);

    for (int l = 0; l < NLAYER; ++l) {
        conv_w4<<<gW4, 256, 0, stream>>>(Wq, Wk, Wv, Wo, l, wf);
        conv_a<<<gCA, 256, 0, stream>>>(h, af, EDIM);
        gemm_mfma<<<gG, 256, 0, stream>>>(af, wf,              bq + l * EDIM, q,  M, EDIM, EDIM);
        gemm_mfma<<<gG, 256, 0, stream>>>(af, wf + 1 * 524288, bk + l * EDIM, ko, M, EDIM, EDIM);
        gemm_mfma<<<gG, 256, 0, stream>>>(af, wf + 2 * 524288, bv + l * EDIM, v,  M, EDIM, EDIM);
        prep_kf<<<gP, 256, 0, stream>>>(ko, kf);
        prep_vf<<<gP, 256, 0, stream>>>(v, vf);
        attn_mfma<<<gA, 256, 0, stream>>>(q, kf, vf, ko);     // o -> S2 (k dead)
        conv_a<<<gCA, 256, 0, stream>>>(ko, af, EDIM);        // hf dead -> reuse S6
        gemm_mfma<<<gG, 256, 0, stream>>>(af, wf + 3 * 524288, bo + l * EDIM, h, M, EDIM, EDIM);
    }
    mean_fc<<<8, 256, 0, stream>>>(h, fcw, fcb, out);
}

// Round 4
// 1343.284 us; speedup vs baseline: 2.8252x; 1.0935x over previous
//
#include <hip/hip_runtime.h>

#define EDIM 512
#define NH 8
#define HD 64
#define SEQ 1024
#define BATCH 8
#define NLAYER 4
#define KSEL 256
#define PQ 8

typedef __attribute__((ext_vector_type(8))) short short8;
typedef __attribute__((ext_vector_type(4))) float f32x4;

// ---- split-bf16 helpers: f ~= hi + lo, |err| ~ 2^-17 |f| ---------------
__device__ __forceinline__ unsigned short bf16_rne(float f) {
    unsigned u = __float_as_uint(f);
    return (unsigned short)((u + 0x7FFFu + ((u >> 16) & 1u)) >> 16);
}
__device__ __forceinline__ float bf16_tof(unsigned short h) {
    return __uint_as_float(((unsigned)h) << 16);
}
__device__ __forceinline__ void split2(float f, unsigned short& hi, unsigned short& lo) {
    hi = bf16_rne(f);
    float r = f - bf16_tof(hi);
    lo = (unsigned short)(__float_as_uint(r) >> 16);
}
__device__ __forceinline__ unsigned fmap(float s) {
    int fi = __float_as_int(s);
    return (unsigned)(fi ^ ((fi >> 31) | 0x80000000));
}
__device__ __forceinline__ float funmap(unsigned u) {
    int fi = (u & 0x80000000u) ? (int)(u ^ 0x80000000u) : (int)~u;
    return __int_as_float(fi);
}

// ---------------------------------------------------------------------------
// A-fragment convert: fp32 A[M,K] -> af shorts, layout
// ((mt*KC + kc)*2 + p)*512 + l*8 ; lane holds A[m=16mt+(l&15)][k=32kc+8(l>>4)+j]
// grid ((K/32)/4 or 1, M/16)
// ---------------------------------------------------------------------------
__global__ __launch_bounds__(256) void conv_a(const float* __restrict__ A,
                                              short* __restrict__ af, int K)
{
    const int t = threadIdx.x, l = t & 63;
    const int KC = K >> 5;
    const int kc = blockIdx.x * 4 + (t >> 6);
    const int mt = blockIdx.y;
    const int m = mt * 16 + (l & 15);
    const int kb = kc * 32 + ((l >> 4) << 3);
    float4 x0 = *(const float4*)(A + (size_t)m * K + kb);
    float4 x1 = *(const float4*)(A + (size_t)m * K + kb + 4);
    float xs[8] = {x0.x, x0.y, x0.z, x0.w, x1.x, x1.y, x1.z, x1.w};
    short8 hi, lo;
#pragma unroll
    for (int j = 0; j < 8; ++j) {
        unsigned short h, lw;
        split2(xs[j], h, lw);
        hi[j] = (short)h; lo[j] = (short)lw;
    }
    short* dst = af + (size_t)((mt * KC + kc) * 2) * 512 + l * 8;
    *(short8*)(dst) = hi;
    *(short8*)(dst + 512) = lo;
}

// ---------------------------------------------------------------------------
// Weight (B-operand) convert, one layer's Wq/Wk/Wv/Wo (z picks matrix).
// layout ((nt*16 + kc)*2 + p)*512 + l*8 ; lane holds W[k=32kc+8(l>>4)+j][n=16nt+(l&15)]
// grid (4, 32, 4). K = EDIM.
// ---------------------------------------------------------------------------
__global__ __launch_bounds__(256) void conv_w4(const float* __restrict__ Wq,
                                               const float* __restrict__ Wk,
                                               const float* __restrict__ Wv,
                                               const float* __restrict__ Wo,
                                               int layer, short* __restrict__ wf)
{
    const int z = blockIdx.z;
    const float* W = (z == 0 ? Wq : z == 1 ? Wk : z == 2 ? Wv : Wo)
                     + (size_t)layer * EDIM * EDIM;
    const int t = threadIdx.x, l = t & 63;
    const int kc = blockIdx.x * 4 + (t >> 6);
    const int nt = blockIdx.y;
    const int n = nt * 16 + (l & 15);
    const int kb = kc * 32 + ((l >> 4) << 3);
    short8 hi, lo;
#pragma unroll
    for (int j = 0; j < 8; ++j) {
        unsigned short h, lw;
        split2(W[(size_t)(kb + j) * EDIM + n], h, lw);
        hi[j] = (short)h; lo[j] = (short)lw;
    }
    short* dst = wf + (size_t)z * 524288 + (size_t)((nt * 16 + kc) * 2) * 512 + l * 8;
    *(short8*)(dst) = hi;
    *(short8*)(dst + 512) = lo;
}

// single matrix variant (emb_w, K=128): grid (1, 32)
__global__ __launch_bounds__(256) void conv_w1(const float* __restrict__ W,
                                               short* __restrict__ wf, int K, int N)
{
    const int t = threadIdx.x, l = t & 63;
    const int KC = K >> 5;
    const int kc = blockIdx.x * 4 + (t >> 6);
    const int nt = blockIdx.y;
    const int n = nt * 16 + (l & 15);
    const int kb = kc * 32 + ((l >> 4) << 3);
    short8 hi, lo;
#pragma unroll
    for (int j = 0; j < 8; ++j) {
        unsigned short h, lw;
        split2(W[(size_t)(kb + j) * N + n], h, lw);
        hi[j] = (short)h; lo[j] = (short)lw;
    }
    short* dst = wf + (size_t)((nt * KC + kc) * 2) * 512 + l * 8;
    *(short8*)(dst) = hi;
    *(short8*)(dst + 512) = lo;
}

// ---------------------------------------------------------------------------
// Split-bf16 MFMA GEMM: C[M,N] = A@W + bias. Tile 128x64 -> grid (M/128, N/64)
// = 512 blocks = 2 WG/CU (was 1). Wave w: m-half w&1 (4 mt), n-half w>>1 (2 nt).
// Same-x blocks land on one XCD (id%8 = x%8) -> A row-slice L2-resident.
// ---------------------------------------------------------------------------
__global__ __launch_bounds__(256) void gemm_mfma(const short* __restrict__ af,
                                                 const short* __restrict__ wf,
                                                 const float* __restrict__ bias,
                                                 float* __restrict__ C,
                                                 int M, int N, int K)
{
    const int t = threadIdx.x, l = t & 63, w = t >> 6;
    const int KC = K >> 5;
    const int mt0 = blockIdx.x * 8 + (w & 1) * 4;
    const int nt0 = blockIdx.y * 4 + (w >> 1) * 2;
    f32x4 acc[4][2] = {};

#pragma unroll 2
    for (int kc = 0; kc < KC; ++kc) {
        short8 ah[4], al[4], bh[2], bl[2];
#pragma unroll
        for (int i = 0; i < 4; ++i) {
            const short* ap = af + (size_t)(((mt0 + i) * KC + kc) * 2) * 512 + l * 8;
            ah[i] = *(const short8*)(ap);
            al[i] = *(const short8*)(ap + 512);
        }
#pragma unroll
        for (int j = 0; j < 2; ++j) {
            const short* bp = wf + (size_t)(((nt0 + j) * KC + kc) * 2) * 512 + l * 8;
            bh[j] = *(const short8*)(bp);
            bl[j] = *(const short8*)(bp + 512);
        }
#pragma unroll
        for (int i = 0; i < 4; ++i)
#pragma unroll
            for (int j = 0; j < 2; ++j) {
                acc[i][j] = __builtin_amdgcn_mfma_f32_16x16x32_bf16(ah[i], bh[j], acc[i][j], 0, 0, 0);
                acc[i][j] = __builtin_amdgcn_mfma_f32_16x16x32_bf16(ah[i], bl[j], acc[i][j], 0, 0, 0);
                acc[i][j] = __builtin_amdgcn_mfma_f32_16x16x32_bf16(al[i], bh[j], acc[i][j], 0, 0, 0);
            }
    }
#pragma unroll
    for (int j = 0; j < 2; ++j) {
        const int col = (nt0 + j) * 16 + (l & 15);
        const float bv = bias[col];
#pragma unroll
        for (int i = 0; i < 4; ++i) {
            const int rowb = (mt0 + i) * 16 + ((l >> 4) << 2);
#pragma unroll
            for (int r = 0; r < 4; ++r)
                C[(size_t)(rowb + r) * N + col] = acc[i][j][r] + bv;
        }
    }
}

// ---------------------------------------------------------------------------
// K fragment prep (unchanged, verified): grid (32, 64)
// ---------------------------------------------------------------------------
__global__ __launch_bounds__(256) void prep_kf(const float* __restrict__ k,
                                               short* __restrict__ kf)
{
    const int bh = blockIdx.y, b = bh >> 3, hh = bh & 7;
    const int t = threadIdx.x, l = t & 63, sub = t >> 6;
    const int kt = blockIdx.x * 2 + (sub >> 1), kc = sub & 1;
    const int key = kt * 16 + (l & 15);
    const int coff = kc * 32 + ((l >> 4) << 3);
    const float* src = k + (size_t)(b * SEQ + key) * EDIM + hh * HD + coff;
    float4 x0 = *(const float4*)(src);
    float4 x1 = *(const float4*)(src + 4);
    float xs[8] = {x0.x, x0.y, x0.z, x0.w, x1.x, x1.y, x1.z, x1.w};
    short8 hi, lo;
#pragma unroll
    for (int j = 0; j < 8; ++j) {
        unsigned short h, lw;
        split2(xs[j], h, lw);
        hi[j] = (short)h; lo[j] = (short)lw;
    }
    short* dst = kf + (size_t)(((bh * 64 + kt) * 2 + kc) * 2) * 512 + l * 8;
    *(short8*)(dst) = hi;
    *(short8*)(dst + 512) = lo;
}

// ---------------------------------------------------------------------------
// V fragment prep (unchanged, verified): grid (32, 64)
// ---------------------------------------------------------------------------
__global__ __launch_bounds__(256) void prep_vf(const float* __restrict__ v,
                                               short* __restrict__ vf)
{
    const int bh = blockIdx.y, b = bh >> 3, hh = bh & 7;
    const int t = threadIdx.x, l = t & 63, n = t >> 6;
    const int jc = blockIdx.x;
    const int c = n * 16 + (l & 15);
    const int jb = jc * 32 + ((l >> 4) << 3);
    short8 hi, lo;
#pragma unroll
    for (int jj = 0; jj < 8; ++jj) {
        float f = v[(size_t)(b * SEQ + jb + jj) * EDIM + hh * HD + c];
        unsigned short h, lw;
        split2(f, h, lw);
        hi[jj] = (short)h; lo[jj] = (short)lw;
    }
    short* dst = vf + (size_t)(((bh * 32 + jc) * 4 + n) * 2) * 512 + l * 8;
    *(short8*)(dst) = hi;
    *(short8*)(dst + 512) = lo;
}

// ---------------------------------------------------------------------------
// Fused sparse attention, 8-row WG (32 KB LDS -> 4 WG/CU).
// Scores kept as fp32 in LDS (no hi/lo split round-trip); after selection each
// wave overwrites its own rows' block IN PLACE with e as bf16 hi/lo shorts.
//
// LDS layout (per q-row r, byte block [r*4096, (r+1)*4096)):
//  - S fp32: col c -> byte ((( c>>2) ^ r) << 4) + (c&3)*4      (16B granule ^ r)
//  - e_hi  : col c -> byte ((( c>>3) ^ r) << 4) + (c&7)*2       in [0,2048)
//  - e_lo  : same + 2048                                        in [2048,4096)
// All accesses verified conflict-clean per 8-lane group.
// grid (64 bh, 128 qblk), 256 thr.
// ---------------------------------------------------------------------------
__global__ __launch_bounds__(256, 4) void attn_mfma(const float* __restrict__ Q,
                                                    const short* __restrict__ KF,
                                                    const short* __restrict__ VF,
                                                    float* __restrict__ O)
{
    __shared__ alignas(16) unsigned char Pbuf[PQ * 4096];   // 32 KB
    __shared__ float zinv[PQ];

    const int bh = blockIdx.x, b = bh >> 3, hh = bh & 7;
    const int q0 = blockIdx.y * PQ;
    const int t = threadIdx.x, l = t & 63, w = t >> 6;

    // Q A-fragments, rows duplicated (m = l&7), scale 1/8 folded in
    short8 aqh[2], aql[2];
    {
        const float* qp = Q + (size_t)(b * SEQ + q0 + (l & 7)) * EDIM + hh * HD + ((l >> 4) << 3);
#pragma unroll
        for (int kc = 0; kc < 2; ++kc) {
            float4 x0 = *(const float4*)(qp + kc * 32);
            float4 x1 = *(const float4*)(qp + kc * 32 + 4);
            float xs[8] = {x0.x, x0.y, x0.z, x0.w, x1.x, x1.y, x1.z, x1.w};
#pragma unroll
            for (int j = 0; j < 8; ++j) {
                unsigned short h, lw;
                split2(xs[j] * 0.125f, h, lw);
                aqh[kc][j] = (short)h; aql[kc][j] = (short)lw;
            }
        }
    }

    // ---- phase 1: wave w computes key tiles 16w..16w+15; fp32 S into LDS.
    // C rows duplicate real rows mod 8; lane group g (=l>>4) holds real rows
    // (4g+r)&7. Groups 0,1 store r={0,1}; groups 2,3 store r={2,3}: 2 b32/lane.
    {
        const short* kfb = KF + (size_t)bh * 64 * 2048;
        const int g = l >> 4;
        const int rowbase = (g & 1) << 2;
        const int rsel = (g >> 1) << 1;          // 0 or 2
        for (int i = 0; i < 16; ++i) {
            const int kt = (w << 4) + i;
            const short* kp = kfb + (size_t)kt * 2048 + l * 8;
            short8 b00 = *(const short8*)(kp);
            short8 b01 = *(const short8*)(kp + 512);
            short8 b10 = *(const short8*)(kp + 1024);
            short8 b11 = *(const short8*)(kp + 1536);
            f32x4 acc = {0.f, 0.f, 0.f, 0.f};
            acc = __builtin_amdgcn_mfma_f32_16x16x32_bf16(aqh[0], b00, acc, 0, 0, 0);
            acc = __builtin_amdgcn_mfma_f32_16x16x32_bf16(aqh[0], b01, acc, 0, 0, 0);
            acc = __builtin_amdgcn_mfma_f32_16x16x32_bf16(aql[0], b00, acc, 0, 0, 0);
            acc = __builtin_amdgcn_mfma_f32_16x16x32_bf16(aqh[1], b10, acc, 0, 0, 0);
            acc = __builtin_amdgcn_mfma_f32_16x16x32_bf16(aqh[1], b11, acc, 0, 0, 0);
            acc = __builtin_amdgcn_mfma_f32_16x16x32_bf16(aql[1], b10, acc, 0, 0, 0);
            const int col = (kt << 4) + (l & 15);
            const int cg = col >> 2, wi = col & 3;
#pragma unroll
            for (int j = 0; j < 2; ++j) {
                const int row = rowbase + rsel + j;
                *(float*)(Pbuf + row * 4096 + (((cg ^ row) << 4) | (wi << 2))) = acc[rsel + j];
            }
        }
    }
    __syncthreads();

    // ---- phase 2: wave w owns rows 2w, 2w+1; lane owns S granules l+64n.
    {
        const int r0 = w << 1, r1 = r0 + 1;

        unsigned u0[16], u1[16];
#pragma unroll
        for (int n = 0; n < 4; ++n) {
            float4 s0 = *(const float4*)(Pbuf + r0 * 4096 + (((l + (n << 6)) ^ r0) << 4));
            float4 s1 = *(const float4*)(Pbuf + r1 * 4096 + (((l + (n << 6)) ^ r1) << 4));
            u0[n * 4 + 0] = fmap(s0.x); u0[n * 4 + 1] = fmap(s0.y);
            u0[n * 4 + 2] = fmap(s0.z); u0[n * 4 + 3] = fmap(s0.w);
            u1[n * 4 + 0] = fmap(s1.x); u1[n * 4 + 1] = fmap(s1.y);
            u1[n * 4 + 2] = fmap(s1.z); u1[n * 4 + 3] = fmap(s1.w);
        }

        unsigned um0 = u0[0], um1 = u1[0];
#pragma unroll
        for (int i = 1; i < 16; ++i) {
            um0 = u0[i] > um0 ? u0[i] : um0;
            um1 = u1[i] > um1 ? u1[i] : um1;
        }
#pragma unroll
        for (int off = 32; off > 0; off >>= 1) {
            unsigned o0 = __shfl_xor((int)um0, off);
            unsigned o1 = __shfl_xor((int)um1, off);
            um0 = o0 > um0 ? o0 : um0;
            um1 = o1 > um1 ? o1 : um1;
        }

        // dual-row exact 256th-largest: interleaved 32-step binary search
        unsigned T0 = 0, T1 = 0;
        for (int bit = 31; bit >= 0; --bit) {
            const unsigned c0 = T0 | (1u << bit), c1 = T1 | (1u << bit);
            int n0 = 0, n1 = 0;
#pragma unroll
            for (int i = 0; i < 16; ++i) {
                n0 += (int)__popcll(__ballot(u0[i] >= c0));
                n1 += (int)__popcll(__ballot(u1[i] >= c1));
            }
            if (n0 >= KSEL) T0 = c0;
            if (n1 >= KSEL) T1 = c1;
        }

        // softmax numerators; in-place hi/lo bf16 write-back (row-local blocks)
        const float m0 = funmap(um0), m1 = funmap(um1);
        float Z0 = 0.f, Z1 = 0.f;
#pragma unroll
        for (int n = 0; n < 4; ++n) {
            const int gg = ((l + (n << 6)) >> 1);
            short4 H, L;
            {
                float e0 = (u0[n * 4 + 0] >= T0) ? __expf(funmap(u0[n * 4 + 0]) - m0) : 0.f;
                float e1 = (u0[n * 4 + 1] >= T0) ? __expf(funmap(u0[n * 4 + 1]) - m0) : 0.f;
                float e2 = (u0[n * 4 + 2] >= T0) ? __expf(funmap(u0[n * 4 + 2]) - m0) : 0.f;
                float e3 = (u0[n * 4 + 3] >= T0) ? __expf(funmap(u0[n * 4 + 3]) - m0) : 0.f;
                Z0 += (e0 + e1) + (e2 + e3);
                unsigned short h, lw;
                split2(e0, h, lw); H.x = (short)h; L.x = (short)lw;
                split2(e1, h, lw); H.y = (short)h; L.y = (short)lw;
                split2(e2, h, lw); H.z = (short)h; L.z = (short)lw;
                split2(e3, h, lw); H.w = (short)h; L.w = (short)lw;
                unsigned char* base = Pbuf + r0 * 4096 + (((gg ^ r0) << 4) | ((l & 1) << 3));
                *(short4*)(base) = H;
                *(short4*)(base + 2048) = L;
            }
            {
                float e0 = (u1[n * 4 + 0] >= T1) ? __expf(funmap(u1[n * 4 + 0]) - m1) : 0.f;
                float e1 = (u1[n * 4 + 1] >= T1) ? __expf(funmap(u1[n * 4 + 1]) - m1) : 0.f;
                float e2 = (u1[n * 4 + 2] >= T1) ? __expf(funmap(u1[n * 4 + 2]) - m1) : 0.f;
                float e3 = (u1[n * 4 + 3] >= T1) ? __expf(funmap(u1[n * 4 + 3]) - m1) : 0.f;
                Z1 += (e0 + e1) + (e2 + e3);
                unsigned short h, lw;
                split2(e0, h, lw); H.x = (short)h; L.x = (short)lw;
                split2(e1, h, lw); H.y = (short)h; L.y = (short)lw;
                split2(e2, h, lw); H.z = (short)h; L.z = (short)lw;
                split2(e3, h, lw); H.w = (short)h; L.w = (short)lw;
                unsigned char* base = Pbuf + r1 * 4096 + (((gg ^ r1) << 4) | ((l & 1) << 3));
                *(short4*)(base) = H;
                *(short4*)(base + 2048) = L;
            }
        }

#pragma unroll
        for (int off = 32; off > 0; off >>= 1) {
            Z0 += __shfl_xor(Z0, off);
            Z1 += __shfl_xor(Z1, off);
        }
        if (l == 0) { zinv[r0] = 1.0f / Z0; zinv[r1] = 1.0f / Z1; }
    }
    __syncthreads();

    // ---- phase 3: wave w owns channel tile w; A rows duplicated (m = l&7).
    // A-frag read: e_hi[m][32jc+8g..+7] = 16B granule (4jc+g)^m  -> distinct
    // bank quads across m (conflict-free); lanes 8-15 broadcast lanes 0-7.
    {
        f32x4 oacc = {0.f, 0.f, 0.f, 0.f};
        const short* vfb = VF + (size_t)bh * 32 * 4096 + (size_t)w * 1024;
        const int m = l & 7, g3 = l >> 4;
        for (int jc = 0; jc < 32; ++jc) {
            const int gg = (jc << 2) + g3;
            const unsigned char* abase = Pbuf + m * 4096 + (((gg ^ m)) << 4);
            short8 ph = *(const short8*)(abase);
            short8 pl = *(const short8*)(abase + 2048);
            const short* vp = vfb + (size_t)jc * 4096 + l * 8;
            short8 vh = *(const short8*)(vp);
            short8 vl = *(const short8*)(vp + 512);
            oacc = __builtin_amdgcn_mfma_f32_16x16x32_bf16(ph, vh, oacc, 0, 0, 0);
            oacc = __builtin_amdgcn_mfma_f32_16x16x32_bf16(ph, vl, oacc, 0, 0, 0);
            oacc = __builtin_amdgcn_mfma_f32_16x16x32_bf16(pl, vh, oacc, 0, 0, 0);
        }
        if (l < 32) {
            const int c = (w << 4) + (l & 15);
            const int rb = (l >> 4) << 2;
#pragma unroll
            for (int r = 0; r < 4; ++r)
                O[(size_t)(b * SEQ + q0 + rb + r) * EDIM + hh * HD + c] =
                    oacc[r] * zinv[rb + r];
        }
    }
}

// ---------------------------------------------------------------------------
__global__ __launch_bounds__(256) void mean_fc(const float* __restrict__ Hf,
                                               const float* __restrict__ fcw,
                                               const float* __restrict__ fcb,
                                               float* __restrict__ out)
{
    __shared__ float hm[EDIM];
    const int b = blockIdx.x, t = threadIdx.x;
    const float* hb = Hf + (size_t)b * SEQ * EDIM;
    float s0 = 0.f, s1 = 0.f;
    for (int s = 0; s < SEQ; ++s) {
        s0 += hb[(size_t)s * EDIM + t];
        s1 += hb[(size_t)s * EDIM + t + 256];
    }
    hm[t] = s0 * (1.0f / SEQ);
    hm[t + 256] = s1 * (1.0f / SEQ);
    __syncthreads();
    if (t < 10) {
        float acc = fcb[t];
        for (int e = 0; e < EDIM; ++e) acc += hm[e] * fcw[e * 10 + t];
        out[b * 10 + t] = acc;
    }
}

// ---------------------------------------------------------------------------
extern "C" void kernel_launch(void* const* d_in, const int* in_sizes, int n_in,
                              void* d_out, int out_size, void* d_ws, size_t ws_size,
                              hipStream_t stream)
{
    const float* x     = (const float*)d_in[0];
    const float* emb_w = (const float*)d_in[1];
    const float* emb_b = (const float*)d_in[2];
    const float* Wq    = (const float*)d_in[3];
    const float* Wk    = (const float*)d_in[4];
    const float* Wv    = (const float*)d_in[5];
    const float* Wo    = (const float*)d_in[6];
    const float* bq    = (const float*)d_in[7];
    const float* bk    = (const float*)d_in[8];
    const float* bv    = (const float*)d_in[9];
    const float* bo    = (const float*)d_in[10];
    const float* fcw   = (const float*)d_in[11];
    const float* fcb   = (const float*)d_in[12];
    float* out = (float*)d_out;
    float* ws  = (float*)d_ws;

    const size_t SZ = (size_t)BATCH * SEQ * EDIM;   // 4,194,304 floats = 16 MiB
    float* h  = ws;                                  // S0
    float* q  = ws + SZ;                             // S1
    float* ko = ws + 2 * SZ;                         // S2: k, then attn out o
    float* v  = ws + 3 * SZ;                         // S3
    short* kf = (short*)(ws + 4 * SZ);               // S4 (16 MiB)
    short* vf = (short*)(ws + 5 * SZ);               // S5 (16 MiB)
    short* af = (short*)(ws + 6 * SZ);               // S6: xf / hf / of (16 MiB)
    short* wf = (short*)(ws + 7 * SZ);               // S7: 4x524288 + emb frags
    short* wfe = wf + 4 * 524288;

    const int M = BATCH * SEQ;                       // 8192
    const dim3 gG(M / 128, EDIM / 64);               // (64, 8) = 512 blocks
    const dim3 gP(32, BATCH * NH);                   // (32, 64)
    const dim3 gA(BATCH * NH, SEQ / PQ);             // (64, 128)
    const dim3 gW4(4, 32, 4);
    const dim3 gCA(4, M / 16);                       // K=512 A-convert
    const dim3 gCAx(1, M / 16);                      // K=128 A-convert

    conv_w1<<<dim3(1, 32), 256, 0, stream>>>(emb_w, wfe, 128, EDIM);
    conv_a<<<gCAx, 256, 0, stream>>>(x, af, 128);
    gemm_mfma<<<gG, 256, 0, stream>>>(af, wfe, emb_b, h, M, EDIM, 128);

    for (int l = 0; l < NLAYER; ++l) {
        conv_w4<<<gW4, 256, 0, stream>>>(Wq, Wk, Wv, Wo, l, wf);
        conv_a<<<gCA, 256, 0, stream>>>(h, af, EDIM);
        gemm_mfma<<<gG, 256, 0, stream>>>(af, wf,              bq + l * EDIM, q,  M, EDIM, EDIM);
        gemm_mfma<<<gG, 256, 0, stream>>>(af, wf + 1 * 524288, bk + l * EDIM, ko, M, EDIM, EDIM);
        gemm_mfma<<<gG, 256, 0, stream>>>(af, wf + 2 * 524288, bv + l * EDIM, v,  M, EDIM, EDIM);
        prep_kf<<<gP, 256, 0, stream>>>(ko, kf);
        prep_vf<<<gP, 256, 0, stream>>>(v, vf);
        attn_mfma<<<gA, 256, 0, stream>>>(q, kf, vf, ko);     // o -> S2 (k dead)
        conv_a<<<gCA, 256, 0, stream>>>(ko, af, EDIM);        // hf dead -> reuse S6
        gemm_mfma<<<gG, 256, 0, stream>>>(af, wf + 3 * 524288, bo + l * EDIM, h, M, EDIM, EDIM);
    }
    mean_fc<<<8, 256, 0, stream>>>(h, fcw, fcb, out);
}

// Round 5
// 1273.082 us; speedup vs baseline: 2.9810x; 1.0551x over previous
//
#include <hip/hip_runtime.h>

#define EDIM 512
#define NH 8
#define HD 64
#define SEQ 1024
#define BATCH 8
#define NLAYER 4
#define KSEL 256
#define PQ 8

typedef __attribute__((ext_vector_type(8))) short short8;
typedef __attribute__((ext_vector_type(4))) float f32x4;

// ---- split-bf16 helpers: f ~= hi + lo, |err| ~ 2^-17 |f| ---------------
__device__ __forceinline__ unsigned short bf16_rne(float f) {
    unsigned u = __float_as_uint(f);
    return (unsigned short)((u + 0x7FFFu + ((u >> 16) & 1u)) >> 16);
}
__device__ __forceinline__ float bf16_tof(unsigned short h) {
    return __uint_as_float(((unsigned)h) << 16);
}
__device__ __forceinline__ void split2(float f, unsigned short& hi, unsigned short& lo) {
    hi = bf16_rne(f);
    float r = f - bf16_tof(hi);
    lo = (unsigned short)(__float_as_uint(r) >> 16);
}
__device__ __forceinline__ unsigned fmap(float s) {
    int fi = __float_as_int(s);
    return (unsigned)(fi ^ ((fi >> 31) | 0x80000000));
}
__device__ __forceinline__ float funmap(unsigned u) {
    int fi = (u & 0x80000000u) ? (int)(u ^ 0x80000000u) : (int)~u;
    return __int_as_float(fi);
}

// ---------------------------------------------------------------------------
// A-fragment convert: fp32 A[M,K] -> af shorts, layout
// ((mt*KC + kc)*2 + p)*512 + l*8 ; lane holds A[m=16mt+(l&15)][k=32kc+8(l>>4)+j]
// grid ((K/32)/4 or 1, M/16)
// ---------------------------------------------------------------------------
__global__ __launch_bounds__(256) void conv_a(const float* __restrict__ A,
                                              short* __restrict__ af, int K)
{
    const int t = threadIdx.x, l = t & 63;
    const int KC = K >> 5;
    const int kc = blockIdx.x * 4 + (t >> 6);
    const int mt = blockIdx.y;
    const int m = mt * 16 + (l & 15);
    const int kb = kc * 32 + ((l >> 4) << 3);
    float4 x0 = *(const float4*)(A + (size_t)m * K + kb);
    float4 x1 = *(const float4*)(A + (size_t)m * K + kb + 4);
    float xs[8] = {x0.x, x0.y, x0.z, x0.w, x1.x, x1.y, x1.z, x1.w};
    short8 hi, lo;
#pragma unroll
    for (int j = 0; j < 8; ++j) {
        unsigned short h, lw;
        split2(xs[j], h, lw);
        hi[j] = (short)h; lo[j] = (short)lw;
    }
    short* dst = af + (size_t)((mt * KC + kc) * 2) * 512 + l * 8;
    *(short8*)(dst) = hi;
    *(short8*)(dst + 512) = lo;
}

// ---------------------------------------------------------------------------
// ALL-layer weight convert (once per call): z = layer*4 + mat (mat: q,k,v,o).
// layout per matrix ((nt*16 + kc)*2 + p)*512 + l*8. grid (4, 32, 16).
// ---------------------------------------------------------------------------
__global__ __launch_bounds__(256) void conv_wall(const float* __restrict__ Wq,
                                                 const float* __restrict__ Wk,
                                                 const float* __restrict__ Wv,
                                                 const float* __restrict__ Wo,
                                                 short* __restrict__ wf)
{
    const int z = blockIdx.z;
    const int layer = z >> 2, mm = z & 3;
    const float* W = (mm == 0 ? Wq : mm == 1 ? Wk : mm == 2 ? Wv : Wo)
                     + (size_t)layer * EDIM * EDIM;
    const int t = threadIdx.x, l = t & 63;
    const int kc = blockIdx.x * 4 + (t >> 6);
    const int nt = blockIdx.y;
    const int n = nt * 16 + (l & 15);
    const int kb = kc * 32 + ((l >> 4) << 3);
    short8 hi, lo;
#pragma unroll
    for (int j = 0; j < 8; ++j) {
        unsigned short h, lw;
        split2(W[(size_t)(kb + j) * EDIM + n], h, lw);
        hi[j] = (short)h; lo[j] = (short)lw;
    }
    short* dst = wf + (size_t)z * 524288 + (size_t)((nt * 16 + kc) * 2) * 512 + l * 8;
    *(short8*)(dst) = hi;
    *(short8*)(dst + 512) = lo;
}

// single matrix variant (emb_w, K=128): grid (1, 32)
__global__ __launch_bounds__(256) void conv_w1(const float* __restrict__ W,
                                               short* __restrict__ wf, int K, int N)
{
    const int t = threadIdx.x, l = t & 63;
    const int KC = K >> 5;
    const int kc = blockIdx.x * 4 + (t >> 6);
    const int nt = blockIdx.y;
    const int n = nt * 16 + (l & 15);
    const int kb = kc * 32 + ((l >> 4) << 3);
    short8 hi, lo;
#pragma unroll
    for (int j = 0; j < 8; ++j) {
        unsigned short h, lw;
        split2(W[(size_t)(kb + j) * N + n], h, lw);
        hi[j] = (short)h; lo[j] = (short)lw;
    }
    short* dst = wf + (size_t)((nt * KC + kc) * 2) * 512 + l * 8;
    *(short8*)(dst) = hi;
    *(short8*)(dst + 512) = lo;
}

// ---------------------------------------------------------------------------
// Split-bf16 MFMA GEMM: C[M,N] = A@W + bias. Tile 128x64, grid (M/128, N/64).
// Wave w: m-half w&1 (4 mt), n-half w>>1 (2 nt). 2 WG/CU.
// ---------------------------------------------------------------------------
__global__ __launch_bounds__(256) void gemm_mfma(const short* __restrict__ af,
                                                 const short* __restrict__ wf,
                                                 const float* __restrict__ bias,
                                                 float* __restrict__ C,
                                                 int M, int N, int K)
{
    const int t = threadIdx.x, l = t & 63, w = t >> 6;
    const int KC = K >> 5;
    const int mt0 = blockIdx.x * 8 + (w & 1) * 4;
    const int nt0 = blockIdx.y * 4 + (w >> 1) * 2;
    f32x4 acc[4][2] = {};

#pragma unroll 2
    for (int kc = 0; kc < KC; ++kc) {
        short8 ah[4], al[4], bh[2], bl[2];
#pragma unroll
        for (int i = 0; i < 4; ++i) {
            const short* ap = af + (size_t)(((mt0 + i) * KC + kc) * 2) * 512 + l * 8;
            ah[i] = *(const short8*)(ap);
            al[i] = *(const short8*)(ap + 512);
        }
#pragma unroll
        for (int j = 0; j < 2; ++j) {
            const short* bp = wf + (size_t)(((nt0 + j) * KC + kc) * 2) * 512 + l * 8;
            bh[j] = *(const short8*)(bp);
            bl[j] = *(const short8*)(bp + 512);
        }
#pragma unroll
        for (int i = 0; i < 4; ++i)
#pragma unroll
            for (int j = 0; j < 2; ++j) {
                acc[i][j] = __builtin_amdgcn_mfma_f32_16x16x32_bf16(ah[i], bh[j], acc[i][j], 0, 0, 0);
                acc[i][j] = __builtin_amdgcn_mfma_f32_16x16x32_bf16(ah[i], bl[j], acc[i][j], 0, 0, 0);
                acc[i][j] = __builtin_amdgcn_mfma_f32_16x16x32_bf16(al[i], bh[j], acc[i][j], 0, 0, 0);
            }
    }
#pragma unroll
    for (int j = 0; j < 2; ++j) {
        const int col = (nt0 + j) * 16 + (l & 15);
        const float bv = bias[col];
#pragma unroll
        for (int i = 0; i < 4; ++i) {
            const int rowb = (mt0 + i) * 16 + ((l >> 4) << 2);
#pragma unroll
            for (int r = 0; r < 4; ++r)
                C[(size_t)(rowb + r) * N + col] = acc[i][j][r] + bv;
        }
    }
}

// ---------------------------------------------------------------------------
// Fused Q/K/V projection: one dispatch, grid (64, 24); y: mat = y>>3, bny = y&7.
// wfl = layer's weight frags (q,k,v contiguous, 524288 apart).
// ---------------------------------------------------------------------------
__global__ __launch_bounds__(256) void gemm_qkv(const short* __restrict__ af,
                                                const short* __restrict__ wfl,
                                                const float* __restrict__ bq,
                                                const float* __restrict__ bk,
                                                const float* __restrict__ bv,
                                                float* __restrict__ Cq,
                                                float* __restrict__ Ck,
                                                float* __restrict__ Cv)
{
    const int mat = blockIdx.y >> 3, bny = blockIdx.y & 7;
    const short* wf = wfl + (size_t)mat * 524288;
    const float* bias = mat == 0 ? bq : mat == 1 ? bk : bv;
    float* C = mat == 0 ? Cq : mat == 1 ? Ck : Cv;
    const int t = threadIdx.x, l = t & 63, w = t >> 6;
    const int KC = EDIM >> 5;
    const int mt0 = blockIdx.x * 8 + (w & 1) * 4;
    const int nt0 = bny * 4 + (w >> 1) * 2;
    f32x4 acc[4][2] = {};

#pragma unroll 2
    for (int kc = 0; kc < KC; ++kc) {
        short8 ah[4], al[4], bh[2], bl[2];
#pragma unroll
        for (int i = 0; i < 4; ++i) {
            const short* ap = af + (size_t)(((mt0 + i) * KC + kc) * 2) * 512 + l * 8;
            ah[i] = *(const short8*)(ap);
            al[i] = *(const short8*)(ap + 512);
        }
#pragma unroll
        for (int j = 0; j < 2; ++j) {
            const short* bp = wf + (size_t)(((nt0 + j) * KC + kc) * 2) * 512 + l * 8;
            bh[j] = *(const short8*)(bp);
            bl[j] = *(const short8*)(bp + 512);
        }
#pragma unroll
        for (int i = 0; i < 4; ++i)
#pragma unroll
            for (int j = 0; j < 2; ++j) {
                acc[i][j] = __builtin_amdgcn_mfma_f32_16x16x32_bf16(ah[i], bh[j], acc[i][j], 0, 0, 0);
                acc[i][j] = __builtin_amdgcn_mfma_f32_16x16x32_bf16(ah[i], bl[j], acc[i][j], 0, 0, 0);
                acc[i][j] = __builtin_amdgcn_mfma_f32_16x16x32_bf16(al[i], bh[j], acc[i][j], 0, 0, 0);
            }
    }
#pragma unroll
    for (int j = 0; j < 2; ++j) {
        const int col = (nt0 + j) * 16 + (l & 15);
        const float bv2 = bias[col];
#pragma unroll
        for (int i = 0; i < 4; ++i) {
            const int rowb = (mt0 + i) * 16 + ((l >> 4) << 2);
#pragma unroll
            for (int r = 0; r < 4; ++r)
                C[(size_t)(rowb + r) * EDIM + col] = acc[i][j][r] + bv2;
        }
    }
}

// ---------------------------------------------------------------------------
// K+V fragment prep, merged: grid (32, 64, 2). z=0: kf, z=1: vf. (bodies
// identical to the verified prep_kf / prep_vf.)
// ---------------------------------------------------------------------------
__global__ __launch_bounds__(256) void prep_kv(const float* __restrict__ k,
                                               const float* __restrict__ v,
                                               short* __restrict__ kf,
                                               short* __restrict__ vf)
{
    const int bh = blockIdx.y, b = bh >> 3, hh = bh & 7;
    const int t = threadIdx.x, l = t & 63;
    if (blockIdx.z == 0) {
        const int sub = t >> 6;
        const int kt = blockIdx.x * 2 + (sub >> 1), kc = sub & 1;
        const int key = kt * 16 + (l & 15);
        const int coff = kc * 32 + ((l >> 4) << 3);
        const float* src = k + (size_t)(b * SEQ + key) * EDIM + hh * HD + coff;
        float4 x0 = *(const float4*)(src);
        float4 x1 = *(const float4*)(src + 4);
        float xs[8] = {x0.x, x0.y, x0.z, x0.w, x1.x, x1.y, x1.z, x1.w};
        short8 hi, lo;
#pragma unroll
        for (int j = 0; j < 8; ++j) {
            unsigned short h, lw;
            split2(xs[j], h, lw);
            hi[j] = (short)h; lo[j] = (short)lw;
        }
        short* dst = kf + (size_t)(((bh * 64 + kt) * 2 + kc) * 2) * 512 + l * 8;
        *(short8*)(dst) = hi;
        *(short8*)(dst + 512) = lo;
    } else {
        const int n = t >> 6;
        const int jc = blockIdx.x;
        const int c = n * 16 + (l & 15);
        const int jb = jc * 32 + ((l >> 4) << 3);
        short8 hi, lo;
#pragma unroll
        for (int jj = 0; jj < 8; ++jj) {
            float f = v[(size_t)(b * SEQ + jb + jj) * EDIM + hh * HD + c];
            unsigned short h, lw;
            split2(f, h, lw);
            hi[jj] = (short)h; lo[jj] = (short)lw;
        }
        short* dst = vf + (size_t)(((bh * 32 + jc) * 4 + n) * 2) * 512 + l * 8;
        *(short8*)(dst) = hi;
        *(short8*)(dst + 512) = lo;
    }
}

// ---------------------------------------------------------------------------
// Fused sparse attention, 8-row WG (32 KB LDS -> 4 WG/CU), fp32 S in LDS,
// in-place e hi/lo write-back, and the EARLY-EXIT exact top-256 search:
//  - skip trial if trial > row max (count provably 0)   [scalar, uniform]
//  - stop when count == 256 exactly: the mask {u >= trial} IS the top-256 set
//    (its min is the 256th largest), identical to the reference's
//    scores >= thresh mask. Ties never hit 256 exactly -> full search, which
//    returns the largest T with count >= 256 == reference semantics.
// grid (64 bh, 128 qblk), 256 thr.
// ---------------------------------------------------------------------------
__global__ __launch_bounds__(256, 4) void attn_mfma(const float* __restrict__ Q,
                                                    const short* __restrict__ KF,
                                                    const short* __restrict__ VF,
                                                    float* __restrict__ O)
{
    __shared__ alignas(16) unsigned char Pbuf[PQ * 4096];   // 32 KB
    __shared__ float zinv[PQ];

    const int bh = blockIdx.x, b = bh >> 3, hh = bh & 7;
    const int q0 = blockIdx.y * PQ;
    const int t = threadIdx.x, l = t & 63, w = t >> 6;

    // Q A-fragments, rows duplicated (m = l&7), scale 1/8 folded in
    short8 aqh[2], aql[2];
    {
        const float* qp = Q + (size_t)(b * SEQ + q0 + (l & 7)) * EDIM + hh * HD + ((l >> 4) << 3);
#pragma unroll
        for (int kc = 0; kc < 2; ++kc) {
            float4 x0 = *(const float4*)(qp + kc * 32);
            float4 x1 = *(const float4*)(qp + kc * 32 + 4);
            float xs[8] = {x0.x, x0.y, x0.z, x0.w, x1.x, x1.y, x1.z, x1.w};
#pragma unroll
            for (int j = 0; j < 8; ++j) {
                unsigned short h, lw;
                split2(xs[j] * 0.125f, h, lw);
                aqh[kc][j] = (short)h; aql[kc][j] = (short)lw;
            }
        }
    }

    // ---- phase 1: wave w computes key tiles 16w..16w+15; fp32 S into LDS.
    {
        const short* kfb = KF + (size_t)bh * 64 * 2048;
        const int g = l >> 4;
        const int rowbase = (g & 1) << 2;
        const int rsel = (g >> 1) << 1;          // 0 or 2
        for (int i = 0; i < 16; ++i) {
            const int kt = (w << 4) + i;
            const short* kp = kfb + (size_t)kt * 2048 + l * 8;
            short8 b00 = *(const short8*)(kp);
            short8 b01 = *(const short8*)(kp + 512);
            short8 b10 = *(const short8*)(kp + 1024);
            short8 b11 = *(const short8*)(kp + 1536);
            f32x4 acc = {0.f, 0.f, 0.f, 0.f};
            acc = __builtin_amdgcn_mfma_f32_16x16x32_bf16(aqh[0], b00, acc, 0, 0, 0);
            acc = __builtin_amdgcn_mfma_f32_16x16x32_bf16(aqh[0], b01, acc, 0, 0, 0);
            acc = __builtin_amdgcn_mfma_f32_16x16x32_bf16(aql[0], b00, acc, 0, 0, 0);
            acc = __builtin_amdgcn_mfma_f32_16x16x32_bf16(aqh[1], b10, acc, 0, 0, 0);
            acc = __builtin_amdgcn_mfma_f32_16x16x32_bf16(aqh[1], b11, acc, 0, 0, 0);
            acc = __builtin_amdgcn_mfma_f32_16x16x32_bf16(aql[1], b10, acc, 0, 0, 0);
            const int col = (kt << 4) + (l & 15);
            const int cg = col >> 2, wi = col & 3;
#pragma unroll
            for (int j = 0; j < 2; ++j) {
                const int row = rowbase + rsel + j;
                *(float*)(Pbuf + row * 4096 + (((cg ^ row) << 4) | (wi << 2))) = acc[rsel + j];
            }
        }
    }
    __syncthreads();

    // ---- phase 2: wave w owns rows 2w, 2w+1; lane owns S granules l+64n.
    {
        const int r0 = w << 1, r1 = r0 + 1;

        unsigned u0[16], u1[16];
#pragma unroll
        for (int n = 0; n < 4; ++n) {
            float4 s0 = *(const float4*)(Pbuf + r0 * 4096 + (((l + (n << 6)) ^ r0) << 4));
            float4 s1 = *(const float4*)(Pbuf + r1 * 4096 + (((l + (n << 6)) ^ r1) << 4));
            u0[n * 4 + 0] = fmap(s0.x); u0[n * 4 + 1] = fmap(s0.y);
            u0[n * 4 + 2] = fmap(s0.z); u0[n * 4 + 3] = fmap(s0.w);
            u1[n * 4 + 0] = fmap(s1.x); u1[n * 4 + 1] = fmap(s1.y);
            u1[n * 4 + 2] = fmap(s1.z); u1[n * 4 + 3] = fmap(s1.w);
        }

        unsigned um0 = u0[0], um1 = u1[0];
#pragma unroll
        for (int i = 1; i < 16; ++i) {
            um0 = u0[i] > um0 ? u0[i] : um0;
            um1 = u1[i] > um1 ? u1[i] : um1;
        }
#pragma unroll
        for (int off = 32; off > 0; off >>= 1) {
            unsigned o0 = __shfl_xor((int)um0, off);
            unsigned o1 = __shfl_xor((int)um1, off);
            um0 = o0 > um0 ? o0 : um0;
            um1 = o1 > um1 ? o1 : um1;
        }

        // dual-row exact 256th-largest with max-skip + exact-count early exit
        unsigned T0 = 0, T1 = 0;
        bool d0 = false, d1 = false;
        for (int bit = 31; bit >= 0; --bit) {
            const unsigned msk = 1u << bit;
            if (!d0) {
                const unsigned c0 = T0 | msk;
                if (c0 <= um0) {
                    int n0 = 0;
#pragma unroll
                    for (int i = 0; i < 16; ++i)
                        n0 += (int)__popcll(__ballot(u0[i] >= c0));
                    if (n0 >= KSEL) { T0 = c0; d0 = (n0 == KSEL); }
                }
            }
            if (!d1) {
                const unsigned c1 = T1 | msk;
                if (c1 <= um1) {
                    int n1 = 0;
#pragma unroll
                    for (int i = 0; i < 16; ++i)
                        n1 += (int)__popcll(__ballot(u1[i] >= c1));
                    if (n1 >= KSEL) { T1 = c1; d1 = (n1 == KSEL); }
                }
            }
            if (d0 & d1) break;
        }

        // softmax numerators; in-place hi/lo bf16 write-back (row-local blocks)
        const float m0 = funmap(um0), m1 = funmap(um1);
        float Z0 = 0.f, Z1 = 0.f;
#pragma unroll
        for (int n = 0; n < 4; ++n) {
            const int gg = ((l + (n << 6)) >> 1);
            short4 H, L;
            {
                float e0 = (u0[n * 4 + 0] >= T0) ? __expf(funmap(u0[n * 4 + 0]) - m0) : 0.f;
                float e1 = (u0[n * 4 + 1] >= T0) ? __expf(funmap(u0[n * 4 + 1]) - m0) : 0.f;
                float e2 = (u0[n * 4 + 2] >= T0) ? __expf(funmap(u0[n * 4 + 2]) - m0) : 0.f;
                float e3 = (u0[n * 4 + 3] >= T0) ? __expf(funmap(u0[n * 4 + 3]) - m0) : 0.f;
                Z0 += (e0 + e1) + (e2 + e3);
                unsigned short h, lw;
                split2(e0, h, lw); H.x = (short)h; L.x = (short)lw;
                split2(e1, h, lw); H.y = (short)h; L.y = (short)lw;
                split2(e2, h, lw); H.z = (short)h; L.z = (short)lw;
                split2(e3, h, lw); H.w = (short)h; L.w = (short)lw;
                unsigned char* base = Pbuf + r0 * 4096 + (((gg ^ r0) << 4) | ((l & 1) << 3));
                *(short4*)(base) = H;
                *(short4*)(base + 2048) = L;
            }
            {
                float e0 = (u1[n * 4 + 0] >= T1) ? __expf(funmap(u1[n * 4 + 0]) - m1) : 0.f;
                float e1 = (u1[n * 4 + 1] >= T1) ? __expf(funmap(u1[n * 4 + 1]) - m1) : 0.f;
                float e2 = (u1[n * 4 + 2] >= T1) ? __expf(funmap(u1[n * 4 + 2]) - m1) : 0.f;
                float e3 = (u1[n * 4 + 3] >= T1) ? __expf(funmap(u1[n * 4 + 3]) - m1) : 0.f;
                Z1 += (e0 + e1) + (e2 + e3);
                unsigned short h, lw;
                split2(e0, h, lw); H.x = (short)h; L.x = (short)lw;
                split2(e1, h, lw); H.y = (short)h; L.y = (short)lw;
                split2(e2, h, lw); H.z = (short)h; L.z = (short)lw;
                split2(e3, h, lw); H.w = (short)h; L.w = (short)lw;
                unsigned char* base = Pbuf + r1 * 4096 + (((gg ^ r1) << 4) | ((l & 1) << 3));
                *(short4*)(base) = H;
                *(short4*)(base + 2048) = L;
            }
        }

#pragma unroll
        for (int off = 32; off > 0; off >>= 1) {
            Z0 += __shfl_xor(Z0, off);
            Z1 += __shfl_xor(Z1, off);
        }
        if (l == 0) { zinv[r0] = 1.0f / Z0; zinv[r1] = 1.0f / Z1; }
    }
    __syncthreads();

    // ---- phase 3: wave w owns channel tile w; A rows duplicated (m = l&7).
    {
        f32x4 oacc = {0.f, 0.f, 0.f, 0.f};
        const short* vfb = VF + (size_t)bh * 32 * 4096 + (size_t)w * 1024;
        const int m = l & 7, g3 = l >> 4;
        for (int jc = 0; jc < 32; ++jc) {
            const int gg = (jc << 2) + g3;
            const unsigned char* abase = Pbuf + m * 4096 + (((gg ^ m)) << 4);
            short8 ph = *(const short8*)(abase);
            short8 pl = *(const short8*)(abase + 2048);
            const short* vp = vfb + (size_t)jc * 4096 + l * 8;
            short8 vh = *(const short8*)(vp);
            short8 vl = *(const short8*)(vp + 512);
            oacc = __builtin_amdgcn_mfma_f32_16x16x32_bf16(ph, vh, oacc, 0, 0, 0);
            oacc = __builtin_amdgcn_mfma_f32_16x16x32_bf16(ph, vl, oacc, 0, 0, 0);
            oacc = __builtin_amdgcn_mfma_f32_16x16x32_bf16(pl, vh, oacc, 0, 0, 0);
        }
        if (l < 32) {
            const int c = (w << 4) + (l & 15);
            const int rb = (l >> 4) << 2;
#pragma unroll
            for (int r = 0; r < 4; ++r)
                O[(size_t)(b * SEQ + q0 + rb + r) * EDIM + hh * HD + c] =
                    oacc[r] * zinv[rb + r];
        }
    }
}

// ---------------------------------------------------------------------------
__global__ __launch_bounds__(256) void mean_fc(const float* __restrict__ Hf,
                                               const float* __restrict__ fcw,
                                               const float* __restrict__ fcb,
                                               float* __restrict__ out)
{
    __shared__ float hm[EDIM];
    const int b = blockIdx.x, t = threadIdx.x;
    const float* hb = Hf + (size_t)b * SEQ * EDIM;
    float s0 = 0.f, s1 = 0.f;
    for (int s = 0; s < SEQ; ++s) {
        s0 += hb[(size_t)s * EDIM + t];
        s1 += hb[(size_t)s * EDIM + t + 256];
    }
    hm[t] = s0 * (1.0f / SEQ);
    hm[t + 256] = s1 * (1.0f / SEQ);
    __syncthreads();
    if (t < 10) {
        float acc = fcb[t];
        for (int e = 0; e < EDIM; ++e) acc += hm[e] * fcw[e * 10 + t];
        out[b * 10 + t] = acc;
    }
}

// ---------------------------------------------------------------------------
extern "C" void kernel_launch(void* const* d_in, const int* in_sizes, int n_in,
                              void* d_out, int out_size, void* d_ws, size_t ws_size,
                              hipStream_t stream)
{
    const float* x     = (const float*)d_in[0];
    const float* emb_w = (const float*)d_in[1];
    const float* emb_b = (const float*)d_in[2];
    const float* Wq    = (const float*)d_in[3];
    const float* Wk    = (const float*)d_in[4];
    const float* Wv    = (const float*)d_in[5];
    const float* Wo    = (const float*)d_in[6];
    const float* bq    = (const float*)d_in[7];
    const float* bk    = (const float*)d_in[8];
    const float* bv    = (const float*)d_in[9];
    const float* bo    = (const float*)d_in[10];
    const float* fcw   = (const float*)d_in[11];
    const float* fcb   = (const float*)d_in[12];
    float* out = (float*)d_out;
    float* ws  = (float*)d_ws;

    const size_t SZ = (size_t)BATCH * SEQ * EDIM;   // 4,194,304 floats = 16 MiB
    float* h  = ws;                                  // S0
    float* q  = ws + SZ;                             // S1
    float* ko = ws + 2 * SZ;                         // S2: k, then attn out o
    float* v  = ws + 3 * SZ;                         // S3
    short* kf = (short*)(ws + 4 * SZ);               // S4 (16 MiB)
    short* vf = (short*)(ws + 5 * SZ);               // S5 (16 MiB)
    short* af = (short*)(ws + 6 * SZ);               // S6: xf / hf / of (16 MiB)
    short* wf = (short*)(ws + 7 * SZ);               // S7: 16 x 524288 shorts (16 MiB)
    // emb weight frags live in the unused tail of af during the embed GEMM
    // (x-conversion only occupies the first 2,097,152 shorts of af).
    short* wfe = af + 4 * 1024 * 1024;               // 256 KB region, disjoint from xf

    const int M = BATCH * SEQ;                       // 8192
    const dim3 gG(M / 128, EDIM / 64);               // (64, 8) = 512 blocks
    const dim3 gQKV(M / 128, 3 * EDIM / 64);         // (64, 24)
    const dim3 gP(32, BATCH * NH, 2);                // merged K/V prep
    const dim3 gA(BATCH * NH, SEQ / PQ);             // (64, 128)
    const dim3 gCA(4, M / 16);                       // K=512 A-convert
    const dim3 gCAx(1, M / 16);                      // K=128 A-convert

    conv_wall<<<dim3(4, 32, 16), 256, 0, stream>>>(Wq, Wk, Wv, Wo, wf);
    conv_w1<<<dim3(1, 32), 256, 0, stream>>>(emb_w, wfe, 128, EDIM);
    conv_a<<<gCAx, 256, 0, stream>>>(x, af, 128);
    gemm_mfma<<<gG, 256, 0, stream>>>(af, wfe, emb_b, h, M, EDIM, 128);

    for (int l = 0; l < NLAYER; ++l) {
        const short* wfl = wf + (size_t)(4 * l) * 524288;
        conv_a<<<gCA, 256, 0, stream>>>(h, af, EDIM);
        gemm_qkv<<<gQKV, 256, 0, stream>>>(af, wfl, bq + l * EDIM, bk + l * EDIM,
                                           bv + l * EDIM, q, ko, v);
        prep_kv<<<gP, 256, 0, stream>>>(ko, v, kf, vf);
        attn_mfma<<<gA, 256, 0, stream>>>(q, kf, vf, ko);     // o -> S2 (k dead)
        conv_a<<<gCA, 256, 0, stream>>>(ko, af, EDIM);        // hf dead -> reuse S6
        gemm_mfma<<<gG, 256, 0, stream>>>(af, wfl + 3 * 524288, bo + l * EDIM, h, M, EDIM, EDIM);
    }
    mean_fc<<<8, 256, 0, stream>>>(h, fcw, fcb, out);
}

// Round 6
// 1245.991 us; speedup vs baseline: 3.0458x; 1.0217x over previous
//
#include <hip/hip_runtime.h>

#define EDIM 512
#define NH 8
#define HD 64
#define SEQ 1024
#define BATCH 8
#define NLAYER 4
#define KSEL 256
#define PQ 8

typedef __attribute__((ext_vector_type(8))) short short8;
typedef __attribute__((ext_vector_type(4))) float f32x4;

// ---- split-bf16 helpers: f ~= hi + lo, |err| ~ 2^-17 |f| ---------------
__device__ __forceinline__ unsigned short bf16_rne(float f) {
    unsigned u = __float_as_uint(f);
    return (unsigned short)((u + 0x7FFFu + ((u >> 16) & 1u)) >> 16);
}
__device__ __forceinline__ float bf16_tof(unsigned short h) {
    return __uint_as_float(((unsigned)h) << 16);
}
__device__ __forceinline__ void split2(float f, unsigned short& hi, unsigned short& lo) {
    hi = bf16_rne(f);
    float r = f - bf16_tof(hi);
    lo = (unsigned short)(__float_as_uint(r) >> 16);
}
__device__ __forceinline__ void split8(const float* xs, short8& hi, short8& lo) {
#pragma unroll
    for (int j = 0; j < 8; ++j) {
        unsigned short h, lw;
        split2(xs[j], h, lw);
        hi[j] = (short)h; lo[j] = (short)lw;
    }
}
__device__ __forceinline__ unsigned fmap(float s) {
    int fi = __float_as_int(s);
    return (unsigned)(fi ^ ((fi >> 31) | 0x80000000));
}
__device__ __forceinline__ float funmap(unsigned u) {
    int fi = (u & 0x80000000u) ? (int)(u ^ 0x80000000u) : (int)~u;
    return __int_as_float(fi);
}

// ---------------------------------------------------------------------------
// A-fragment convert (x only now): fp32 A[M,K] -> af shorts, layout
// ((mt*KC + kc)*2 + p)*512 + l*8 ; lane holds A[m=16mt+(l&15)][k=32kc+8(l>>4)+j]
// grid (1, M/16) for K=128.
// ---------------------------------------------------------------------------
__global__ __launch_bounds__(256) void conv_a(const float* __restrict__ A,
                                              short* __restrict__ af, int K)
{
    const int t = threadIdx.x, l = t & 63;
    const int KC = K >> 5;
    const int kc = blockIdx.x * 4 + (t >> 6);
    const int mt = blockIdx.y;
    const int m = mt * 16 + (l & 15);
    const int kb = kc * 32 + ((l >> 4) << 3);
    float4 x0 = *(const float4*)(A + (size_t)m * K + kb);
    float4 x1 = *(const float4*)(A + (size_t)m * K + kb + 4);
    float xs[8] = {x0.x, x0.y, x0.z, x0.w, x1.x, x1.y, x1.z, x1.w};
    short8 hi, lo;
    split8(xs, hi, lo);
    short* dst = af + (size_t)((mt * KC + kc) * 2) * 512 + l * 8;
    *(short8*)(dst) = hi;
    *(short8*)(dst + 512) = lo;
}

// ---------------------------------------------------------------------------
// ALL-layer weight convert (once per call): z = layer*4 + mat. grid (4,32,16).
// ---------------------------------------------------------------------------
__global__ __launch_bounds__(256) void conv_wall(const float* __restrict__ Wq,
                                                 const float* __restrict__ Wk,
                                                 const float* __restrict__ Wv,
                                                 const float* __restrict__ Wo,
                                                 short* __restrict__ wf)
{
    const int z = blockIdx.z;
    const int layer = z >> 2, mm = z & 3;
    const float* W = (mm == 0 ? Wq : mm == 1 ? Wk : mm == 2 ? Wv : Wo)
                     + (size_t)layer * EDIM * EDIM;
    const int t = threadIdx.x, l = t & 63;
    const int kc = blockIdx.x * 4 + (t >> 6);
    const int nt = blockIdx.y;
    const int n = nt * 16 + (l & 15);
    const int kb = kc * 32 + ((l >> 4) << 3);
    float xs[8];
#pragma unroll
    for (int j = 0; j < 8; ++j) xs[j] = W[(size_t)(kb + j) * EDIM + n];
    short8 hi, lo;
    split8(xs, hi, lo);
    short* dst = wf + (size_t)z * 524288 + (size_t)((nt * 16 + kc) * 2) * 512 + l * 8;
    *(short8*)(dst) = hi;
    *(short8*)(dst + 512) = lo;
}

// single matrix variant (emb_w, K=128): grid (1, 32)
__global__ __launch_bounds__(256) void conv_w1(const float* __restrict__ W,
                                               short* __restrict__ wf, int K, int N)
{
    const int t = threadIdx.x, l = t & 63;
    const int KC = K >> 5;
    const int kc = blockIdx.x * 4 + (t >> 6);
    const int nt = blockIdx.y;
    const int n = nt * 16 + (l & 15);
    const int kb = kc * 32 + ((l >> 4) << 3);
    float xs[8];
#pragma unroll
    for (int j = 0; j < 8; ++j) xs[j] = W[(size_t)(kb + j) * N + n];
    short8 hi, lo;
    split8(xs, hi, lo);
    short* dst = wf + (size_t)((nt * KC + kc) * 2) * 512 + l * 8;
    *(short8*)(dst) = hi;
    *(short8*)(dst + 512) = lo;
}

// ---------------------------------------------------------------------------
// Split-bf16 MFMA GEMM + fused A-fragment epilogue for the NEXT GEMM (K=512):
// writes C fp32 (N=512) AND af_out frags via LDS transpose (stride 68: b128
// frag reads land 2-way max = free). Tile 128x64, grid (M/128, 8).
// ---------------------------------------------------------------------------
__global__ __launch_bounds__(256, 3) void gemm_af(const short* __restrict__ af_in,
                                                  const short* __restrict__ wf,
                                                  const float* __restrict__ bias,
                                                  float* __restrict__ Cout,
                                                  short* __restrict__ af_out,
                                                  int K)
{
    __shared__ float S[128 * 68];
    const int t = threadIdx.x, l = t & 63, w = t >> 6;
    const int KC = K >> 5;
    const int mt0 = blockIdx.x * 8 + (w & 1) * 4;
    const int nt0l = (w >> 1) * 2;
    f32x4 acc[4][2] = {};

#pragma unroll 2
    for (int kc = 0; kc < KC; ++kc) {
        short8 ah[4], al[4], bh[2], bl[2];
#pragma unroll
        for (int i = 0; i < 4; ++i) {
            const short* ap = af_in + (size_t)(((mt0 + i) * KC + kc) * 2) * 512 + l * 8;
            ah[i] = *(const short8*)(ap);
            al[i] = *(const short8*)(ap + 512);
        }
#pragma unroll
        for (int j = 0; j < 2; ++j) {
            const short* bp = wf + (size_t)(((blockIdx.y * 4 + nt0l + j) * KC + kc) * 2) * 512 + l * 8;
            bh[j] = *(const short8*)(bp);
            bl[j] = *(const short8*)(bp + 512);
        }
#pragma unroll
        for (int i = 0; i < 4; ++i)
#pragma unroll
            for (int j = 0; j < 2; ++j) {
                acc[i][j] = __builtin_amdgcn_mfma_f32_16x16x32_bf16(ah[i], bh[j], acc[i][j], 0, 0, 0);
                acc[i][j] = __builtin_amdgcn_mfma_f32_16x16x32_bf16(ah[i], bl[j], acc[i][j], 0, 0, 0);
                acc[i][j] = __builtin_amdgcn_mfma_f32_16x16x32_bf16(al[i], bh[j], acc[i][j], 0, 0, 0);
            }
    }
    // stage acc+bias into S[row_local][col_local] and write C fp32
#pragma unroll
    for (int j = 0; j < 2; ++j) {
        const int cl = (nt0l + j) * 16 + (l & 15);
        const float bv = bias[blockIdx.y * 64 + cl];
#pragma unroll
        for (int i = 0; i < 4; ++i) {
            const int rl = ((w & 1) * 4 + i) * 16 + ((l >> 4) << 2);
#pragma unroll
            for (int r = 0; r < 4; ++r) {
                const float v = acc[i][j][r] + bv;
                S[(rl + r) * 68 + cl] = v;
                Cout[(size_t)(blockIdx.x * 128 + rl + r) * EDIM + blockIdx.y * 64 + cl] = v;
            }
        }
    }
    __syncthreads();
    // af_out: wave w -> local mt tiles {2w, 2w+1}, kc in {2by, 2by+1}
#pragma unroll
    for (int mi = 0; mi < 2; ++mi) {
        const int mtl = w * 2 + mi;
        const int mt = blockIdx.x * 8 + mtl;
#pragma unroll
        for (int kcl = 0; kcl < 2; ++kcl) {
            const int kc = blockIdx.y * 2 + kcl;
            const float* src = &S[(mtl * 16 + (l & 15)) * 68 + kcl * 32 + ((l >> 4) << 3)];
            float4 x0 = *(const float4*)(src);
            float4 x1 = *(const float4*)(src + 4);
            float xs[8] = {x0.x, x0.y, x0.z, x0.w, x1.x, x1.y, x1.z, x1.w};
            short8 hi, lo;
            split8(xs, hi, lo);
            short* dst = af_out + (size_t)((mt * 16 + kc) * 2) * 512 + l * 8;
            *(short8*)(dst) = hi;
            *(short8*)(dst + 512) = lo;
        }
    }
}

// ---------------------------------------------------------------------------
// Fused Q/K/V projection: grid (64, 24). y<8: Q (fp32 out); y in [8,16): K ->
// kf frags; y in [16,24): V -> vf frags. Frag layouts identical to the
// verified prep_kf/prep_vf (K stage stride 68, V stage stride 66 - both
// <=2-way bank aliasing on every access pattern).
// ---------------------------------------------------------------------------
__global__ __launch_bounds__(256, 3) void gemm_qkv(const short* __restrict__ af,
                                                   const short* __restrict__ wfl,
                                                   const float* __restrict__ bq,
                                                   const float* __restrict__ bk,
                                                   const float* __restrict__ bv,
                                                   float* __restrict__ Qout,
                                                   short* __restrict__ kf,
                                                   short* __restrict__ vf)
{
    __shared__ float S[128 * 68];
    const int y = blockIdx.y;
    const int mat = y >> 3, e = y & 7;
    const short* wfm = wfl + (size_t)mat * 524288;
    const int t = threadIdx.x, l = t & 63, w = t >> 6;
    const int KC = EDIM >> 5;
    const int mt0 = blockIdx.x * 8 + (w & 1) * 4;
    const int nt0l = (w >> 1) * 2;
    f32x4 acc[4][2] = {};

#pragma unroll 2
    for (int kc = 0; kc < KC; ++kc) {
        short8 ah[4], al[4], bh[2], bl[2];
#pragma unroll
        for (int i = 0; i < 4; ++i) {
            const short* ap = af + (size_t)(((mt0 + i) * KC + kc) * 2) * 512 + l * 8;
            ah[i] = *(const short8*)(ap);
            al[i] = *(const short8*)(ap + 512);
        }
#pragma unroll
        for (int j = 0; j < 2; ++j) {
            const short* bp = wfm + (size_t)(((e * 4 + nt0l + j) * KC + kc) * 2) * 512 + l * 8;
            bh[j] = *(const short8*)(bp);
            bl[j] = *(const short8*)(bp + 512);
        }
#pragma unroll
        for (int i = 0; i < 4; ++i)
#pragma unroll
            for (int j = 0; j < 2; ++j) {
                acc[i][j] = __builtin_amdgcn_mfma_f32_16x16x32_bf16(ah[i], bh[j], acc[i][j], 0, 0, 0);
                acc[i][j] = __builtin_amdgcn_mfma_f32_16x16x32_bf16(ah[i], bl[j], acc[i][j], 0, 0, 0);
                acc[i][j] = __builtin_amdgcn_mfma_f32_16x16x32_bf16(al[i], bh[j], acc[i][j], 0, 0, 0);
            }
    }

    if (mat == 0) {
        // Q: plain fp32 + bias
#pragma unroll
        for (int j = 0; j < 2; ++j) {
            const int col = e * 64 + (nt0l + j) * 16 + (l & 15);
            const float bvx = bq[col];
#pragma unroll
            for (int i = 0; i < 4; ++i) {
                const int rowb = (mt0 + i) * 16 + ((l >> 4) << 2);
#pragma unroll
                for (int r = 0; r < 4; ++r)
                    Qout[(size_t)(rowb + r) * EDIM + col] = acc[i][j][r] + bvx;
            }
        }
        return;
    }

    const int STR = (mat == 1) ? 68 : 66;
    const float* bias = (mat == 1) ? bk : bv;
#pragma unroll
    for (int j = 0; j < 2; ++j) {
        const int cl = (nt0l + j) * 16 + (l & 15);
        const float bvx = bias[e * 64 + cl];
#pragma unroll
        for (int i = 0; i < 4; ++i) {
            const int rl = ((w & 1) * 4 + i) * 16 + ((l >> 4) << 2);
#pragma unroll
            for (int r = 0; r < 4; ++r)
                S[(rl + r) * STR + cl] = acc[i][j][r] + bvx;
        }
    }
    __syncthreads();

    const int b = blockIdx.x >> 3;
    const int bh = b * 8 + e;
    if (mat == 1) {
        // K frags: wave w -> key-tiles {2w, 2w+1} local, kc 0..2
#pragma unroll
        for (int ki = 0; ki < 2; ++ki) {
            const int ktl = w * 2 + ki;
            const int kt = (blockIdx.x & 7) * 8 + ktl;
#pragma unroll
            for (int kc = 0; kc < 2; ++kc) {
                const float* src = &S[(ktl * 16 + (l & 15)) * 68 + kc * 32 + ((l >> 4) << 3)];
                float4 x0 = *(const float4*)(src);
                float4 x1 = *(const float4*)(src + 4);
                float xs[8] = {x0.x, x0.y, x0.z, x0.w, x1.x, x1.y, x1.z, x1.w};
                short8 hi, lo;
                split8(xs, hi, lo);
                short* dst = kf + (size_t)(((bh * 64 + kt) * 2 + kc) * 2) * 512 + l * 8;
                *(short8*)(dst) = hi;
                *(short8*)(dst + 512) = lo;
            }
        }
    } else {
        // V frags: wave w -> jc local = w; n 0..4; lane holds 8 consecutive keys
        const int jc = (blockIdx.x & 7) * 4 + w;
#pragma unroll
        for (int n = 0; n < 4; ++n) {
            float xs[8];
#pragma unroll
            for (int j2 = 0; j2 < 8; ++j2)
                xs[j2] = S[(w * 32 + ((l >> 4) << 3) + j2) * 66 + n * 16 + (l & 15)];
            short8 hi, lo;
            split8(xs, hi, lo);
            short* dst = vf + (size_t)(((bh * 32 + jc) * 4 + n) * 2) * 512 + l * 8;
            *(short8*)(dst) = hi;
            *(short8*)(dst + 512) = lo;
        }
    }
}

// ---------------------------------------------------------------------------
// Fused sparse attention. 8-row WG, LDS exactly 32 KB -> 5 WG/CU.
// e pre-scaled by 1/Z in phase 2 (no zinv array, no phase-3 multiply).
// Phase-3 output written directly as A-fragments (af_o) for the Wo GEMM via a
// small LDS transpose (o fp32 never materialized).
// grid (64 bh, 128 qblk), 256 thr.
// ---------------------------------------------------------------------------
__global__ __launch_bounds__(256, 5) void attn_mfma(const float* __restrict__ Q,
                                                    const short* __restrict__ KF,
                                                    const short* __restrict__ VF,
                                                    short* __restrict__ afo)
{
    __shared__ alignas(16) unsigned char Pbuf[PQ * 4096];   // 32768 B exactly

    const int bh = blockIdx.x, b = bh >> 3, hh = bh & 7;
    const int q0 = blockIdx.y * PQ;
    const int t = threadIdx.x, l = t & 63, w = t >> 6;

    // Q A-fragments, rows duplicated (m = l&7), scale 1/8 folded in
    short8 aqh[2], aql[2];
    {
        const float* qp = Q + (size_t)(b * SEQ + q0 + (l & 7)) * EDIM + hh * HD + ((l >> 4) << 3);
#pragma unroll
        for (int kc = 0; kc < 2; ++kc) {
            float4 x0 = *(const float4*)(qp + kc * 32);
            float4 x1 = *(const float4*)(qp + kc * 32 + 4);
            float xs[8] = {x0.x * 0.125f, x0.y * 0.125f, x0.z * 0.125f, x0.w * 0.125f,
                           x1.x * 0.125f, x1.y * 0.125f, x1.z * 0.125f, x1.w * 0.125f};
            split8(xs, aqh[kc], aql[kc]);
        }
    }

    // ---- phase 1: wave w computes key tiles 16w..16w+15; fp32 S into LDS.
    {
        const short* kfb = KF + (size_t)bh * 64 * 2048;
        const int g = l >> 4;
        const int rowbase = (g & 1) << 2;
        const int rsel = (g >> 1) << 1;
        for (int i = 0; i < 16; ++i) {
            const int kt = (w << 4) + i;
            const short* kp = kfb + (size_t)kt * 2048 + l * 8;
            short8 b00 = *(const short8*)(kp);
            short8 b01 = *(const short8*)(kp + 512);
            short8 b10 = *(const short8*)(kp + 1024);
            short8 b11 = *(const short8*)(kp + 1536);
            f32x4 acc = {0.f, 0.f, 0.f, 0.f};
            acc = __builtin_amdgcn_mfma_f32_16x16x32_bf16(aqh[0], b00, acc, 0, 0, 0);
            acc = __builtin_amdgcn_mfma_f32_16x16x32_bf16(aqh[0], b01, acc, 0, 0, 0);
            acc = __builtin_amdgcn_mfma_f32_16x16x32_bf16(aql[0], b00, acc, 0, 0, 0);
            acc = __builtin_amdgcn_mfma_f32_16x16x32_bf16(aqh[1], b10, acc, 0, 0, 0);
            acc = __builtin_amdgcn_mfma_f32_16x16x32_bf16(aqh[1], b11, acc, 0, 0, 0);
            acc = __builtin_amdgcn_mfma_f32_16x16x32_bf16(aql[1], b10, acc, 0, 0, 0);
            const int col = (kt << 4) + (l & 15);
            const int cg = col >> 2, wi = col & 3;
#pragma unroll
            for (int j = 0; j < 2; ++j) {
                const int row = rowbase + rsel + j;
                *(float*)(Pbuf + row * 4096 + (((cg ^ row) << 4) | (wi << 2))) = acc[rsel + j];
            }
        }
    }
    __syncthreads();

    // ---- phase 2: wave w owns rows 2w, 2w+1; lane owns S granules l+64n.
    {
        const int r0 = w << 1, r1 = r0 + 1;

        unsigned u0[16], u1[16];
#pragma unroll
        for (int n = 0; n < 4; ++n) {
            float4 s0 = *(const float4*)(Pbuf + r0 * 4096 + (((l + (n << 6)) ^ r0) << 4));
            float4 s1 = *(const float4*)(Pbuf + r1 * 4096 + (((l + (n << 6)) ^ r1) << 4));
            u0[n * 4 + 0] = fmap(s0.x); u0[n * 4 + 1] = fmap(s0.y);
            u0[n * 4 + 2] = fmap(s0.z); u0[n * 4 + 3] = fmap(s0.w);
            u1[n * 4 + 0] = fmap(s1.x); u1[n * 4 + 1] = fmap(s1.y);
            u1[n * 4 + 2] = fmap(s1.z); u1[n * 4 + 3] = fmap(s1.w);
        }

        unsigned um0 = u0[0], um1 = u1[0];
#pragma unroll
        for (int i = 1; i < 16; ++i) {
            um0 = u0[i] > um0 ? u0[i] : um0;
            um1 = u1[i] > um1 ? u1[i] : um1;
        }
#pragma unroll
        for (int off = 32; off > 0; off >>= 1) {
            unsigned o0 = __shfl_xor((int)um0, off);
            unsigned o1 = __shfl_xor((int)um1, off);
            um0 = o0 > um0 ? o0 : um0;
            um1 = o1 > um1 ? o1 : um1;
        }

        // dual-row exact 256th-largest with max-skip + exact-count early exit
        unsigned T0 = 0, T1 = 0;
        bool d0 = false, d1 = false;
        for (int bit = 31; bit >= 0; --bit) {
            const unsigned msk = 1u << bit;
            if (!d0) {
                const unsigned c0 = T0 | msk;
                if (c0 <= um0) {
                    int n0 = 0;
#pragma unroll
                    for (int i = 0; i < 16; ++i)
                        n0 += (int)__popcll(__ballot(u0[i] >= c0));
                    if (n0 >= KSEL) { T0 = c0; d0 = (n0 == KSEL); }
                }
            }
            if (!d1) {
                const unsigned c1 = T1 | msk;
                if (c1 <= um1) {
                    int n1 = 0;
#pragma unroll
                    for (int i = 0; i < 16; ++i)
                        n1 += (int)__popcll(__ballot(u1[i] >= c1));
                    if (n1 >= KSEL) { T1 = c1; d1 = (n1 == KSEL); }
                }
            }
            if (d0 & d1) break;
        }

        // softmax numerators, Z-reduce FIRST, then write e/Z hi/lo in place
        const float m0 = funmap(um0), m1 = funmap(um1);
        float e0[16], e1[16];
        float Z0 = 0.f, Z1 = 0.f;
#pragma unroll
        for (int i = 0; i < 16; ++i) {
            e0[i] = (u0[i] >= T0) ? __expf(funmap(u0[i]) - m0) : 0.f;
            e1[i] = (u1[i] >= T1) ? __expf(funmap(u1[i]) - m1) : 0.f;
            Z0 += e0[i];
            Z1 += e1[i];
        }
#pragma unroll
        for (int off = 32; off > 0; off >>= 1) {
            Z0 += __shfl_xor(Z0, off);
            Z1 += __shfl_xor(Z1, off);
        }
        const float zi0 = 1.0f / Z0, zi1 = 1.0f / Z1;
#pragma unroll
        for (int n = 0; n < 4; ++n) {
            const int gg = ((l + (n << 6)) >> 1);
            short4 H, L;
            unsigned short h, lw;
            split2(e0[n * 4 + 0] * zi0, h, lw); H.x = (short)h; L.x = (short)lw;
            split2(e0[n * 4 + 1] * zi0, h, lw); H.y = (short)h; L.y = (short)lw;
            split2(e0[n * 4 + 2] * zi0, h, lw); H.z = (short)h; L.z = (short)lw;
            split2(e0[n * 4 + 3] * zi0, h, lw); H.w = (short)h; L.w = (short)lw;
            unsigned char* base0 = Pbuf + r0 * 4096 + (((gg ^ r0) << 4) | ((l & 1) << 3));
            *(short4*)(base0) = H;
            *(short4*)(base0 + 2048) = L;
            split2(e1[n * 4 + 0] * zi1, h, lw); H.x = (short)h; L.x = (short)lw;
            split2(e1[n * 4 + 1] * zi1, h, lw); H.y = (short)h; L.y = (short)lw;
            split2(e1[n * 4 + 2] * zi1, h, lw); H.z = (short)h; L.z = (short)lw;
            split2(e1[n * 4 + 3] * zi1, h, lw); H.w = (short)h; L.w = (short)lw;
            unsigned char* base1 = Pbuf + r1 * 4096 + (((gg ^ r1) << 4) | ((l & 1) << 3));
            *(short4*)(base1) = H;
            *(short4*)(base1 + 2048) = L;
        }
    }
    __syncthreads();

    // ---- phase 3: wave w owns channel tile w; A rows duplicated (m = l&7).
    f32x4 oacc = {0.f, 0.f, 0.f, 0.f};
    {
        const short* vfb = VF + (size_t)bh * 32 * 4096 + (size_t)w * 1024;
        const int m = l & 7, g3 = l >> 4;
        for (int jc = 0; jc < 32; ++jc) {
            const int gg = (jc << 2) + g3;
            const unsigned char* abase = Pbuf + m * 4096 + ((gg ^ m) << 4);
            short8 ph = *(const short8*)(abase);
            short8 pl = *(const short8*)(abase + 2048);
            const short* vp = vfb + (size_t)jc * 4096 + l * 8;
            short8 vh = *(const short8*)(vp);
            short8 vl = *(const short8*)(vp + 512);
            oacc = __builtin_amdgcn_mfma_f32_16x16x32_bf16(ph, vh, oacc, 0, 0, 0);
            oacc = __builtin_amdgcn_mfma_f32_16x16x32_bf16(ph, vl, oacc, 0, 0, 0);
            oacc = __builtin_amdgcn_mfma_f32_16x16x32_bf16(pl, vh, oacc, 0, 0, 0);
        }
    }
    __syncthreads();   // all P reads done before overwrite

    // stage O (8 rows x 64 head-channels fp32, stride 68) into Pbuf
    if (l < 32) {
        const int c = (w << 4) + (l & 15);
        const int rb = (l >> 4) << 2;
#pragma unroll
        for (int r = 0; r < 4; ++r)
            *(float*)(Pbuf + (size_t)((rb + r) * 68 + c) * 4) = oacc[r];
    }
    __syncthreads();

    // af_o write: waves 0,1 (kcl = w); active lanes hold row m%16 = l&15
    if (w < 2) {
        const int mhalf = (q0 >> 3) & 1;
        if (((l >> 3) & 1) == mhalf) {
            const int rl = l & 7;
            const float* src = (const float*)(Pbuf) + rl * 68 + w * 32 + ((l >> 4) << 3);
            float4 x0 = *(const float4*)(src);
            float4 x1 = *(const float4*)(src + 4);
            float xs[8] = {x0.x, x0.y, x0.z, x0.w, x1.x, x1.y, x1.z, x1.w};
            short8 hi, lo;
            split8(xs, hi, lo);
            const int mt = (b * SEQ + q0) >> 4;
            const int kc = hh * 2 + w;
            short* dst = afo + (size_t)((mt * 16 + kc) * 2) * 512 + l * 8;
            *(short8*)(dst) = hi;
            *(short8*)(dst + 512) = lo;
        }
    }
}

// ---------------------------------------------------------------------------
__global__ __launch_bounds__(256) void mean_fc(const float* __restrict__ Hf,
                                               const float* __restrict__ fcw,
                                               const float* __restrict__ fcb,
                                               float* __restrict__ out)
{
    __shared__ float hm[EDIM];
    const int b = blockIdx.x, t = threadIdx.x;
    const float* hb = Hf + (size_t)b * SEQ * EDIM;
    float s0 = 0.f, s1 = 0.f;
    for (int s = 0; s < SEQ; ++s) {
        s0 += hb[(size_t)s * EDIM + t];
        s1 += hb[(size_t)s * EDIM + t + 256];
    }
    hm[t] = s0 * (1.0f / SEQ);
    hm[t + 256] = s1 * (1.0f / SEQ);
    __syncthreads();
    if (t < 10) {
        float acc = fcb[t];
        for (int e = 0; e < EDIM; ++e) acc += hm[e] * fcw[e * 10 + t];
        out[b * 10 + t] = acc;
    }
}

// ---------------------------------------------------------------------------
extern "C" void kernel_launch(void* const* d_in, const int* in_sizes, int n_in,
                              void* d_out, int out_size, void* d_ws, size_t ws_size,
                              hipStream_t stream)
{
    const float* x     = (const float*)d_in[0];
    const float* emb_w = (const float*)d_in[1];
    const float* emb_b = (const float*)d_in[2];
    const float* Wq    = (const float*)d_in[3];
    const float* Wk    = (const float*)d_in[4];
    const float* Wv    = (const float*)d_in[5];
    const float* Wo    = (const float*)d_in[6];
    const float* bq    = (const float*)d_in[7];
    const float* bk    = (const float*)d_in[8];
    const float* bv    = (const float*)d_in[9];
    const float* bo    = (const float*)d_in[10];
    const float* fcw   = (const float*)d_in[11];
    const float* fcb   = (const float*)d_in[12];
    float* out = (float*)d_out;
    float* ws  = (float*)d_ws;

    const size_t SZ = (size_t)BATCH * SEQ * EDIM;    // 4,194,304 floats = 16 MiB
    float* h   = ws;                                  // S0: h fp32 (mean_fc input)
    float* q   = ws + SZ;                             // S1: q fp32
    short* afo = (short*)(ws + 2 * SZ);               // S2: attn-out frags
    short* afx = (short*)(ws + 3 * SZ);               // S3: x frags (4 MiB used)
    short* wfe = afx + 4 * 1024 * 1024;               // S3 tail: emb weight frags
    short* kf  = (short*)(ws + 4 * SZ);               // S4
    short* vf  = (short*)(ws + 5 * SZ);               // S5
    short* afh = (short*)(ws + 6 * SZ);               // S6: h frags
    short* wf  = (short*)(ws + 7 * SZ);               // S7: 16 x 524288 shorts

    const int M = BATCH * SEQ;                        // 8192
    const dim3 gG(M / 128, EDIM / 64);                // (64, 8)
    const dim3 gQKV(M / 128, 3 * EDIM / 64);          // (64, 24)
    const dim3 gA(BATCH * NH, SEQ / PQ);              // (64, 128)

    conv_wall<<<dim3(4, 32, 16), 256, 0, stream>>>(Wq, Wk, Wv, Wo, wf);
    conv_w1<<<dim3(1, 32), 256, 0, stream>>>(emb_w, wfe, 128, EDIM);
    conv_a<<<dim3(1, M / 16), 256, 0, stream>>>(x, afx, 128);
    gemm_af<<<gG, 256, 0, stream>>>(afx, wfe, emb_b, h, afh, 128);

    for (int l = 0; l < NLAYER; ++l) {
        const short* wfl = wf + (size_t)(4 * l) * 524288;
        gemm_qkv<<<gQKV, 256, 0, stream>>>(afh, wfl, bq + l * EDIM, bk + l * EDIM,
                                           bv + l * EDIM, q, kf, vf);
        attn_mfma<<<gA, 256, 0, stream>>>(q, kf, vf, afo);
        gemm_af<<<gG, 256, 0, stream>>>(afo, wfl + 3 * 524288, bo + l * EDIM, h, afh, EDIM);
    }
    mean_fc<<<8, 256, 0, stream>>>(h, fcw, fcb, out);
}

// Round 7
// 1138.435 us; speedup vs baseline: 3.3335x; 1.0945x over previous
//
#include <hip/hip_runtime.h>

#define EDIM 512
#define NH 8
#define HD 64
#define SEQ 1024
#define BATCH 8
#define NLAYER 4
#define KSEL 256

typedef __attribute__((ext_vector_type(8))) short short8;
typedef __attribute__((ext_vector_type(4))) float f32x4;

// ---- split-bf16 helpers: f ~= hi + lo, |err| ~ 2^-17 |f| ---------------
__device__ __forceinline__ unsigned short bf16_rne(float f) {
    unsigned u = __float_as_uint(f);
    return (unsigned short)((u + 0x7FFFu + ((u >> 16) & 1u)) >> 16);
}
__device__ __forceinline__ float bf16_tof(unsigned short h) {
    return __uint_as_float(((unsigned)h) << 16);
}
__device__ __forceinline__ void split2(float f, unsigned short& hi, unsigned short& lo) {
    hi = bf16_rne(f);
    float r = f - bf16_tof(hi);
    lo = (unsigned short)(__float_as_uint(r) >> 16);
}
__device__ __forceinline__ void split8(const float* xs, short8& hi, short8& lo) {
#pragma unroll
    for (int j = 0; j < 8; ++j) {
        unsigned short h, lw;
        split2(xs[j], h, lw);
        hi[j] = (short)h; lo[j] = (short)lw;
    }
}
__device__ __forceinline__ unsigned fmap(float s) {
    int fi = __float_as_int(s);
    return (unsigned)(fi ^ ((fi >> 31) | 0x80000000));
}
__device__ __forceinline__ float funmap(unsigned u) {
    int fi = (u & 0x80000000u) ? (int)(u ^ 0x80000000u) : (int)~u;
    return __int_as_float(fi);
}

// ---------------------------------------------------------------------------
// A-fragment convert (x only): grid (1, M/16), K=128.
// ---------------------------------------------------------------------------
__global__ __launch_bounds__(256) void conv_a(const float* __restrict__ A,
                                              short* __restrict__ af, int K)
{
    const int t = threadIdx.x, l = t & 63;
    const int KC = K >> 5;
    const int kc = blockIdx.x * 4 + (t >> 6);
    const int mt = blockIdx.y;
    const int m = mt * 16 + (l & 15);
    const int kb = kc * 32 + ((l >> 4) << 3);
    float4 x0 = *(const float4*)(A + (size_t)m * K + kb);
    float4 x1 = *(const float4*)(A + (size_t)m * K + kb + 4);
    float xs[8] = {x0.x, x0.y, x0.z, x0.w, x1.x, x1.y, x1.z, x1.w};
    short8 hi, lo;
    split8(xs, hi, lo);
    short* dst = af + (size_t)((mt * KC + kc) * 2) * 512 + l * 8;
    *(short8*)(dst) = hi;
    *(short8*)(dst + 512) = lo;
}

// ---------------------------------------------------------------------------
// ALL-layer weight convert: z = layer*4 + mat. grid (4,32,16).
// ---------------------------------------------------------------------------
__global__ __launch_bounds__(256) void conv_wall(const float* __restrict__ Wq,
                                                 const float* __restrict__ Wk,
                                                 const float* __restrict__ Wv,
                                                 const float* __restrict__ Wo,
                                                 short* __restrict__ wf)
{
    const int z = blockIdx.z;
    const int layer = z >> 2, mm = z & 3;
    const float* W = (mm == 0 ? Wq : mm == 1 ? Wk : mm == 2 ? Wv : Wo)
                     + (size_t)layer * EDIM * EDIM;
    const int t = threadIdx.x, l = t & 63;
    const int kc = blockIdx.x * 4 + (t >> 6);
    const int nt = blockIdx.y;
    const int n = nt * 16 + (l & 15);
    const int kb = kc * 32 + ((l >> 4) << 3);
    float xs[8];
#pragma unroll
    for (int j = 0; j < 8; ++j) xs[j] = W[(size_t)(kb + j) * EDIM + n];
    short8 hi, lo;
    split8(xs, hi, lo);
    short* dst = wf + (size_t)z * 524288 + (size_t)((nt * 16 + kc) * 2) * 512 + l * 8;
    *(short8*)(dst) = hi;
    *(short8*)(dst + 512) = lo;
}

// single matrix variant (emb_w, K=128): grid (1, 32)
__global__ __launch_bounds__(256) void conv_w1(const float* __restrict__ W,
                                               short* __restrict__ wf, int K, int N)
{
    const int t = threadIdx.x, l = t & 63;
    const int KC = K >> 5;
    const int kc = blockIdx.x * 4 + (t >> 6);
    const int nt = blockIdx.y;
    const int n = nt * 16 + (l & 15);
    const int kb = kc * 32 + ((l >> 4) << 3);
    float xs[8];
#pragma unroll
    for (int j = 0; j < 8; ++j) xs[j] = W[(size_t)(kb + j) * N + n];
    short8 hi, lo;
    split8(xs, hi, lo);
    short* dst = wf + (size_t)((nt * KC + kc) * 2) * 512 + l * 8;
    *(short8*)(dst) = hi;
    *(short8*)(dst + 512) = lo;
}

// ---------------------------------------------------------------------------
// Split-bf16 MFMA GEMM + fused A-fragment epilogue (unchanged from R6).
// ---------------------------------------------------------------------------
__global__ __launch_bounds__(256, 3) void gemm_af(const short* __restrict__ af_in,
                                                  const short* __restrict__ wf,
                                                  const float* __restrict__ bias,
                                                  float* __restrict__ Cout,
                                                  short* __restrict__ af_out,
                                                  int K)
{
    __shared__ float S[128 * 68];
    const int t = threadIdx.x, l = t & 63, w = t >> 6;
    const int KC = K >> 5;
    const int mt0 = blockIdx.x * 8 + (w & 1) * 4;
    const int nt0l = (w >> 1) * 2;
    f32x4 acc[4][2] = {};

#pragma unroll 2
    for (int kc = 0; kc < KC; ++kc) {
        short8 ah[4], al[4], bh[2], bl[2];
#pragma unroll
        for (int i = 0; i < 4; ++i) {
            const short* ap = af_in + (size_t)(((mt0 + i) * KC + kc) * 2) * 512 + l * 8;
            ah[i] = *(const short8*)(ap);
            al[i] = *(const short8*)(ap + 512);
        }
#pragma unroll
        for (int j = 0; j < 2; ++j) {
            const short* bp = wf + (size_t)(((blockIdx.y * 4 + nt0l + j) * KC + kc) * 2) * 512 + l * 8;
            bh[j] = *(const short8*)(bp);
            bl[j] = *(const short8*)(bp + 512);
        }
#pragma unroll
        for (int i = 0; i < 4; ++i)
#pragma unroll
            for (int j = 0; j < 2; ++j) {
                acc[i][j] = __builtin_amdgcn_mfma_f32_16x16x32_bf16(ah[i], bh[j], acc[i][j], 0, 0, 0);
                acc[i][j] = __builtin_amdgcn_mfma_f32_16x16x32_bf16(ah[i], bl[j], acc[i][j], 0, 0, 0);
                acc[i][j] = __builtin_amdgcn_mfma_f32_16x16x32_bf16(al[i], bh[j], acc[i][j], 0, 0, 0);
            }
    }
#pragma unroll
    for (int j = 0; j < 2; ++j) {
        const int cl = (nt0l + j) * 16 + (l & 15);
        const float bv = bias[blockIdx.y * 64 + cl];
#pragma unroll
        for (int i = 0; i < 4; ++i) {
            const int rl = ((w & 1) * 4 + i) * 16 + ((l >> 4) << 2);
#pragma unroll
            for (int r = 0; r < 4; ++r) {
                const float v = acc[i][j][r] + bv;
                S[(rl + r) * 68 + cl] = v;
                Cout[(size_t)(blockIdx.x * 128 + rl + r) * EDIM + blockIdx.y * 64 + cl] = v;
            }
        }
    }
    __syncthreads();
#pragma unroll
    for (int mi = 0; mi < 2; ++mi) {
        const int mtl = w * 2 + mi;
        const int mt = blockIdx.x * 8 + mtl;
#pragma unroll
        for (int kcl = 0; kcl < 2; ++kcl) {
            const int kc = blockIdx.y * 2 + kcl;
            const float* src = &S[(mtl * 16 + (l & 15)) * 68 + kcl * 32 + ((l >> 4) << 3)];
            float4 x0 = *(const float4*)(src);
            float4 x1 = *(const float4*)(src + 4);
            float xs[8] = {x0.x, x0.y, x0.z, x0.w, x1.x, x1.y, x1.z, x1.w};
            short8 hi, lo;
            split8(xs, hi, lo);
            short* dst = af_out + (size_t)((mt * 16 + kc) * 2) * 512 + l * 8;
            *(short8*)(dst) = hi;
            *(short8*)(dst + 512) = lo;
        }
    }
}

// ---------------------------------------------------------------------------
// Fused Q/K/V projection with K/V fragment epilogues (unchanged from R6).
// ---------------------------------------------------------------------------
__global__ __launch_bounds__(256, 3) void gemm_qkv(const short* __restrict__ af,
                                                   const short* __restrict__ wfl,
                                                   const float* __restrict__ bq,
                                                   const float* __restrict__ bk,
                                                   const float* __restrict__ bv,
                                                   float* __restrict__ Qout,
                                                   short* __restrict__ kf,
                                                   short* __restrict__ vf)
{
    __shared__ float S[128 * 68];
    const int y = blockIdx.y;
    const int mat = y >> 3, e = y & 7;
    const short* wfm = wfl + (size_t)mat * 524288;
    const int t = threadIdx.x, l = t & 63, w = t >> 6;
    const int KC = EDIM >> 5;
    const int mt0 = blockIdx.x * 8 + (w & 1) * 4;
    const int nt0l = (w >> 1) * 2;
    f32x4 acc[4][2] = {};

#pragma unroll 2
    for (int kc = 0; kc < KC; ++kc) {
        short8 ah[4], al[4], bh[2], bl[2];
#pragma unroll
        for (int i = 0; i < 4; ++i) {
            const short* ap = af + (size_t)(((mt0 + i) * KC + kc) * 2) * 512 + l * 8;
            ah[i] = *(const short8*)(ap);
            al[i] = *(const short8*)(ap + 512);
        }
#pragma unroll
        for (int j = 0; j < 2; ++j) {
            const short* bp = wfm + (size_t)(((e * 4 + nt0l + j) * KC + kc) * 2) * 512 + l * 8;
            bh[j] = *(const short8*)(bp);
            bl[j] = *(const short8*)(bp + 512);
        }
#pragma unroll
        for (int i = 0; i < 4; ++i)
#pragma unroll
            for (int j = 0; j < 2; ++j) {
                acc[i][j] = __builtin_amdgcn_mfma_f32_16x16x32_bf16(ah[i], bh[j], acc[i][j], 0, 0, 0);
                acc[i][j] = __builtin_amdgcn_mfma_f32_16x16x32_bf16(ah[i], bl[j], acc[i][j], 0, 0, 0);
                acc[i][j] = __builtin_amdgcn_mfma_f32_16x16x32_bf16(al[i], bh[j], acc[i][j], 0, 0, 0);
            }
    }

    if (mat == 0) {
#pragma unroll
        for (int j = 0; j < 2; ++j) {
            const int col = e * 64 + (nt0l + j) * 16 + (l & 15);
            const float bvx = bq[col];
#pragma unroll
            for (int i = 0; i < 4; ++i) {
                const int rowb = (mt0 + i) * 16 + ((l >> 4) << 2);
#pragma unroll
                for (int r = 0; r < 4; ++r)
                    Qout[(size_t)(rowb + r) * EDIM + col] = acc[i][j][r] + bvx;
            }
        }
        return;
    }

    const int STR = (mat == 1) ? 68 : 66;
    const float* bias = (mat == 1) ? bk : bv;
#pragma unroll
    for (int j = 0; j < 2; ++j) {
        const int cl = (nt0l + j) * 16 + (l & 15);
        const float bvx = bias[e * 64 + cl];
#pragma unroll
        for (int i = 0; i < 4; ++i) {
            const int rl = ((w & 1) * 4 + i) * 16 + ((l >> 4) << 2);
#pragma unroll
            for (int r = 0; r < 4; ++r)
                S[(rl + r) * STR + cl] = acc[i][j][r] + bvx;
        }
    }
    __syncthreads();

    const int b = blockIdx.x >> 3;
    const int bh2 = b * 8 + e;
    if (mat == 1) {
#pragma unroll
        for (int ki = 0; ki < 2; ++ki) {
            const int ktl = w * 2 + ki;
            const int kt = (blockIdx.x & 7) * 8 + ktl;
#pragma unroll
            for (int kc = 0; kc < 2; ++kc) {
                const float* src = &S[(ktl * 16 + (l & 15)) * 68 + kc * 32 + ((l >> 4) << 3)];
                float4 x0 = *(const float4*)(src);
                float4 x1 = *(const float4*)(src + 4);
                float xs[8] = {x0.x, x0.y, x0.z, x0.w, x1.x, x1.y, x1.z, x1.w};
                short8 hi, lo;
                split8(xs, hi, lo);
                short* dst = kf + (size_t)(((bh2 * 64 + kt) * 2 + kc) * 2) * 512 + l * 8;
                *(short8*)(dst) = hi;
                *(short8*)(dst + 512) = lo;
            }
        }
    } else {
        const int jc = (blockIdx.x & 7) * 4 + w;
#pragma unroll
        for (int n = 0; n < 4; ++n) {
            float xs[8];
#pragma unroll
            for (int j2 = 0; j2 < 8; ++j2)
                xs[j2] = S[(w * 32 + ((l >> 4) << 3) + j2) * 66 + n * 16 + (l & 15)];
            short8 hi, lo;
            split8(xs, hi, lo);
            short* dst = vf + (size_t)(((bh2 * 32 + jc) * 4 + n) * 2) * 512 + l * 8;
            *(short8*)(dst) = hi;
            *(short8*)(dst + 512) = lo;
        }
    }
}

// ---------------------------------------------------------------------------
// Fused sparse attention, PQ=16 / 512-thread (8-wave) WG, fp32 S (64 KB) + 8.3
// KB scratch -> 2 WG/CU = 16 waves/CU. No MFMA row-duplication: full 16-row
// A-frags in both QK^T and PV. Phase 3 split (4 ch-tiles x 2 key-halves) with
// LDS partial combine. Output written directly as Wo-GEMM A-fragments.
// grid (64 bh, 64 qblk).
// ---------------------------------------------------------------------------
#define SPART 65536
#define SSTG  69632

__global__ __launch_bounds__(512, 4) void attn_mfma(const float* __restrict__ Q,
                                                    const short* __restrict__ KF,
                                                    const short* __restrict__ VF,
                                                    short* __restrict__ afo)
{
    __shared__ alignas(16) unsigned char Sb[16 * 4096 + 4096 + 4352];  // 73984 B

    const int bh = blockIdx.x, b = bh >> 3, hh = bh & 7;
    const int q0 = blockIdx.y * 16;
    const int t = threadIdx.x, l = t & 63, w = t >> 6;

    // Q A-fragments, 16 real rows (m = l&15), scale 1/8 folded in
    short8 aqh[2], aql[2];
    {
        const float* qp = Q + (size_t)(b * SEQ + q0 + (l & 15)) * EDIM + hh * HD + ((l >> 4) << 3);
#pragma unroll
        for (int kc = 0; kc < 2; ++kc) {
            float4 x0 = *(const float4*)(qp + kc * 32);
            float4 x1 = *(const float4*)(qp + kc * 32 + 4);
            float xs[8] = {x0.x * 0.125f, x0.y * 0.125f, x0.z * 0.125f, x0.w * 0.125f,
                           x1.x * 0.125f, x1.y * 0.125f, x1.z * 0.125f, x1.w * 0.125f};
            split8(xs, aqh[kc], aql[kc]);
        }
    }

    // ---- phase 1: wave w -> key tiles 8w..8w+7; full 16-row C; fp32 S to LDS.
    {
        const short* kfb = KF + (size_t)bh * 64 * 2048;
        const int rb = (l >> 4) << 2;
        for (int i = 0; i < 8; ++i) {
            const int kt = (w << 3) + i;
            const short* kp = kfb + (size_t)kt * 2048 + l * 8;
            short8 b00 = *(const short8*)(kp);
            short8 b01 = *(const short8*)(kp + 512);
            short8 b10 = *(const short8*)(kp + 1024);
            short8 b11 = *(const short8*)(kp + 1536);
            f32x4 acc = {0.f, 0.f, 0.f, 0.f};
            acc = __builtin_amdgcn_mfma_f32_16x16x32_bf16(aqh[0], b00, acc, 0, 0, 0);
            acc = __builtin_amdgcn_mfma_f32_16x16x32_bf16(aqh[0], b01, acc, 0, 0, 0);
            acc = __builtin_amdgcn_mfma_f32_16x16x32_bf16(aql[0], b00, acc, 0, 0, 0);
            acc = __builtin_amdgcn_mfma_f32_16x16x32_bf16(aqh[1], b10, acc, 0, 0, 0);
            acc = __builtin_amdgcn_mfma_f32_16x16x32_bf16(aqh[1], b11, acc, 0, 0, 0);
            acc = __builtin_amdgcn_mfma_f32_16x16x32_bf16(aql[1], b10, acc, 0, 0, 0);
            const int col = (kt << 4) + (l & 15);
            const int cg = col >> 2, wi = col & 3;
#pragma unroll
            for (int r = 0; r < 4; ++r) {
                const int row = rb + r;
                *(float*)(Sb + row * 4096 + (((cg ^ row) << 4) | (wi << 2))) = acc[r];
            }
        }
    }
    __syncthreads();

    // ---- phase 2: wave w owns rows 2w, 2w+1 (8 waves -> 16 rows).
    {
        const int r0 = w << 1, r1 = r0 + 1;

        unsigned u0[16], u1[16];
#pragma unroll
        for (int n = 0; n < 4; ++n) {
            float4 s0 = *(const float4*)(Sb + r0 * 4096 + (((l + (n << 6)) ^ r0) << 4));
            float4 s1 = *(const float4*)(Sb + r1 * 4096 + (((l + (n << 6)) ^ r1) << 4));
            u0[n * 4 + 0] = fmap(s0.x); u0[n * 4 + 1] = fmap(s0.y);
            u0[n * 4 + 2] = fmap(s0.z); u0[n * 4 + 3] = fmap(s0.w);
            u1[n * 4 + 0] = fmap(s1.x); u1[n * 4 + 1] = fmap(s1.y);
            u1[n * 4 + 2] = fmap(s1.z); u1[n * 4 + 3] = fmap(s1.w);
        }

        unsigned um0 = u0[0], um1 = u1[0];
#pragma unroll
        for (int i = 1; i < 16; ++i) {
            um0 = u0[i] > um0 ? u0[i] : um0;
            um1 = u1[i] > um1 ? u1[i] : um1;
        }
#pragma unroll
        for (int off = 32; off > 0; off >>= 1) {
            unsigned o0 = __shfl_xor((int)um0, off);
            unsigned o1 = __shfl_xor((int)um1, off);
            um0 = o0 > um0 ? o0 : um0;
            um1 = o1 > um1 ? o1 : um1;
        }

        // dual-row exact 256th-largest with max-skip + exact-count early exit
        unsigned T0 = 0, T1 = 0;
        bool d0 = false, d1 = false;
        for (int bit = 31; bit >= 0; --bit) {
            const unsigned msk = 1u << bit;
            if (!d0) {
                const unsigned c0 = T0 | msk;
                if (c0 <= um0) {
                    int n0 = 0;
#pragma unroll
                    for (int i = 0; i < 16; ++i)
                        n0 += (int)__popcll(__ballot(u0[i] >= c0));
                    if (n0 >= KSEL) { T0 = c0; d0 = (n0 == KSEL); }
                }
            }
            if (!d1) {
                const unsigned c1 = T1 | msk;
                if (c1 <= um1) {
                    int n1 = 0;
#pragma unroll
                    for (int i = 0; i < 16; ++i)
                        n1 += (int)__popcll(__ballot(u1[i] >= c1));
                    if (n1 >= KSEL) { T1 = c1; d1 = (n1 == KSEL); }
                }
            }
            if (d0 & d1) break;
        }

        // softmax numerators, Z-reduce, write e/Z hi/lo in place (row-local)
        const float m0 = funmap(um0), m1 = funmap(um1);
        float e0[16], e1[16];
        float Z0 = 0.f, Z1 = 0.f;
#pragma unroll
        for (int i = 0; i < 16; ++i) {
            e0[i] = (u0[i] >= T0) ? __expf(funmap(u0[i]) - m0) : 0.f;
            e1[i] = (u1[i] >= T1) ? __expf(funmap(u1[i]) - m1) : 0.f;
            Z0 += e0[i];
            Z1 += e1[i];
        }
#pragma unroll
        for (int off = 32; off > 0; off >>= 1) {
            Z0 += __shfl_xor(Z0, off);
            Z1 += __shfl_xor(Z1, off);
        }
        const float zi0 = 1.0f / Z0, zi1 = 1.0f / Z1;
#pragma unroll
        for (int n = 0; n < 4; ++n) {
            const int gg = ((l + (n << 6)) >> 1);
            short4 H, L;
            unsigned short h, lw;
            split2(e0[n * 4 + 0] * zi0, h, lw); H.x = (short)h; L.x = (short)lw;
            split2(e0[n * 4 + 1] * zi0, h, lw); H.y = (short)h; L.y = (short)lw;
            split2(e0[n * 4 + 2] * zi0, h, lw); H.z = (short)h; L.z = (short)lw;
            split2(e0[n * 4 + 3] * zi0, h, lw); H.w = (short)h; L.w = (short)lw;
            unsigned char* base0 = Sb + r0 * 4096 + (((gg ^ r0) << 4) | ((l & 1) << 3));
            *(short4*)(base0) = H;
            *(short4*)(base0 + 2048) = L;
            split2(e1[n * 4 + 0] * zi1, h, lw); H.x = (short)h; L.x = (short)lw;
            split2(e1[n * 4 + 1] * zi1, h, lw); H.y = (short)h; L.y = (short)lw;
            split2(e1[n * 4 + 2] * zi1, h, lw); H.z = (short)h; L.z = (short)lw;
            split2(e1[n * 4 + 3] * zi1, h, lw); H.w = (short)h; L.w = (short)lw;
            unsigned char* base1 = Sb + r1 * 4096 + (((gg ^ r1) << 4) | ((l & 1) << 3));
            *(short4*)(base1) = H;
            *(short4*)(base1 + 2048) = L;
        }
    }
    __syncthreads();

    // ---- phase 3: wave w -> ch-tile (w&3), key half (w>>2); full 16-row A.
    f32x4 oacc = {0.f, 0.f, 0.f, 0.f};
    const int cht = w & 3;
    {
        const int hf = w >> 2;
        const short* vfb = VF + (size_t)bh * 32 * 4096 + (size_t)cht * 1024;
        const int m = l & 15, g3 = l >> 4;
        for (int jc = hf * 16; jc < hf * 16 + 16; ++jc) {
            const int gg = (jc << 2) + g3;
            const unsigned char* abase = Sb + m * 4096 + ((gg ^ m) << 4);
            short8 ph = *(const short8*)(abase);
            short8 pl = *(const short8*)(abase + 2048);
            const short* vp = vfb + (size_t)jc * 4096 + l * 8;
            short8 vh = *(const short8*)(vp);
            short8 vl = *(const short8*)(vp + 512);
            oacc = __builtin_amdgcn_mfma_f32_16x16x32_bf16(ph, vh, oacc, 0, 0, 0);
            oacc = __builtin_amdgcn_mfma_f32_16x16x32_bf16(ph, vl, oacc, 0, 0, 0);
            oacc = __builtin_amdgcn_mfma_f32_16x16x32_bf16(pl, vh, oacc, 0, 0, 0);
        }
    }
    // combine key-halves: waves 4-7 stash partials, waves 0-3 add
    {
        float* part = (float*)(Sb + SPART);
        const int ch = l & 15, rb = (l >> 4) << 2;
        if (w >= 4) {
#pragma unroll
            for (int r = 0; r < 4; ++r)
                part[(cht * 16 + rb + r) * 16 + ch] = oacc[r];
        }
        __syncthreads();
        if (w < 4) {
            float* stage = (float*)(Sb + SSTG);
#pragma unroll
            for (int r = 0; r < 4; ++r) {
                const float v = oacc[r] + part[(cht * 16 + rb + r) * 16 + ch];
                stage[(rb + r) * 68 + cht * 16 + ch] = v;
            }
        }
        __syncthreads();
    }
    // afo write: waves 0,1 (kc chunk = w); full-lane 16-row A-fragment
    if (w < 2) {
        const float* stage = (const float*)(Sb + SSTG);
        const float* src = stage + (l & 15) * 68 + w * 32 + ((l >> 4) << 3);
        float4 x0 = *(const float4*)(src);
        float4 x1 = *(const float4*)(src + 4);
        float xs[8] = {x0.x, x0.y, x0.z, x0.w, x1.x, x1.y, x1.z, x1.w};
        short8 hi, lo;
        split8(xs, hi, lo);
        const int mt = (b * SEQ + q0) >> 4;
        const int kc = hh * 2 + w;
        short* dst = afo + (size_t)((mt * 16 + kc) * 2) * 512 + l * 8;
        *(short8*)(dst) = hi;
        *(short8*)(dst + 512) = lo;
    }
}

// ---------------------------------------------------------------------------
__global__ __launch_bounds__(256) void mean_fc(const float* __restrict__ Hf,
                                               const float* __restrict__ fcw,
                                               const float* __restrict__ fcb,
                                               float* __restrict__ out)
{
    __shared__ float hm[EDIM];
    const int b = blockIdx.x, t = threadIdx.x;
    const float* hb = Hf + (size_t)b * SEQ * EDIM;
    float s0 = 0.f, s1 = 0.f;
    for (int s = 0; s < SEQ; ++s) {
        s0 += hb[(size_t)s * EDIM + t];
        s1 += hb[(size_t)s * EDIM + t + 256];
    }
    hm[t] = s0 * (1.0f / SEQ);
    hm[t + 256] = s1 * (1.0f / SEQ);
    __syncthreads();
    if (t < 10) {
        float acc = fcb[t];
        for (int e = 0; e < EDIM; ++e) acc += hm[e] * fcw[e * 10 + t];
        out[b * 10 + t] = acc;
    }
}

// ---------------------------------------------------------------------------
extern "C" void kernel_launch(void* const* d_in, const int* in_sizes, int n_in,
                              void* d_out, int out_size, void* d_ws, size_t ws_size,
                              hipStream_t stream)
{
    const float* x     = (const float*)d_in[0];
    const float* emb_w = (const float*)d_in[1];
    const float* emb_b = (const float*)d_in[2];
    const float* Wq    = (const float*)d_in[3];
    const float* Wk    = (const float*)d_in[4];
    const float* Wv    = (const float*)d_in[5];
    const float* Wo    = (const float*)d_in[6];
    const float* bq    = (const float*)d_in[7];
    const float* bk    = (const float*)d_in[8];
    const float* bv    = (const float*)d_in[9];
    const float* bo    = (const float*)d_in[10];
    const float* fcw   = (const float*)d_in[11];
    const float* fcb   = (const float*)d_in[12];
    float* out = (float*)d_out;
    float* ws  = (float*)d_ws;

    const size_t SZ = (size_t)BATCH * SEQ * EDIM;    // 4,194,304 floats = 16 MiB
    float* h   = ws;                                  // S0: h fp32 (mean_fc input)
    float* q   = ws + SZ;                             // S1: q fp32
    short* afo = (short*)(ws + 2 * SZ);               // S2: attn-out frags
    short* afx = (short*)(ws + 3 * SZ);               // S3: x frags (4 MiB used)
    short* wfe = afx + 4 * 1024 * 1024;               // S3 tail: emb weight frags
    short* kf  = (short*)(ws + 4 * SZ);               // S4
    short* vf  = (short*)(ws + 5 * SZ);               // S5
    short* afh = (short*)(ws + 6 * SZ);               // S6: h frags
    short* wf  = (short*)(ws + 7 * SZ);               // S7: 16 x 524288 shorts

    const int M = BATCH * SEQ;                        // 8192
    const dim3 gG(M / 128, EDIM / 64);                // (64, 8)
    const dim3 gQKV(M / 128, 3 * EDIM / 64);          // (64, 24)
    const dim3 gA(BATCH * NH, SEQ / 16);              // (64, 64)

    conv_wall<<<dim3(4, 32, 16), 256, 0, stream>>>(Wq, Wk, Wv, Wo, wf);
    conv_w1<<<dim3(1, 32), 256, 0, stream>>>(emb_w, wfe, 128, EDIM);
    conv_a<<<dim3(1, M / 16), 256, 0, stream>>>(x, afx, 128);
    gemm_af<<<gG, 256, 0, stream>>>(afx, wfe, emb_b, h, afh, 128);

    for (int l = 0; l < NLAYER; ++l) {
        const short* wfl = wf + (size_t)(4 * l) * 524288;
        gemm_qkv<<<gQKV, 256, 0, stream>>>(afh, wfl, bq + l * EDIM, bk + l * EDIM,
                                           bv + l * EDIM, q, kf, vf);
        attn_mfma<<<gA, 512, 0, stream>>>(q, kf, vf, afo);
        gemm_af<<<gG, 256, 0, stream>>>(afo, wfl + 3 * 524288, bo + l * EDIM, h, afh, EDIM);
    }
    mean_fc<<<8, 256, 0, stream>>>(h, fcw, fcb, out);
}

// Round 9
// 1083.766 us; speedup vs baseline: 3.5017x; 1.0504x over previous
//
#include <hip/hip_runtime.h>

#define EDIM 512
#define NH 8
#define HD 64
#define SEQ 1024
#define BATCH 8
#define NLAYER 4
#define KSEL 256

typedef __attribute__((ext_vector_type(8))) short short8;
typedef __attribute__((ext_vector_type(4))) float f32x4;

// ---- split-bf16 helpers: f ~= hi + lo, |err| ~ 2^-17 |f| ---------------
__device__ __forceinline__ unsigned short bf16_rne(float f) {
    unsigned u = __float_as_uint(f);
    return (unsigned short)((u + 0x7FFFu + ((u >> 16) & 1u)) >> 16);
}
__device__ __forceinline__ float bf16_tof(unsigned short h) {
    return __uint_as_float(((unsigned)h) << 16);
}
__device__ __forceinline__ void split2(float f, unsigned short& hi, unsigned short& lo) {
    hi = bf16_rne(f);
    float r = f - bf16_tof(hi);
    lo = (unsigned short)(__float_as_uint(r) >> 16);
}
__device__ __forceinline__ void split8(const float* xs, short8& hi, short8& lo) {
#pragma unroll
    for (int j = 0; j < 8; ++j) {
        unsigned short h, lw;
        split2(xs[j], h, lw);
        hi[j] = (short)h; lo[j] = (short)lw;
    }
}
__device__ __forceinline__ unsigned fmap(float s) {
    int fi = __float_as_int(s);
    return (unsigned)(fi ^ ((fi >> 31) | 0x80000000));
}
__device__ __forceinline__ float funmap(unsigned u) {
    int fi = (u & 0x80000000u) ? (int)(u ^ 0x80000000u) : (int)~u;
    return __int_as_float(fi);
}

// ---------------------------------------------------------------------------
// A-fragment convert (x only): grid (1, M/16), K=128.
// ---------------------------------------------------------------------------
__global__ __launch_bounds__(256) void conv_a(const float* __restrict__ A,
                                              short* __restrict__ af, int K)
{
    const int t = threadIdx.x, l = t & 63;
    const int KC = K >> 5;
    const int kc = blockIdx.x * 4 + (t >> 6);
    const int mt = blockIdx.y;
    const int m = mt * 16 + (l & 15);
    const int kb = kc * 32 + ((l >> 4) << 3);
    float4 x0 = *(const float4*)(A + (size_t)m * K + kb);
    float4 x1 = *(const float4*)(A + (size_t)m * K + kb + 4);
    float xs[8] = {x0.x, x0.y, x0.z, x0.w, x1.x, x1.y, x1.z, x1.w};
    short8 hi, lo;
    split8(xs, hi, lo);
    short* dst = af + (size_t)((mt * KC + kc) * 2) * 512 + l * 8;
    *(short8*)(dst) = hi;
    *(short8*)(dst + 512) = lo;
}

// ---------------------------------------------------------------------------
// ALL-layer weight convert: z = layer*4 + mat. grid (4,32,16).
// Wq (mat 0) pre-scaled by 0.125 (exact power of 2): q' = q/8 bit-exactly.
// ---------------------------------------------------------------------------
__global__ __launch_bounds__(256) void conv_wall(const float* __restrict__ Wq,
                                                 const float* __restrict__ Wk,
                                                 const float* __restrict__ Wv,
                                                 const float* __restrict__ Wo,
                                                 short* __restrict__ wf)
{
    const int z = blockIdx.z;
    const int layer = z >> 2, mm = z & 3;
    const float* W = (mm == 0 ? Wq : mm == 1 ? Wk : mm == 2 ? Wv : Wo)
                     + (size_t)layer * EDIM * EDIM;
    const float sc = (mm == 0) ? 0.125f : 1.0f;
    const int t = threadIdx.x, l = t & 63;
    const int kc = blockIdx.x * 4 + (t >> 6);
    const int nt = blockIdx.y;
    const int n = nt * 16 + (l & 15);
    const int kb = kc * 32 + ((l >> 4) << 3);
    float xs[8];
#pragma unroll
    for (int j = 0; j < 8; ++j) xs[j] = W[(size_t)(kb + j) * EDIM + n] * sc;
    short8 hi, lo;
    split8(xs, hi, lo);
    short* dst = wf + (size_t)z * 524288 + (size_t)((nt * 16 + kc) * 2) * 512 + l * 8;
    *(short8*)(dst) = hi;
    *(short8*)(dst + 512) = lo;
}

// single matrix variant (emb_w, K=128): grid (1, 32)
__global__ __launch_bounds__(256) void conv_w1(const float* __restrict__ W,
                                               short* __restrict__ wf, int K, int N)
{
    const int t = threadIdx.x, l = t & 63;
    const int KC = K >> 5;
    const int kc = blockIdx.x * 4 + (t >> 6);
    const int nt = blockIdx.y;
    const int n = nt * 16 + (l & 15);
    const int kb = kc * 32 + ((l >> 4) << 3);
    float xs[8];
#pragma unroll
    for (int j = 0; j < 8; ++j) xs[j] = W[(size_t)(kb + j) * N + n];
    short8 hi, lo;
    split8(xs, hi, lo);
    short* dst = wf + (size_t)((nt * KC + kc) * 2) * 512 + l * 8;
    *(short8*)(dst) = hi;
    *(short8*)(dst + 512) = lo;
}

// ---------------------------------------------------------------------------
// Split-bf16 MFMA GEMM + fused A-fragment epilogue. Cout optional.
// ---------------------------------------------------------------------------
__global__ __launch_bounds__(256, 3) void gemm_af(const short* __restrict__ af_in,
                                                  const short* __restrict__ wf,
                                                  const float* __restrict__ bias,
                                                  float* __restrict__ Cout,
                                                  short* __restrict__ af_out,
                                                  int K)
{
    __shared__ float S[128 * 68];
    const int t = threadIdx.x, l = t & 63, w = t >> 6;
    const int KC = K >> 5;
    const int mt0 = blockIdx.x * 8 + (w & 1) * 4;
    const int nt0l = (w >> 1) * 2;
    f32x4 acc[4][2] = {};

#pragma unroll 2
    for (int kc = 0; kc < KC; ++kc) {
        short8 ah[4], al[4], bh[2], bl[2];
#pragma unroll
        for (int i = 0; i < 4; ++i) {
            const short* ap = af_in + (size_t)(((mt0 + i) * KC + kc) * 2) * 512 + l * 8;
            ah[i] = *(const short8*)(ap);
            al[i] = *(const short8*)(ap + 512);
        }
#pragma unroll
        for (int j = 0; j < 2; ++j) {
            const short* bp = wf + (size_t)(((blockIdx.y * 4 + nt0l + j) * KC + kc) * 2) * 512 + l * 8;
            bh[j] = *(const short8*)(bp);
            bl[j] = *(const short8*)(bp + 512);
        }
#pragma unroll
        for (int i = 0; i < 4; ++i)
#pragma unroll
            for (int j = 0; j < 2; ++j) {
                acc[i][j] = __builtin_amdgcn_mfma_f32_16x16x32_bf16(ah[i], bh[j], acc[i][j], 0, 0, 0);
                acc[i][j] = __builtin_amdgcn_mfma_f32_16x16x32_bf16(ah[i], bl[j], acc[i][j], 0, 0, 0);
                acc[i][j] = __builtin_amdgcn_mfma_f32_16x16x32_bf16(al[i], bh[j], acc[i][j], 0, 0, 0);
            }
    }
#pragma unroll
    for (int j = 0; j < 2; ++j) {
        const int cl = (nt0l + j) * 16 + (l & 15);
        const float bv = bias[blockIdx.y * 64 + cl];
#pragma unroll
        for (int i = 0; i < 4; ++i) {
            const int rl = ((w & 1) * 4 + i) * 16 + ((l >> 4) << 2);
#pragma unroll
            for (int r = 0; r < 4; ++r) {
                const float v = acc[i][j][r] + bv;
                S[(rl + r) * 68 + cl] = v;
                if (Cout)
                    Cout[(size_t)(blockIdx.x * 128 + rl + r) * EDIM + blockIdx.y * 64 + cl] = v;
            }
        }
    }
    __syncthreads();
#pragma unroll
    for (int mi = 0; mi < 2; ++mi) {
        const int mtl = w * 2 + mi;
        const int mt = blockIdx.x * 8 + mtl;
#pragma unroll
        for (int kcl = 0; kcl < 2; ++kcl) {
            const int kc = blockIdx.y * 2 + kcl;
            const float* src = &S[(mtl * 16 + (l & 15)) * 68 + kcl * 32 + ((l >> 4) << 3)];
            float4 x0 = *(const float4*)(src);
            float4 x1 = *(const float4*)(src + 4);
            float xs[8] = {x0.x, x0.y, x0.z, x0.w, x1.x, x1.y, x1.z, x1.w};
            short8 hi, lo;
            split8(xs, hi, lo);
            short* dst = af_out + (size_t)((mt * 16 + kc) * 2) * 512 + l * 8;
            *(short8*)(dst) = hi;
            *(short8*)(dst + 512) = lo;
        }
    }
}

// ---------------------------------------------------------------------------
// Fused Q/K/V projection. grid (64, 24). y<8: Q -> qf A-fragments (Wq/bq carry
// the 1/8 scale; layout == afh: ((mt*16 + kc)*2)*512, kc = e*2 + kcl, 16 MiB);
// y in [8,16): K -> kf; y in [16,24): V -> vf.
// ---------------------------------------------------------------------------
__global__ __launch_bounds__(256, 3) void gemm_qkv(const short* __restrict__ af,
                                                   const short* __restrict__ wfl,
                                                   const float* __restrict__ bq,
                                                   const float* __restrict__ bk,
                                                   const float* __restrict__ bv,
                                                   short* __restrict__ qf,
                                                   short* __restrict__ kf,
                                                   short* __restrict__ vf)
{
    __shared__ float S[128 * 68];
    const int y = blockIdx.y;
    const int mat = y >> 3, e = y & 7;
    const short* wfm = wfl + (size_t)mat * 524288;
    const int t = threadIdx.x, l = t & 63, w = t >> 6;
    const int KC = EDIM >> 5;
    const int mt0 = blockIdx.x * 8 + (w & 1) * 4;
    const int nt0l = (w >> 1) * 2;
    f32x4 acc[4][2] = {};

#pragma unroll 2
    for (int kc = 0; kc < KC; ++kc) {
        short8 ah[4], al[4], bh[2], bl[2];
#pragma unroll
        for (int i = 0; i < 4; ++i) {
            const short* ap = af + (size_t)(((mt0 + i) * KC + kc) * 2) * 512 + l * 8;
            ah[i] = *(const short8*)(ap);
            al[i] = *(const short8*)(ap + 512);
        }
#pragma unroll
        for (int j = 0; j < 2; ++j) {
            const short* bp = wfm + (size_t)(((e * 4 + nt0l + j) * KC + kc) * 2) * 512 + l * 8;
            bh[j] = *(const short8*)(bp);
            bl[j] = *(const short8*)(bp + 512);
        }
#pragma unroll
        for (int i = 0; i < 4; ++i)
#pragma unroll
            for (int j = 0; j < 2; ++j) {
                acc[i][j] = __builtin_amdgcn_mfma_f32_16x16x32_bf16(ah[i], bh[j], acc[i][j], 0, 0, 0);
                acc[i][j] = __builtin_amdgcn_mfma_f32_16x16x32_bf16(ah[i], bl[j], acc[i][j], 0, 0, 0);
                acc[i][j] = __builtin_amdgcn_mfma_f32_16x16x32_bf16(al[i], bh[j], acc[i][j], 0, 0, 0);
            }
    }

    const int STR = (mat == 2) ? 66 : 68;
    const float* bias = mat == 0 ? bq : mat == 1 ? bk : bv;
    const float bsc = (mat == 0) ? 0.125f : 1.0f;
#pragma unroll
    for (int j = 0; j < 2; ++j) {
        const int cl = (nt0l + j) * 16 + (l & 15);
        const float bvx = bias[e * 64 + cl] * bsc;
#pragma unroll
        for (int i = 0; i < 4; ++i) {
            const int rl = ((w & 1) * 4 + i) * 16 + ((l >> 4) << 2);
#pragma unroll
            for (int r = 0; r < 4; ++r)
                S[(rl + r) * STR + cl] = acc[i][j][r] + bvx;
        }
    }
    __syncthreads();

    if (mat == 0) {
        // Q A-fragments: mt = blockIdx.x*8 + mtl, chunk kc = e*2 + kcl (0..15)
#pragma unroll
        for (int mi = 0; mi < 2; ++mi) {
            const int mtl = w * 2 + mi;
            const int mt = blockIdx.x * 8 + mtl;
#pragma unroll
            for (int kcl = 0; kcl < 2; ++kcl) {
                const int kc = e * 2 + kcl;
                const float* src = &S[(mtl * 16 + (l & 15)) * 68 + kcl * 32 + ((l >> 4) << 3)];
                float4 x0 = *(const float4*)(src);
                float4 x1 = *(const float4*)(src + 4);
                float xs[8] = {x0.x, x0.y, x0.z, x0.w, x1.x, x1.y, x1.z, x1.w};
                short8 hi, lo;
                split8(xs, hi, lo);
                short* dst = qf + (size_t)((mt * 16 + kc) * 2) * 512 + l * 8;
                *(short8*)(dst) = hi;
                *(short8*)(dst + 512) = lo;
            }
        }
        return;
    }

    const int b = blockIdx.x >> 3;
    const int bh2 = b * 8 + e;
    if (mat == 1) {
#pragma unroll
        for (int ki = 0; ki < 2; ++ki) {
            const int ktl = w * 2 + ki;
            const int kt = (blockIdx.x & 7) * 8 + ktl;
#pragma unroll
            for (int kc = 0; kc < 2; ++kc) {
                const float* src = &S[(ktl * 16 + (l & 15)) * 68 + kc * 32 + ((l >> 4) << 3)];
                float4 x0 = *(const float4*)(src);
                float4 x1 = *(const float4*)(src + 4);
                float xs[8] = {x0.x, x0.y, x0.z, x0.w, x1.x, x1.y, x1.z, x1.w};
                short8 hi, lo;
                split8(xs, hi, lo);
                short* dst = kf + (size_t)(((bh2 * 64 + kt) * 2 + kc) * 2) * 512 + l * 8;
                *(short8*)(dst) = hi;
                *(short8*)(dst + 512) = lo;
            }
        }
    } else {
        const int jc = (blockIdx.x & 7) * 4 + w;
#pragma unroll
        for (int n = 0; n < 4; ++n) {
            float xs[8];
#pragma unroll
            for (int j2 = 0; j2 < 8; ++j2)
                xs[j2] = S[(w * 32 + ((l >> 4) << 3) + j2) * 66 + n * 16 + (l & 15)];
            short8 hi, lo;
            split8(xs, hi, lo);
            short* dst = vf + (size_t)(((bh2 * 32 + jc) * 4 + n) * 2) * 512 + l * 8;
            *(short8*)(dst) = hi;
            *(short8*)(dst + 512) = lo;
        }
    }
}

// ---------------------------------------------------------------------------
// Fused sparse attention, PQ=16 / 512-thread WG, fp32 S (64 KB) -> 2 WG/CU.
// Q read directly as pre-scaled fragments (chunk hh*2+kc of 16). Phase 2:
// per-chunk e split+write (short liveness), zinv[16] in LDS; phase 3
// post-multiplies. grid (64 bh, 64 qblk).
// ---------------------------------------------------------------------------
#define SPART 65536
#define SSTG  69632
#define SZINV 73984

__global__ __launch_bounds__(512, 4) void attn_mfma(const short* __restrict__ QF,
                                                    const short* __restrict__ KF,
                                                    const short* __restrict__ VF,
                                                    short* __restrict__ afo)
{
    __shared__ alignas(16) unsigned char Sb[16 * 4096 + 4096 + 4352 + 64];

    const int bh = blockIdx.x, b = bh >> 3, hh = bh & 7;
    const int q0 = blockIdx.y * 16;
    const int t = threadIdx.x, l = t & 63, w = t >> 6;
    const int qmt = (b * SEQ + q0) >> 4;

    // Q A-fragments: direct loads (scale already folded into Wq/bq)
    short8 aqh[2], aql[2];
#pragma unroll
    for (int kc = 0; kc < 2; ++kc) {
        const short* qp = QF + (size_t)((qmt * 16 + hh * 2 + kc) * 2) * 512 + l * 8;
        aqh[kc] = *(const short8*)(qp);
        aql[kc] = *(const short8*)(qp + 512);
    }

    // ---- phase 1: wave w -> key tiles 8w..8w+7; full 16-row C; fp32 S to LDS.
    {
        const short* kfb = KF + (size_t)bh * 64 * 2048;
        const int rb = (l >> 4) << 2;
        for (int i = 0; i < 8; ++i) {
            const int kt = (w << 3) + i;
            const short* kp = kfb + (size_t)kt * 2048 + l * 8;
            short8 b00 = *(const short8*)(kp);
            short8 b01 = *(const short8*)(kp + 512);
            short8 b10 = *(const short8*)(kp + 1024);
            short8 b11 = *(const short8*)(kp + 1536);
            f32x4 acc = {0.f, 0.f, 0.f, 0.f};
            acc = __builtin_amdgcn_mfma_f32_16x16x32_bf16(aqh[0], b00, acc, 0, 0, 0);
            acc = __builtin_amdgcn_mfma_f32_16x16x32_bf16(aqh[0], b01, acc, 0, 0, 0);
            acc = __builtin_amdgcn_mfma_f32_16x16x32_bf16(aql[0], b00, acc, 0, 0, 0);
            acc = __builtin_amdgcn_mfma_f32_16x16x32_bf16(aqh[1], b10, acc, 0, 0, 0);
            acc = __builtin_amdgcn_mfma_f32_16x16x32_bf16(aqh[1], b11, acc, 0, 0, 0);
            acc = __builtin_amdgcn_mfma_f32_16x16x32_bf16(aql[1], b10, acc, 0, 0, 0);
            const int col = (kt << 4) + (l & 15);
            const int cg = col >> 2, wi = col & 3;
#pragma unroll
            for (int r = 0; r < 4; ++r) {
                const int row = rb + r;
                *(float*)(Sb + row * 4096 + (((cg ^ row) << 4) | (wi << 2))) = acc[r];
            }
        }
    }
    __syncthreads();

    // ---- phase 2: wave w owns rows 2w, 2w+1.
    {
        const int r0 = w << 1, r1 = r0 + 1;

        unsigned u0[16], u1[16];
#pragma unroll
        for (int n = 0; n < 4; ++n) {
            float4 s0 = *(const float4*)(Sb + r0 * 4096 + (((l + (n << 6)) ^ r0) << 4));
            float4 s1 = *(const float4*)(Sb + r1 * 4096 + (((l + (n << 6)) ^ r1) << 4));
            u0[n * 4 + 0] = fmap(s0.x); u0[n * 4 + 1] = fmap(s0.y);
            u0[n * 4 + 2] = fmap(s0.z); u0[n * 4 + 3] = fmap(s0.w);
            u1[n * 4 + 0] = fmap(s1.x); u1[n * 4 + 1] = fmap(s1.y);
            u1[n * 4 + 2] = fmap(s1.z); u1[n * 4 + 3] = fmap(s1.w);
        }

        unsigned um0 = u0[0], um1 = u1[0];
#pragma unroll
        for (int i = 1; i < 16; ++i) {
            um0 = u0[i] > um0 ? u0[i] : um0;
            um1 = u1[i] > um1 ? u1[i] : um1;
        }
#pragma unroll
        for (int off = 32; off > 0; off >>= 1) {
            unsigned o0 = __shfl_xor((int)um0, off);
            unsigned o1 = __shfl_xor((int)um1, off);
            um0 = o0 > um0 ? o0 : um0;
            um1 = o1 > um1 ? o1 : um1;
        }

        // dual-row exact 256th-largest with max-skip + exact-count early exit
        unsigned T0 = 0, T1 = 0;
        bool d0 = false, d1 = false;
        for (int bit = 31; bit >= 0; --bit) {
            const unsigned msk = 1u << bit;
            if (!d0) {
                const unsigned c0 = T0 | msk;
                if (c0 <= um0) {
                    int n0 = 0;
#pragma unroll
                    for (int i = 0; i < 16; ++i)
                        n0 += (int)__popcll(__ballot(u0[i] >= c0));
                    if (n0 >= KSEL) { T0 = c0; d0 = (n0 == KSEL); }
                }
            }
            if (!d1) {
                const unsigned c1 = T1 | msk;
                if (c1 <= um1) {
                    int n1 = 0;
#pragma unroll
                    for (int i = 0; i < 16; ++i)
                        n1 += (int)__popcll(__ballot(u1[i] >= c1));
                    if (n1 >= KSEL) { T1 = c1; d1 = (n1 == KSEL); }
                }
            }
            if (d0 & d1) break;
        }

        // per-chunk e compute + hi/lo write-back (unscaled); Z accumulated
        const float m0 = funmap(um0), m1 = funmap(um1);
        float Z0 = 0.f, Z1 = 0.f;
#pragma unroll
        for (int n = 0; n < 4; ++n) {
            const int gg = ((l + (n << 6)) >> 1);
            short4 H, L;
            unsigned short h, lw;
            {
                float e0 = (u0[n * 4 + 0] >= T0) ? __expf(funmap(u0[n * 4 + 0]) - m0) : 0.f;
                float e1 = (u0[n * 4 + 1] >= T0) ? __expf(funmap(u0[n * 4 + 1]) - m0) : 0.f;
                float e2 = (u0[n * 4 + 2] >= T0) ? __expf(funmap(u0[n * 4 + 2]) - m0) : 0.f;
                float e3 = (u0[n * 4 + 3] >= T0) ? __expf(funmap(u0[n * 4 + 3]) - m0) : 0.f;
                Z0 += (e0 + e1) + (e2 + e3);
                split2(e0, h, lw); H.x = (short)h; L.x = (short)lw;
                split2(e1, h, lw); H.y = (short)h; L.y = (short)lw;
                split2(e2, h, lw); H.z = (short)h; L.z = (short)lw;
                split2(e3, h, lw); H.w = (short)h; L.w = (short)lw;
                unsigned char* base0 = Sb + r0 * 4096 + (((gg ^ r0) << 4) | ((l & 1) << 3));
                *(short4*)(base0) = H;
                *(short4*)(base0 + 2048) = L;
            }
            {
                float e0 = (u1[n * 4 + 0] >= T1) ? __expf(funmap(u1[n * 4 + 0]) - m1) : 0.f;
                float e1 = (u1[n * 4 + 1] >= T1) ? __expf(funmap(u1[n * 4 + 1]) - m1) : 0.f;
                float e2 = (u1[n * 4 + 2] >= T1) ? __expf(funmap(u1[n * 4 + 2]) - m1) : 0.f;
                float e3 = (u1[n * 4 + 3] >= T1) ? __expf(funmap(u1[n * 4 + 3]) - m1) : 0.f;
                Z1 += (e0 + e1) + (e2 + e3);
                split2(e0, h, lw); H.x = (short)h; L.x = (short)lw;
                split2(e1, h, lw); H.y = (short)h; L.y = (short)lw;
                split2(e2, h, lw); H.z = (short)h; L.z = (short)lw;
                split2(e3, h, lw); H.w = (short)h; L.w = (short)lw;
                unsigned char* base1 = Sb + r1 * 4096 + (((gg ^ r1) << 4) | ((l & 1) << 3));
                *(short4*)(base1) = H;
                *(short4*)(base1 + 2048) = L;
            }
        }

#pragma unroll
        for (int off = 32; off > 0; off >>= 1) {
            Z0 += __shfl_xor(Z0, off);
            Z1 += __shfl_xor(Z1, off);
        }
        if (l == 0) {
            float* zin = (float*)(Sb + SZINV);
            zin[r0] = 1.0f / Z0;
            zin[r1] = 1.0f / Z1;
        }
    }
    __syncthreads();

    // ---- phase 3: wave w -> ch-tile (w&3), key half (w>>2); full 16-row A.
    f32x4 oacc = {0.f, 0.f, 0.f, 0.f};
    const int cht = w & 3;
    {
        const int hf = w >> 2;
        const short* vfb = VF + (size_t)bh * 32 * 4096 + (size_t)cht * 1024;
        const int m = l & 15, g3 = l >> 4;
        for (int jc = hf * 16; jc < hf * 16 + 16; ++jc) {
            const int gg = (jc << 2) + g3;
            const unsigned char* abase = Sb + m * 4096 + ((gg ^ m) << 4);
            short8 ph = *(const short8*)(abase);
            short8 pl = *(const short8*)(abase + 2048);
            const short* vp = vfb + (size_t)jc * 4096 + l * 8;
            short8 vh = *(const short8*)(vp);
            short8 vl = *(const short8*)(vp + 512);
            oacc = __builtin_amdgcn_mfma_f32_16x16x32_bf16(ph, vh, oacc, 0, 0, 0);
            oacc = __builtin_amdgcn_mfma_f32_16x16x32_bf16(ph, vl, oacc, 0, 0, 0);
            oacc = __builtin_amdgcn_mfma_f32_16x16x32_bf16(pl, vh, oacc, 0, 0, 0);
        }
    }
    // combine key-halves; scale by zinv; stage fp32
    {
        float* part = (float*)(Sb + SPART);
        const float* zin = (const float*)(Sb + SZINV);
        const int ch = l & 15, rb = (l >> 4) << 2;
        if (w >= 4) {
#pragma unroll
            for (int r = 0; r < 4; ++r)
                part[(cht * 16 + rb + r) * 16 + ch] = oacc[r];
        }
        __syncthreads();
        if (w < 4) {
            float* stage = (float*)(Sb + SSTG);
#pragma unroll
            for (int r = 0; r < 4; ++r) {
                const float v = (oacc[r] + part[(cht * 16 + rb + r) * 16 + ch]) * zin[rb + r];
                stage[(rb + r) * 68 + cht * 16 + ch] = v;
            }
        }
        __syncthreads();
    }
    // afo write: waves 0,1 (kc chunk = w); full-lane 16-row A-fragment
    if (w < 2) {
        const float* stage = (const float*)(Sb + SSTG);
        const float* src = stage + (l & 15) * 68 + w * 32 + ((l >> 4) << 3);
        float4 x0 = *(const float4*)(src);
        float4 x1 = *(const float4*)(src + 4);
        float xs[8] = {x0.x, x0.y, x0.z, x0.w, x1.x, x1.y, x1.z, x1.w};
        short8 hi, lo;
        split8(xs, hi, lo);
        const int kc = hh * 2 + w;
        short* dst = afo + (size_t)((qmt * 16 + kc) * 2) * 512 + l * 8;
        *(short8*)(dst) = hi;
        *(short8*)(dst + 512) = lo;
    }
}

// ---------------------------------------------------------------------------
__global__ __launch_bounds__(256) void mean_fc(const float* __restrict__ Hf,
                                               const float* __restrict__ fcw,
                                               const float* __restrict__ fcb,
                                               float* __restrict__ out)
{
    __shared__ float hm[EDIM];
    const int b = blockIdx.x, t = threadIdx.x;
    const float* hb = Hf + (size_t)b * SEQ * EDIM;
    float s0 = 0.f, s1 = 0.f;
    for (int s = 0; s < SEQ; ++s) {
        s0 += hb[(size_t)s * EDIM + t];
        s1 += hb[(size_t)s * EDIM + t + 256];
    }
    hm[t] = s0 * (1.0f / SEQ);
    hm[t + 256] = s1 * (1.0f / SEQ);
    __syncthreads();
    if (t < 10) {
        float acc = fcb[t];
        for (int e = 0; e < EDIM; ++e) acc += hm[e] * fcw[e * 10 + t];
        out[b * 10 + t] = acc;
    }
}

// ---------------------------------------------------------------------------
extern "C" void kernel_launch(void* const* d_in, const int* in_sizes, int n_in,
                              void* d_out, int out_size, void* d_ws, size_t ws_size,
                              hipStream_t stream)
{
    const float* x     = (const float*)d_in[0];
    const float* emb_w = (const float*)d_in[1];
    const float* emb_b = (const float*)d_in[2];
    const float* Wq    = (const float*)d_in[3];
    const float* Wk    = (const float*)d_in[4];
    const float* Wv    = (const float*)d_in[5];
    const float* Wo    = (const float*)d_in[6];
    const float* bq    = (const float*)d_in[7];
    const float* bk    = (const float*)d_in[8];
    const float* bv    = (const float*)d_in[9];
    const float* bo    = (const float*)d_in[10];
    const float* fcw   = (const float*)d_in[11];
    const float* fcb   = (const float*)d_in[12];
    float* out = (float*)d_out;
    float* ws  = (float*)d_ws;

    const size_t SZ = (size_t)BATCH * SEQ * EDIM;    // 4,194,304 floats = 16 MiB
    float* h   = ws;                                  // S0: h fp32 (final layer only)
    short* qf  = (short*)(ws + SZ);                   // S1: Q frags (16 MiB exactly)
    short* afo = (short*)(ws + 2 * SZ);               // S2: attn-out frags
    short* afx = (short*)(ws + 3 * SZ);               // S3: x frags (4 MiB used)
    short* wfe = afx + 4 * 1024 * 1024;               // S3 tail: emb weight frags
    short* kf  = (short*)(ws + 4 * SZ);               // S4
    short* vf  = (short*)(ws + 5 * SZ);               // S5
    short* afh = (short*)(ws + 6 * SZ);               // S6: h frags
    short* wf  = (short*)(ws + 7 * SZ);               // S7: 16 x 524288 shorts

    const int M = BATCH * SEQ;                        // 8192
    const dim3 gG(M / 128, EDIM / 64);                // (64, 8)
    const dim3 gQKV(M / 128, 3 * EDIM / 64);          // (64, 24)
    const dim3 gA(BATCH * NH, SEQ / 16);              // (64, 64)

    conv_wall<<<dim3(4, 32, 16), 256, 0, stream>>>(Wq, Wk, Wv, Wo, wf);
    conv_w1<<<dim3(1, 32), 256, 0, stream>>>(emb_w, wfe, 128, EDIM);
    conv_a<<<dim3(1, M / 16), 256, 0, stream>>>(x, afx, 128);
    gemm_af<<<gG, 256, 0, stream>>>(afx, wfe, emb_b, nullptr, afh, 128);

    for (int l = 0; l < NLAYER; ++l) {
        const short* wfl = wf + (size_t)(4 * l) * 524288;
        gemm_qkv<<<gQKV, 256, 0, stream>>>(afh, wfl, bq + l * EDIM, bk + l * EDIM,
                                           bv + l * EDIM, qf, kf, vf);
        attn_mfma<<<gA, 512, 0, stream>>>(qf, kf, vf, afo);
        gemm_af<<<gG, 256, 0, stream>>>(afo, wfl + 3 * 524288, bo + l * EDIM,
                                        (l == NLAYER - 1) ? h : nullptr, afh, EDIM);
    }
    mean_fc<<<8, 256, 0, stream>>>(h, fcw, fcb, out);
}

// Round 10
// 1059.310 us; speedup vs baseline: 3.5825x; 1.0231x over previous
//
#include <hip/hip_runtime.h>

#define EDIM 512
#define NH 8
#define HD 64
#define SEQ 1024
#define BATCH 8
#define NLAYER 4
#define KSEL 256

typedef __attribute__((ext_vector_type(8))) short short8;
typedef __attribute__((ext_vector_type(4))) float f32x4;

// ---- split-bf16 helpers: f ~= hi + lo, |err| ~ 2^-17 |f| ---------------
__device__ __forceinline__ unsigned short bf16_rne(float f) {
    unsigned u = __float_as_uint(f);
    return (unsigned short)((u + 0x7FFFu + ((u >> 16) & 1u)) >> 16);
}
__device__ __forceinline__ float bf16_tof(unsigned short h) {
    return __uint_as_float(((unsigned)h) << 16);
}
__device__ __forceinline__ void split2(float f, unsigned short& hi, unsigned short& lo) {
    hi = bf16_rne(f);
    float r = f - bf16_tof(hi);
    lo = (unsigned short)(__float_as_uint(r) >> 16);
}
// truncation variant (used for e in attn: e >= 0, same 2^-17 error class, fewer ops)
__device__ __forceinline__ void split2t(float f, unsigned short& hi, unsigned short& lo) {
    hi = (unsigned short)(__float_as_uint(f) >> 16);
    float r = f - bf16_tof(hi);
    lo = (unsigned short)(__float_as_uint(r) >> 16);
}
__device__ __forceinline__ void split8(const float* xs, short8& hi, short8& lo) {
#pragma unroll
    for (int j = 0; j < 8; ++j) {
        unsigned short h, lw;
        split2(xs[j], h, lw);
        hi[j] = (short)h; lo[j] = (short)lw;
    }
}
__device__ __forceinline__ unsigned fmap(float s) {
    int fi = __float_as_int(s);
    return (unsigned)(fi ^ ((fi >> 31) | 0x80000000));
}
__device__ __forceinline__ float funmap(unsigned u) {
    int fi = (u & 0x80000000u) ? (int)(u ^ 0x80000000u) : (int)~u;
    return __int_as_float(fi);
}

// ---------------------------------------------------------------------------
// A-fragment convert (x only): grid (1, M/16), K=128.
// ---------------------------------------------------------------------------
__global__ __launch_bounds__(256) void conv_a(const float* __restrict__ A,
                                              short* __restrict__ af, int K)
{
    const int t = threadIdx.x, l = t & 63;
    const int KC = K >> 5;
    const int kc = blockIdx.x * 4 + (t >> 6);
    const int mt = blockIdx.y;
    const int m = mt * 16 + (l & 15);
    const int kb = kc * 32 + ((l >> 4) << 3);
    float4 x0 = *(const float4*)(A + (size_t)m * K + kb);
    float4 x1 = *(const float4*)(A + (size_t)m * K + kb + 4);
    float xs[8] = {x0.x, x0.y, x0.z, x0.w, x1.x, x1.y, x1.z, x1.w};
    short8 hi, lo;
    split8(xs, hi, lo);
    short* dst = af + (size_t)((mt * KC + kc) * 2) * 512 + l * 8;
    *(short8*)(dst) = hi;
    *(short8*)(dst + 512) = lo;
}

// ---------------------------------------------------------------------------
// ALL-layer weight convert: z = layer*4 + mat. grid (4,32,16).
// Wq (mat 0) pre-scaled by 0.125 (exact power of 2): q' = q/8 bit-exactly.
// ---------------------------------------------------------------------------
__global__ __launch_bounds__(256) void conv_wall(const float* __restrict__ Wq,
                                                 const float* __restrict__ Wk,
                                                 const float* __restrict__ Wv,
                                                 const float* __restrict__ Wo,
                                                 short* __restrict__ wf)
{
    const int z = blockIdx.z;
    const int layer = z >> 2, mm = z & 3;
    const float* W = (mm == 0 ? Wq : mm == 1 ? Wk : mm == 2 ? Wv : Wo)
                     + (size_t)layer * EDIM * EDIM;
    const float sc = (mm == 0) ? 0.125f : 1.0f;
    const int t = threadIdx.x, l = t & 63;
    const int kc = blockIdx.x * 4 + (t >> 6);
    const int nt = blockIdx.y;
    const int n = nt * 16 + (l & 15);
    const int kb = kc * 32 + ((l >> 4) << 3);
    float xs[8];
#pragma unroll
    for (int j = 0; j < 8; ++j) xs[j] = W[(size_t)(kb + j) * EDIM + n] * sc;
    short8 hi, lo;
    split8(xs, hi, lo);
    short* dst = wf + (size_t)z * 524288 + (size_t)((nt * 16 + kc) * 2) * 512 + l * 8;
    *(short8*)(dst) = hi;
    *(short8*)(dst + 512) = lo;
}

// single matrix variant (emb_w, K=128): grid (1, 32)
__global__ __launch_bounds__(256) void conv_w1(const float* __restrict__ W,
                                               short* __restrict__ wf, int K, int N)
{
    const int t = threadIdx.x, l = t & 63;
    const int KC = K >> 5;
    const int kc = blockIdx.x * 4 + (t >> 6);
    const int nt = blockIdx.y;
    const int n = nt * 16 + (l & 15);
    const int kb = kc * 32 + ((l >> 4) << 3);
    float xs[8];
#pragma unroll
    for (int j = 0; j < 8; ++j) xs[j] = W[(size_t)(kb + j) * N + n];
    short8 hi, lo;
    split8(xs, hi, lo);
    short* dst = wf + (size_t)((nt * KC + kc) * 2) * 512 + l * 8;
    *(short8*)(dst) = hi;
    *(short8*)(dst + 512) = lo;
}

// ---------------------------------------------------------------------------
// Split-bf16 MFMA GEMM + fused A-fragment epilogue. Cout optional.
// ---------------------------------------------------------------------------
__global__ __launch_bounds__(256, 3) void gemm_af(const short* __restrict__ af_in,
                                                  const short* __restrict__ wf,
                                                  const float* __restrict__ bias,
                                                  float* __restrict__ Cout,
                                                  short* __restrict__ af_out,
                                                  int K)
{
    __shared__ float S[128 * 68];
    const int t = threadIdx.x, l = t & 63, w = t >> 6;
    const int KC = K >> 5;
    const int mt0 = blockIdx.x * 8 + (w & 1) * 4;
    const int nt0l = (w >> 1) * 2;
    f32x4 acc[4][2] = {};

#pragma unroll 2
    for (int kc = 0; kc < KC; ++kc) {
        short8 ah[4], al[4], bh[2], bl[2];
#pragma unroll
        for (int i = 0; i < 4; ++i) {
            const short* ap = af_in + (size_t)(((mt0 + i) * KC + kc) * 2) * 512 + l * 8;
            ah[i] = *(const short8*)(ap);
            al[i] = *(const short8*)(ap + 512);
        }
#pragma unroll
        for (int j = 0; j < 2; ++j) {
            const short* bp = wf + (size_t)(((blockIdx.y * 4 + nt0l + j) * KC + kc) * 2) * 512 + l * 8;
            bh[j] = *(const short8*)(bp);
            bl[j] = *(const short8*)(bp + 512);
        }
#pragma unroll
        for (int i = 0; i < 4; ++i)
#pragma unroll
            for (int j = 0; j < 2; ++j) {
                acc[i][j] = __builtin_amdgcn_mfma_f32_16x16x32_bf16(ah[i], bh[j], acc[i][j], 0, 0, 0);
                acc[i][j] = __builtin_amdgcn_mfma_f32_16x16x32_bf16(ah[i], bl[j], acc[i][j], 0, 0, 0);
                acc[i][j] = __builtin_amdgcn_mfma_f32_16x16x32_bf16(al[i], bh[j], acc[i][j], 0, 0, 0);
            }
    }
#pragma unroll
    for (int j = 0; j < 2; ++j) {
        const int cl = (nt0l + j) * 16 + (l & 15);
        const float bv = bias[blockIdx.y * 64 + cl];
#pragma unroll
        for (int i = 0; i < 4; ++i) {
            const int rl = ((w & 1) * 4 + i) * 16 + ((l >> 4) << 2);
#pragma unroll
            for (int r = 0; r < 4; ++r) {
                const float v = acc[i][j][r] + bv;
                S[(rl + r) * 68 + cl] = v;
                if (Cout)
                    Cout[(size_t)(blockIdx.x * 128 + rl + r) * EDIM + blockIdx.y * 64 + cl] = v;
            }
        }
    }
    __syncthreads();
#pragma unroll
    for (int mi = 0; mi < 2; ++mi) {
        const int mtl = w * 2 + mi;
        const int mt = blockIdx.x * 8 + mtl;
#pragma unroll
        for (int kcl = 0; kcl < 2; ++kcl) {
            const int kc = blockIdx.y * 2 + kcl;
            const float* src = &S[(mtl * 16 + (l & 15)) * 68 + kcl * 32 + ((l >> 4) << 3)];
            float4 x0 = *(const float4*)(src);
            float4 x1 = *(const float4*)(src + 4);
            float xs[8] = {x0.x, x0.y, x0.z, x0.w, x1.x, x1.y, x1.z, x1.w};
            short8 hi, lo;
            split8(xs, hi, lo);
            short* dst = af_out + (size_t)((mt * 16 + kc) * 2) * 512 + l * 8;
            *(short8*)(dst) = hi;
            *(short8*)(dst + 512) = lo;
        }
    }
}

// ---------------------------------------------------------------------------
// Fused Q/K/V projection. grid (64, 24). y<8: Q -> qf A-fragments (Wq/bq carry
// the 1/8 scale; layout == afh); y in [8,16): K -> kf; y in [16,24): V -> vf.
// ---------------------------------------------------------------------------
__global__ __launch_bounds__(256, 3) void gemm_qkv(const short* __restrict__ af,
                                                   const short* __restrict__ wfl,
                                                   const float* __restrict__ bq,
                                                   const float* __restrict__ bk,
                                                   const float* __restrict__ bv,
                                                   short* __restrict__ qf,
                                                   short* __restrict__ kf,
                                                   short* __restrict__ vf)
{
    __shared__ float S[128 * 68];
    const int y = blockIdx.y;
    const int mat = y >> 3, e = y & 7;
    const short* wfm = wfl + (size_t)mat * 524288;
    const int t = threadIdx.x, l = t & 63, w = t >> 6;
    const int KC = EDIM >> 5;
    const int mt0 = blockIdx.x * 8 + (w & 1) * 4;
    const int nt0l = (w >> 1) * 2;
    f32x4 acc[4][2] = {};

#pragma unroll 2
    for (int kc = 0; kc < KC; ++kc) {
        short8 ah[4], al[4], bh[2], bl[2];
#pragma unroll
        for (int i = 0; i < 4; ++i) {
            const short* ap = af + (size_t)(((mt0 + i) * KC + kc) * 2) * 512 + l * 8;
            ah[i] = *(const short8*)(ap);
            al[i] = *(const short8*)(ap + 512);
        }
#pragma unroll
        for (int j = 0; j < 2; ++j) {
            const short* bp = wfm + (size_t)(((e * 4 + nt0l + j) * KC + kc) * 2) * 512 + l * 8;
            bh[j] = *(const short8*)(bp);
            bl[j] = *(const short8*)(bp + 512);
        }
#pragma unroll
        for (int i = 0; i < 4; ++i)
#pragma unroll
            for (int j = 0; j < 2; ++j) {
                acc[i][j] = __builtin_amdgcn_mfma_f32_16x16x32_bf16(ah[i], bh[j], acc[i][j], 0, 0, 0);
                acc[i][j] = __builtin_amdgcn_mfma_f32_16x16x32_bf16(ah[i], bl[j], acc[i][j], 0, 0, 0);
                acc[i][j] = __builtin_amdgcn_mfma_f32_16x16x32_bf16(al[i], bh[j], acc[i][j], 0, 0, 0);
            }
    }

    const int STR = (mat == 2) ? 66 : 68;
    const float* bias = mat == 0 ? bq : mat == 1 ? bk : bv;
    const float bsc = (mat == 0) ? 0.125f : 1.0f;
#pragma unroll
    for (int j = 0; j < 2; ++j) {
        const int cl = (nt0l + j) * 16 + (l & 15);
        const float bvx = bias[e * 64 + cl] * bsc;
#pragma unroll
        for (int i = 0; i < 4; ++i) {
            const int rl = ((w & 1) * 4 + i) * 16 + ((l >> 4) << 2);
#pragma unroll
            for (int r = 0; r < 4; ++r)
                S[(rl + r) * STR + cl] = acc[i][j][r] + bvx;
        }
    }
    __syncthreads();

    if (mat == 0) {
        // Q A-fragments: mt = blockIdx.x*8 + mtl, chunk kc = e*2 + kcl (0..15)
#pragma unroll
        for (int mi = 0; mi < 2; ++mi) {
            const int mtl = w * 2 + mi;
            const int mt = blockIdx.x * 8 + mtl;
#pragma unroll
            for (int kcl = 0; kcl < 2; ++kcl) {
                const int kc = e * 2 + kcl;
                const float* src = &S[(mtl * 16 + (l & 15)) * 68 + kcl * 32 + ((l >> 4) << 3)];
                float4 x0 = *(const float4*)(src);
                float4 x1 = *(const float4*)(src + 4);
                float xs[8] = {x0.x, x0.y, x0.z, x0.w, x1.x, x1.y, x1.z, x1.w};
                short8 hi, lo;
                split8(xs, hi, lo);
                short* dst = qf + (size_t)((mt * 16 + kc) * 2) * 512 + l * 8;
                *(short8*)(dst) = hi;
                *(short8*)(dst + 512) = lo;
            }
        }
        return;
    }

    const int b = blockIdx.x >> 3;
    const int bh2 = b * 8 + e;
    if (mat == 1) {
#pragma unroll
        for (int ki = 0; ki < 2; ++ki) {
            const int ktl = w * 2 + ki;
            const int kt = (blockIdx.x & 7) * 8 + ktl;
#pragma unroll
            for (int kc = 0; kc < 2; ++kc) {
                const float* src = &S[(ktl * 16 + (l & 15)) * 68 + kc * 32 + ((l >> 4) << 3)];
                float4 x0 = *(const float4*)(src);
                float4 x1 = *(const float4*)(src + 4);
                float xs[8] = {x0.x, x0.y, x0.z, x0.w, x1.x, x1.y, x1.z, x1.w};
                short8 hi, lo;
                split8(xs, hi, lo);
                short* dst = kf + (size_t)(((bh2 * 64 + kt) * 2 + kc) * 2) * 512 + l * 8;
                *(short8*)(dst) = hi;
                *(short8*)(dst + 512) = lo;
            }
        }
    } else {
        const int jc = (blockIdx.x & 7) * 4 + w;
#pragma unroll
        for (int n = 0; n < 4; ++n) {
            float xs[8];
#pragma unroll
            for (int j2 = 0; j2 < 8; ++j2)
                xs[j2] = S[(w * 32 + ((l >> 4) << 3) + j2) * 66 + n * 16 + (l & 15)];
            short8 hi, lo;
            split8(xs, hi, lo);
            short* dst = vf + (size_t)(((bh2 * 32 + jc) * 4 + n) * 2) * 512 + l * 8;
            *(short8*)(dst) = hi;
            *(short8*)(dst + 512) = lo;
        }
    }
}

// ---------------------------------------------------------------------------
// Fused sparse attention, PQ=16 / 512-thread WG, fp32 S (64 KB) -> 2 WG/CU.
// Selection runs in FLOAT domain: the binary search's candidate threshold is
// maintained in scalar uint space (monotone map), converted once per step via
// scalar funmap, counted with v_cmp_ge_f32 against the stored floats.
// Set selected is identical to the uint-domain search (strict monotonicity).
// grid (64 bh, 64 qblk).
// ---------------------------------------------------------------------------
#define SPART 65536
#define SSTG  69632
#define SZINV 73984

__global__ __launch_bounds__(512, 4) void attn_mfma(const short* __restrict__ QF,
                                                    const short* __restrict__ KF,
                                                    const short* __restrict__ VF,
                                                    short* __restrict__ afo)
{
    __shared__ alignas(16) unsigned char Sb[16 * 4096 + 4096 + 4352 + 64];

    const int bh = blockIdx.x, b = bh >> 3, hh = bh & 7;
    const int q0 = blockIdx.y * 16;
    const int t = threadIdx.x, l = t & 63, w = t >> 6;
    const int qmt = (b * SEQ + q0) >> 4;

    // Q A-fragments: direct loads (scale already folded into Wq/bq)
    short8 aqh[2], aql[2];
#pragma unroll
    for (int kc = 0; kc < 2; ++kc) {
        const short* qp = QF + (size_t)((qmt * 16 + hh * 2 + kc) * 2) * 512 + l * 8;
        aqh[kc] = *(const short8*)(qp);
        aql[kc] = *(const short8*)(qp + 512);
    }

    // ---- phase 1: wave w -> key tiles 8w..8w+7; full 16-row C; fp32 S to LDS.
    {
        const short* kfb = KF + (size_t)bh * 64 * 2048;
        const int rb = (l >> 4) << 2;
        for (int i = 0; i < 8; ++i) {
            const int kt = (w << 3) + i;
            const short* kp = kfb + (size_t)kt * 2048 + l * 8;
            short8 b00 = *(const short8*)(kp);
            short8 b01 = *(const short8*)(kp + 512);
            short8 b10 = *(const short8*)(kp + 1024);
            short8 b11 = *(const short8*)(kp + 1536);
            f32x4 acc = {0.f, 0.f, 0.f, 0.f};
            acc = __builtin_amdgcn_mfma_f32_16x16x32_bf16(aqh[0], b00, acc, 0, 0, 0);
            acc = __builtin_amdgcn_mfma_f32_16x16x32_bf16(aqh[0], b01, acc, 0, 0, 0);
            acc = __builtin_amdgcn_mfma_f32_16x16x32_bf16(aql[0], b00, acc, 0, 0, 0);
            acc = __builtin_amdgcn_mfma_f32_16x16x32_bf16(aqh[1], b10, acc, 0, 0, 0);
            acc = __builtin_amdgcn_mfma_f32_16x16x32_bf16(aqh[1], b11, acc, 0, 0, 0);
            acc = __builtin_amdgcn_mfma_f32_16x16x32_bf16(aql[1], b10, acc, 0, 0, 0);
            const int col = (kt << 4) + (l & 15);
            const int cg = col >> 2, wi = col & 3;
#pragma unroll
            for (int r = 0; r < 4; ++r) {
                const int row = rb + r;
                *(float*)(Sb + row * 4096 + (((cg ^ row) << 4) | (wi << 2))) = acc[r];
            }
        }
    }
    __syncthreads();

    // ---- phase 2: wave w owns rows 2w, 2w+1 (float-domain selection).
    {
        const int r0 = w << 1, r1 = r0 + 1;

        float s0[16], s1[16];
#pragma unroll
        for (int n = 0; n < 4; ++n) {
            float4 a = *(const float4*)(Sb + r0 * 4096 + (((l + (n << 6)) ^ r0) << 4));
            float4 c = *(const float4*)(Sb + r1 * 4096 + (((l + (n << 6)) ^ r1) << 4));
            s0[n * 4 + 0] = a.x; s0[n * 4 + 1] = a.y; s0[n * 4 + 2] = a.z; s0[n * 4 + 3] = a.w;
            s1[n * 4 + 0] = c.x; s1[n * 4 + 1] = c.y; s1[n * 4 + 2] = c.z; s1[n * 4 + 3] = c.w;
        }

        float m0 = s0[0], m1 = s1[0];
#pragma unroll
        for (int i = 1; i < 16; ++i) {
            m0 = fmaxf(m0, s0[i]);
            m1 = fmaxf(m1, s1[i]);
        }
#pragma unroll
        for (int off = 32; off > 0; off >>= 1) {
            m0 = fmaxf(m0, __shfl_xor(m0, off));
            m1 = fmaxf(m1, __shfl_xor(m1, off));
        }
        const unsigned um0 = (unsigned)__builtin_amdgcn_readfirstlane((int)fmap(m0));
        const unsigned um1 = (unsigned)__builtin_amdgcn_readfirstlane((int)fmap(m1));

        // dual-row exact 256th-largest; candidates in scalar uint space,
        // counting via float compares (monotone-equivalent).
        unsigned T0 = 0, T1 = 0;
        bool d0 = false, d1 = false;
        for (int bit = 31; bit >= 0; --bit) {
            const unsigned msk = 1u << bit;
            if (!d0) {
                const unsigned c0 = T0 | msk;
                if (c0 <= um0) {
                    const float fc0 = funmap(c0);
                    int n0 = 0;
#pragma unroll
                    for (int i = 0; i < 16; ++i)
                        n0 += (int)__popcll(__ballot(s0[i] >= fc0));
                    if (n0 >= KSEL) { T0 = c0; d0 = (n0 == KSEL); }
                }
            }
            if (!d1) {
                const unsigned c1 = T1 | msk;
                if (c1 <= um1) {
                    const float fc1 = funmap(c1);
                    int n1 = 0;
#pragma unroll
                    for (int i = 0; i < 16; ++i)
                        n1 += (int)__popcll(__ballot(s1[i] >= fc1));
                    if (n1 >= KSEL) { T1 = c1; d1 = (n1 == KSEL); }
                }
            }
            if (d0 & d1) break;
        }
        const float fT0 = funmap(T0), fT1 = funmap(T1);

        // per-chunk e compute + hi/lo write-back (trunc split); Z accumulated
        float Z0 = 0.f, Z1 = 0.f;
#pragma unroll
        for (int n = 0; n < 4; ++n) {
            const int gg = ((l + (n << 6)) >> 1);
            short4 H, L;
            unsigned short h, lw;
            {
                float e0 = (s0[n * 4 + 0] >= fT0) ? __expf(s0[n * 4 + 0] - m0) : 0.f;
                float e1 = (s0[n * 4 + 1] >= fT0) ? __expf(s0[n * 4 + 1] - m0) : 0.f;
                float e2 = (s0[n * 4 + 2] >= fT0) ? __expf(s0[n * 4 + 2] - m0) : 0.f;
                float e3 = (s0[n * 4 + 3] >= fT0) ? __expf(s0[n * 4 + 3] - m0) : 0.f;
                Z0 += (e0 + e1) + (e2 + e3);
                split2t(e0, h, lw); H.x = (short)h; L.x = (short)lw;
                split2t(e1, h, lw); H.y = (short)h; L.y = (short)lw;
                split2t(e2, h, lw); H.z = (short)h; L.z = (short)lw;
                split2t(e3, h, lw); H.w = (short)h; L.w = (short)lw;
                unsigned char* base0 = Sb + r0 * 4096 + (((gg ^ r0) << 4) | ((l & 1) << 3));
                *(short4*)(base0) = H;
                *(short4*)(base0 + 2048) = L;
            }
            {
                float e0 = (s1[n * 4 + 0] >= fT1) ? __expf(s1[n * 4 + 0] - m1) : 0.f;
                float e1 = (s1[n * 4 + 1] >= fT1) ? __expf(s1[n * 4 + 1] - m1) : 0.f;
                float e2 = (s1[n * 4 + 2] >= fT1) ? __expf(s1[n * 4 + 2] - m1) : 0.f;
                float e3 = (s1[n * 4 + 3] >= fT1) ? __expf(s1[n * 4 + 3] - m1) : 0.f;
                Z1 += (e0 + e1) + (e2 + e3);
                split2t(e0, h, lw); H.x = (short)h; L.x = (short)lw;
                split2t(e1, h, lw); H.y = (short)h; L.y = (short)lw;
                split2t(e2, h, lw); H.z = (short)h; L.z = (short)lw;
                split2t(e3, h, lw); H.w = (short)h; L.w = (short)lw;
                unsigned char* base1 = Sb + r1 * 4096 + (((gg ^ r1) << 4) | ((l & 1) << 3));
                *(short4*)(base1) = H;
                *(short4*)(base1 + 2048) = L;
            }
        }

#pragma unroll
        for (int off = 32; off > 0; off >>= 1) {
            Z0 += __shfl_xor(Z0, off);
            Z1 += __shfl_xor(Z1, off);
        }
        if (l == 0) {
            float* zin = (float*)(Sb + SZINV);
            zin[r0] = 1.0f / Z0;
            zin[r1] = 1.0f / Z1;
        }
    }
    __syncthreads();

    // ---- phase 3: wave w -> ch-tile (w&3), key half (w>>2); full 16-row A.
    f32x4 oacc = {0.f, 0.f, 0.f, 0.f};
    const int cht = w & 3;
    {
        const int hf = w >> 2;
        const short* vfb = VF + (size_t)bh * 32 * 4096 + (size_t)cht * 1024;
        const int m = l & 15, g3 = l >> 4;
        for (int jc = hf * 16; jc < hf * 16 + 16; ++jc) {
            const int gg = (jc << 2) + g3;
            const unsigned char* abase = Sb + m * 4096 + ((gg ^ m) << 4);
            short8 ph = *(const short8*)(abase);
            short8 pl = *(const short8*)(abase + 2048);
            const short* vp = vfb + (size_t)jc * 4096 + l * 8;
            short8 vh = *(const short8*)(vp);
            short8 vl = *(const short8*)(vp + 512);
            oacc = __builtin_amdgcn_mfma_f32_16x16x32_bf16(ph, vh, oacc, 0, 0, 0);
            oacc = __builtin_amdgcn_mfma_f32_16x16x32_bf16(ph, vl, oacc, 0, 0, 0);
            oacc = __builtin_amdgcn_mfma_f32_16x16x32_bf16(pl, vh, oacc, 0, 0, 0);
        }
    }
    // combine key-halves; scale by zinv; stage fp32
    {
        float* part = (float*)(Sb + SPART);
        const float* zin = (const float*)(Sb + SZINV);
        const int ch = l & 15, rb = (l >> 4) << 2;
        if (w >= 4) {
#pragma unroll
            for (int r = 0; r < 4; ++r)
                part[(cht * 16 + rb + r) * 16 + ch] = oacc[r];
        }
        __syncthreads();
        if (w < 4) {
            float* stage = (float*)(Sb + SSTG);
#pragma unroll
            for (int r = 0; r < 4; ++r) {
                const float v = (oacc[r] + part[(cht * 16 + rb + r) * 16 + ch]) * zin[rb + r];
                stage[(rb + r) * 68 + cht * 16 + ch] = v;
            }
        }
        __syncthreads();
    }
    // afo write: waves 0,1 (kc chunk = w); full-lane 16-row A-fragment
    if (w < 2) {
        const float* stage = (const float*)(Sb + SSTG);
        const float* src = stage + (l & 15) * 68 + w * 32 + ((l >> 4) << 3);
        float4 x0 = *(const float4*)(src);
        float4 x1 = *(const float4*)(src + 4);
        float xs[8] = {x0.x, x0.y, x0.z, x0.w, x1.x, x1.y, x1.z, x1.w};
        short8 hi, lo;
        split8(xs, hi, lo);
        const int kc = hh * 2 + w;
        short* dst = afo + (size_t)((qmt * 16 + kc) * 2) * 512 + l * 8;
        *(short8*)(dst) = hi;
        *(short8*)(dst + 512) = lo;
    }
}

// ---------------------------------------------------------------------------
__global__ __launch_bounds__(256) void mean_fc(const float* __restrict__ Hf,
                                               const float* __restrict__ fcw,
                                               const float* __restrict__ fcb,
                                               float* __restrict__ out)
{
    __shared__ float hm[EDIM];
    const int b = blockIdx.x, t = threadIdx.x;
    const float* hb = Hf + (size_t)b * SEQ * EDIM;
    float s0 = 0.f, s1 = 0.f;
    for (int s = 0; s < SEQ; ++s) {
        s0 += hb[(size_t)s * EDIM + t];
        s1 += hb[(size_t)s * EDIM + t + 256];
    }
    hm[t] = s0 * (1.0f / SEQ);
    hm[t + 256] = s1 * (1.0f / SEQ);
    __syncthreads();
    if (t < 10) {
        float acc = fcb[t];
        for (int e = 0; e < EDIM; ++e) acc += hm[e] * fcw[e * 10 + t];
        out[b * 10 + t] = acc;
    }
}

// ---------------------------------------------------------------------------
extern "C" void kernel_launch(void* const* d_in, const int* in_sizes, int n_in,
                              void* d_out, int out_size, void* d_ws, size_t ws_size,
                              hipStream_t stream)
{
    const float* x     = (const float*)d_in[0];
    const float* emb_w = (const float*)d_in[1];
    const float* emb_b = (const float*)d_in[2];
    const float* Wq    = (const float*)d_in[3];
    const float* Wk    = (const float*)d_in[4];
    const float* Wv    = (const float*)d_in[5];
    const float* Wo    = (const float*)d_in[6];
    const float* bq    = (const float*)d_in[7];
    const float* bk    = (const float*)d_in[8];
    const float* bv    = (const float*)d_in[9];
    const float* bo    = (const float*)d_in[10];
    const float* fcw   = (const float*)d_in[11];
    const float* fcb   = (const float*)d_in[12];
    float* out = (float*)d_out;
    float* ws  = (float*)d_ws;

    const size_t SZ = (size_t)BATCH * SEQ * EDIM;    // 4,194,304 floats = 16 MiB
    float* h   = ws;                                  // S0: h fp32 (final layer only)
    short* qf  = (short*)(ws + SZ);                   // S1: Q frags (16 MiB exactly)
    short* afo = (short*)(ws + 2 * SZ);               // S2: attn-out frags
    short* afx = (short*)(ws + 3 * SZ);               // S3: x frags (4 MiB used)
    short* wfe = afx + 4 * 1024 * 1024;               // S3 tail: emb weight frags
    short* kf  = (short*)(ws + 4 * SZ);               // S4
    short* vf  = (short*)(ws + 5 * SZ);               // S5
    short* afh = (short*)(ws + 6 * SZ);               // S6: h frags
    short* wf  = (short*)(ws + 7 * SZ);               // S7: 16 x 524288 shorts

    const int M = BATCH * SEQ;                        // 8192
    const dim3 gG(M / 128, EDIM / 64);                // (64, 8)
    const dim3 gQKV(M / 128, 3 * EDIM / 64);          // (64, 24)
    const dim3 gA(BATCH * NH, SEQ / 16);              // (64, 64)

    conv_wall<<<dim3(4, 32, 16), 256, 0, stream>>>(Wq, Wk, Wv, Wo, wf);
    conv_w1<<<dim3(1, 32), 256, 0, stream>>>(emb_w, wfe, 128, EDIM);
    conv_a<<<dim3(1, M / 16), 256, 0, stream>>>(x, afx, 128);
    gemm_af<<<gG, 256, 0, stream>>>(afx, wfe, emb_b, nullptr, afh, 128);

    for (int l = 0; l < NLAYER; ++l) {
        const short* wfl = wf + (size_t)(4 * l) * 524288;
        gemm_qkv<<<gQKV, 256, 0, stream>>>(afh, wfl, bq + l * EDIM, bk + l * EDIM,
                                           bv + l * EDIM, qf, kf, vf);
        attn_mfma<<<gA, 512, 0, stream>>>(qf, kf, vf, afo);
        gemm_af<<<gG, 256, 0, stream>>>(afo, wfl + 3 * 524288, bo + l * EDIM,
                                        (l == NLAYER - 1) ? h : nullptr, afh, EDIM);
    }
    mean_fc<<<8, 256, 0, stream>>>(h, fcw, fcb, out);
}